// Round 7
// baseline (762.420 us; speedup 1.0000x reference)
//
#include <hip/hip_runtime.h>
#include <math.h>

typedef unsigned int   uint;
typedef unsigned short ushort;
using bf16x8 = __attribute__((ext_vector_type(8))) __bf16;
using f32x4  = __attribute__((ext_vector_type(4))) float;

constexpr int NB   = 128;
constexpr int NCAP = 512;
constexpr int NCLS = 43;
constexpr int NO   = 21;
constexpr int KO   = NCLS * NO; // 903

// ---- workspace layout (float offsets) ----
constexpr size_t F_X1H  = 0;          // conv1 out hi, blocked [16][131072][8] bf16
constexpr size_t F_X1L  = 8388608;
constexpr size_t F_PART = 0;          // conv3/4/5 K-split partials (x1 dead)
constexpr size_t F_STAT = 16777216;   // 1,024
constexpr size_t F_WPH  = 16778240;   // conv2 w (147,456)
constexpr size_t F_WPL  = 16925696;
constexpr size_t F_W3H  = 17073152;
constexpr size_t F_W3L  = 17204224;
constexpr size_t F_W4H  = 17335296;
constexpr size_t F_W4L  = 17400832;
constexpr size_t F_W5H  = 17466368;
constexpr size_t F_W5L  = 17728512;
constexpr size_t F_X3H  = 17990656;   // conv2 out hi, blocked [32][131072][8] bf16
constexpr size_t F_X3L  = 34767872;   // ends 51,545,088
constexpr size_t F_H3   = 51545088;   // h3 NHWC fp32 (2,097,152)
constexpr size_t F_X4H  = 53642240;
constexpr size_t F_X4L  = 54690816;
constexpr size_t F_H4   = 55739392;
constexpr size_t F_X5H  = 56787968;
constexpr size_t F_X5L  = 57312256;
constexpr size_t F_H5   = 57836544;   // (524,288)
// routing phase:
constexpr size_t F_PRI  = 0;          // bf16 priors: 59,179,008 ushorts
constexpr size_t F_CAPS = 59179008;   // 524,288
constexpr size_t F_LOG  = 59703296;   // 2,818,048
constexpr size_t F_S    = 65339392;   // 115,584
constexpr size_t F_OUTS = 65454976;   // 115,584

__device__ inline ushort f2bf(float x) {
  uint u = __float_as_uint(x);
  uint r = (u + 0x7fffu + ((u >> 16) & 1u)) >> 16;  // RNE
  return (ushort)r;
}
__device__ inline float bf2f(ushort h) { return __uint_as_float(((uint)h) << 16); }

// ---------------- conv1: fp32 direct, writes blocked pre-BN bf16 hi/lo ----
__global__ __launch_bounds__(256) void conv1_k(
    const float* __restrict__ in, const float* __restrict__ w,
    ushort* __restrict__ oh, ushort* __restrict__ ol)
{
  constexpr int KS = 3, ICC = 3, IHT = 10, IWT = 18;
  const int ocb = blockIdx.z & 3;
  const int b   = blockIdx.z >> 2;
  const int tx0 = blockIdx.x * 16;
  const int ty0 = blockIdx.y * 8;
  const int oc0 = ocb * 32;

  __shared__ float lin[ICC][IHT][IWT];
  __shared__ float lw[ICC][KS * KS][32];

  const int t  = threadIdx.x;
  const int pq = t & 3;
  const int ty = (t >> 2) & 7;
  const int oq = t >> 5;

  float acc[4][4];
#pragma unroll
  for (int m = 0; m < 4; ++m)
#pragma unroll
    for (int j = 0; j < 4; ++j) acc[m][j] = 0.f;

  const int gx0 = tx0 - 1;
  const int gy0 = ty0 - 1;

  for (int e = t; e < ICC * IHT * IWT; e += 256) {
    int ic = e / (IHT * IWT);
    int rr = e % (IHT * IWT);
    int ey = rr / IWT, ex = rr % IWT;
    int gy = gy0 + ey, gx = gx0 + ex;
    float v = 0.f;
    if ((unsigned)gy < 128u && (unsigned)gx < 128u)
      v = in[((size_t)(b * 3 + ic) * 128 + gy) * 128 + gx];
    lin[ic][ey][ex] = v;
  }
  for (int e = t; e < ICC * 9 * 32; e += 256) {
    int ocl = e & 31;
    int rr  = e >> 5;
    int kk  = rr % 9;
    int ic  = rr / 9;
    lw[ic][kk][ocl] = w[((size_t)(oc0 + ocl) * 3 + ic) * 9 + kk];
  }
  __syncthreads();

  for (int ic = 0; ic < ICC; ++ic) {
#pragma unroll
    for (int ky = 0; ky < KS; ++ky) {
#pragma unroll
      for (int kx = 0; kx < KS; ++kx) {
        float xv[4];
#pragma unroll
        for (int j = 0; j < 4; ++j)
          xv[j] = lin[ic][ty + ky][pq * 4 + j + kx];
        const float4 w4 = *(const float4*)&lw[ic][ky * KS + kx][oq * 4];
#pragma unroll
        for (int j = 0; j < 4; ++j) {
          acc[0][j] = fmaf(w4.x, xv[j], acc[0][j]);
          acc[1][j] = fmaf(w4.y, xv[j], acc[1][j]);
          acc[2][j] = fmaf(w4.z, xv[j], acc[2][j]);
          acc[3][j] = fmaf(w4.w, xv[j], acc[3][j]);
        }
      }
    }
  }

  const int oy = ty0 + ty;
  const int oc0q = oc0 + oq * 4;
  const size_t icb = oc0q >> 3;
  const int off = oc0q & 7;
#pragma unroll
  for (int j = 0; j < 4; ++j) {
    int px = tx0 + pq * 4 + j;
    size_t pxg = ((size_t)b * 128 + oy) * 128 + px;
    size_t addr = (icb * 131072 + pxg) * 8 + off;
    ushort h0 = f2bf(acc[0][j]); ushort l0 = f2bf(acc[0][j] - bf2f(h0));
    ushort h1 = f2bf(acc[1][j]); ushort l1 = f2bf(acc[1][j] - bf2f(h1));
    ushort h2 = f2bf(acc[2][j]); ushort l2 = f2bf(acc[2][j] - bf2f(h2));
    ushort h3 = f2bf(acc[3][j]); ushort l3 = f2bf(acc[3][j] - bf2f(h3));
    uint2 uh; uh.x = (uint)h0 | ((uint)h1 << 16); uh.y = (uint)h2 | ((uint)h3 << 16);
    uint2 ul; ul.x = (uint)l0 | ((uint)l1 << 16); ul.y = (uint)l2 | ((uint)l3 << 16);
    *(uint2*)(oh + addr) = uh;
    *(uint2*)(ol + addr) = ul;
  }
}

// ---------------- BN stats: blocked bf16 hi/lo ----------------
__global__ __launch_bounds__(256) void bn_stats_blocked_k(
    const ushort* __restrict__ xh, const ushort* __restrict__ xl,
    float* __restrict__ stats, int nj, int totpx, int slices)
{
  const int j  = blockIdx.x % nj;
  const int sl = blockIdx.x / nj;
  float s[8] = {0,0,0,0,0,0,0,0}, q[8] = {0,0,0,0,0,0,0,0};
  const ushort* ph = xh + (size_t)j * totpx * 8;
  const ushort* pl = xl + (size_t)j * totpx * 8;
  for (int p = sl * 256 + threadIdx.x; p < totpx; p += slices * 256) {
    uint4 vh = *(const uint4*)(ph + (size_t)p * 8);
    uint4 vl = *(const uint4*)(pl + (size_t)p * 8);
    uint hw[4] = {vh.x, vh.y, vh.z, vh.w};
    uint lw[4] = {vl.x, vl.y, vl.z, vl.w};
#pragma unroll
    for (int m = 0; m < 4; ++m) {
      float v0 = __uint_as_float(hw[m] << 16) + __uint_as_float(lw[m] << 16);
      float v1 = __uint_as_float(hw[m] & 0xffff0000u) + __uint_as_float(lw[m] & 0xffff0000u);
      s[2*m] += v0; q[2*m] += v0 * v0;
      s[2*m+1] += v1; q[2*m+1] += v1 * v1;
    }
  }
#pragma unroll
  for (int off = 32; off > 0; off >>= 1)
#pragma unroll
    for (int k = 0; k < 8; ++k) {
      s[k] += __shfl_down(s[k], off);
      q[k] += __shfl_down(q[k], off);
    }
  __shared__ float red[4][16];
  int wid = threadIdx.x >> 6, lane = threadIdx.x & 63;
  if (lane == 0) {
#pragma unroll
    for (int k = 0; k < 8; ++k) { red[wid][k] = s[k]; red[wid][8 + k] = q[k]; }
  }
  __syncthreads();
  if (threadIdx.x < 16) {
    float a = red[0][threadIdx.x] + red[1][threadIdx.x] + red[2][threadIdx.x] + red[3][threadIdx.x];
    int C = nj * 8;
    int c = j * 8 + (threadIdx.x & 7);
    atomicAdd(&stats[(threadIdx.x >> 3) * C + c], a);
  }
}

__global__ __launch_bounds__(256) void bn_stats_nhwc_k(
    const float* __restrict__ x, float* __restrict__ stats,
    int cmask, int lg2c, int totpx)
{
  int g = blockIdx.x * 256 + threadIdx.x;
  int c = g & cmask;
  int p0 = g >> lg2c;
  int stride = (gridDim.x * 256) >> lg2c;
  float s = 0.f, q = 0.f;
  for (int p = p0; p < totpx; p += stride) {
    float v = x[((size_t)p << lg2c) | c];
    s += v; q += v * v;
  }
  atomicAdd(&stats[c], s);
  atomicAdd(&stats[cmask + 1 + c], q);
}

// ---- BN+LReLU+split fp32 NHWC -> blocked bf16 hi/lo (inline fin) ----
template<int C>
__global__ __launch_bounds__(256) void split_blocked_k(
    const float* __restrict__ h, const float* __restrict__ stats,
    const float* __restrict__ g, const float* __restrict__ bt, float inv_n,
    ushort* __restrict__ oh, ushort* __restrict__ ol, int totpx)
{
  __shared__ ushort lh[16][C + 8], ll[16][C + 8];
  __shared__ float scs[C], sfs[C];
  const int px0 = blockIdx.x * 16;
  const int t = threadIdx.x;
  if (t < C) {
    float m = stats[t] * inv_n;
    float v = stats[C + t] * inv_n - m * m;
    float rs = rsqrtf(v + 1e-5f);
    float sc = g[t] * rs;
    scs[t] = sc; sfs[t] = bt[t] - m * sc;
  }
  __syncthreads();
  for (int e = t; e < 16 * C / 4; e += 256) {
    int px = e / (C / 4);
    int c0 = (e % (C / 4)) * 4;
    float4 v  = *(const float4*)(h + (size_t)(px0 + px) * C + c0);
    float a0 = fmaf(v.x, scs[c0],   sfs[c0]);   a0 = fmaxf(a0, 0.1f * a0);
    float a1 = fmaf(v.y, scs[c0+1], sfs[c0+1]); a1 = fmaxf(a1, 0.1f * a1);
    float a2 = fmaf(v.z, scs[c0+2], sfs[c0+2]); a2 = fmaxf(a2, 0.1f * a2);
    float a3 = fmaf(v.w, scs[c0+3], sfs[c0+3]); a3 = fmaxf(a3, 0.1f * a3);
    ushort h0 = f2bf(a0), h1 = f2bf(a1), h2v = f2bf(a2), h3v = f2bf(a3);
    lh[px][c0]   = h0;  ll[px][c0]   = f2bf(a0 - bf2f(h0));
    lh[px][c0+1] = h1;  ll[px][c0+1] = f2bf(a1 - bf2f(h1));
    lh[px][c0+2] = h2v; ll[px][c0+2] = f2bf(a2 - bf2f(h2v));
    lh[px][c0+3] = h3v; ll[px][c0+3] = f2bf(a3 - bf2f(h3v));
  }
  __syncthreads();
  for (int e = t; e < 16 * (C / 8); e += 256) {
    int j = e >> 4, px = e & 15;
    *(uint4*)(oh + ((size_t)j * totpx + px0 + px) * 8) = *(const uint4*)&lh[px][j * 8];
    *(uint4*)(ol + ((size_t)j * totpx + px0 + px) * 8) = *(const uint4*)&ll[px][j * 8];
  }
}

// ------- all weight splits merged; FRAGMENT-ORDERED layouts -------
// conv2: d = ((((kk*4+ic32)*2+ohf)*8+of)*4+kg)*128 + lr*8 + ici
// convs: d = ((((ky*NCH+ch)*NWO+wo)*4+of)*4+kx)*128 + lr*8 + ici
__global__ void wsplit_all_k(
    const float* __restrict__ c2w, const float* __restrict__ c3w,
    const float* __restrict__ c4w, const float* __restrict__ c5w,
    ushort* __restrict__ wph, ushort* __restrict__ wpl,
    ushort* __restrict__ w3h, ushort* __restrict__ w3l,
    ushort* __restrict__ w4h, ushort* __restrict__ w4l,
    ushort* __restrict__ w5h, ushort* __restrict__ w5l)
{
  int i = blockIdx.x * 256 + threadIdx.x;
  if (i < 294912) {
    int kk = i % 9; int r = i / 9; int ic = r & 127; int oc = r >> 7;
    float v = c2w[i];
    ushort hi = f2bf(v), lo = f2bf(v - bf2f(hi));
    int ohf = oc >> 7, of = (oc >> 4) & 7, lr = oc & 15;
    int ic32 = ic >> 5, kg = (ic >> 3) & 3, ici = ic & 7;
    size_t d = ((((size_t)(kk * 4 + ic32) * 2 + ohf) * 8 + of) * 4 + kg) * 128
               + lr * 8 + ici;
    wph[d] = hi; wpl[d] = lo;
    return;
  }
  i -= 294912;
  const float* w; ushort *wh, *wl; int OC, IC, n;
  if (i < 262144)      { w = c3w; wh = w3h; wl = w3l; OC = 64;  IC = 256; n = i; }
  else if (i < 393216) { w = c4w; wh = w4h; wl = w4l; OC = 128; IC = 64;  n = i - 262144; }
  else if (i < 917504) { w = c5w; wh = w5h; wl = w5l; OC = 256; IC = 128; n = i - 393216; }
  else return;
  int kx = n & 3, ky = (n >> 2) & 3;
  int ic = (n >> 4) % IC, oc = (n >> 4) / IC;
  float v = w[n];
  ushort hi = f2bf(v), lo = f2bf(v - bf2f(hi));
  int NCH = IC >> 3, NWO = OC >> 6;
  int wo = oc >> 6, of = (oc >> 4) & 3, lr = oc & 15;
  int ch = ic >> 3, ici = ic & 7;
  size_t d = ((((size_t)(ky * NCH + ch) * NWO + wo) * 4 + of) * 4 + kx) * 128
             + lr * 8 + ici;
  wh[d] = hi; wl[d] = lo;
}

// ------- conv2 via MFMA (bf16x3): W fragments straight from global -------
// 1 row x 128 px x 256 oc per block; BN of x1 fused in X staging; XCD swizzle.
__global__ __launch_bounds__(256, 2) void conv2_mfma_k(
    const ushort* __restrict__ x1h, const ushort* __restrict__ x1l,
    const ushort* __restrict__ wph, const ushort* __restrict__ wpl,
    const float* __restrict__ stats, const float* __restrict__ g1,
    const float* __restrict__ b1,
    ushort* __restrict__ x3h, ushort* __restrict__ x3l)
{
  const int bid = blockIdx.x;                 // 1024 blocks
  const int wid = (bid & 7) * 128 + (bid >> 3);
  const int y0  = wid & 127;
  const int b   = wid >> 7;

  __shared__ ushort xs[2][4][130][8];   // [hl][icg][xi][ic8] : 16,640 B
  __shared__ float scs[128], sfs[128];

  const int t = threadIdx.x;
  if (t < 128) {
    float m = stats[t] * (1.f / 131072.f);
    float v = stats[128 + t] * (1.f / 131072.f) - m * m;
    float rs = rsqrtf(v + 1e-5f);
    float sc = g1[t] * rs;
    scs[t] = sc; sfs[t] = b1[t] - m * sc;
  }

  const int w  = t >> 6;
  const int l  = t & 63;
  const int xhf = w & 1;        // x half (64 px)
  const int ohf = w >> 1;       // oc half (128 oc)
  const int lr = l & 15;
  const int kg = l >> 4;

  f32x4 acc[8][4];
#pragma unroll
  for (int i = 0; i < 8; ++i)
#pragma unroll
    for (int j = 0; j < 4; ++j) acc[i][j] = (f32x4){0.f, 0.f, 0.f, 0.f};

  for (int ky = 0; ky < 3; ++ky) {
    const int gy = y0 + ky - 1;
    const bool rowok = (unsigned)gy < 128u;
    for (int ic32 = 0; ic32 < 4; ++ic32) {
      __syncthreads();
      // stage X: 130 xi x 4 icg, BN+LReLU fused
      for (int e = t; e < 520; e += 256) {
        int icg = e / 130;
        int xi  = e - icg * 130;
        int gx = xi - 1;
        uint4 rh = {0, 0, 0, 0}, rl = {0, 0, 0, 0};
        if (rowok && (unsigned)gx < 128u) {
          int jb = ic32 * 4 + icg;
          size_t gi = ((size_t)jb * 131072 + ((size_t)b * 128 + gy) * 128 + gx) * 8;
          uint4 vh = *(const uint4*)(x1h + gi);
          uint4 vl = *(const uint4*)(x1l + gi);
          int c0 = jb * 8;
          uint hw[4] = {vh.x, vh.y, vh.z, vh.w};
          uint lw[4] = {vl.x, vl.y, vl.z, vl.w};
          uint ohv[4], olv[4];
#pragma unroll
          for (int m = 0; m < 4; ++m) {
            float f0 = __uint_as_float(hw[m] << 16) + __uint_as_float(lw[m] << 16);
            float f1 = __uint_as_float(hw[m] & 0xffff0000u) + __uint_as_float(lw[m] & 0xffff0000u);
            float a0 = fmaf(f0, scs[c0 + 2*m],   sfs[c0 + 2*m]);   a0 = fmaxf(a0, 0.1f * a0);
            float a1 = fmaf(f1, scs[c0 + 2*m+1], sfs[c0 + 2*m+1]); a1 = fmaxf(a1, 0.1f * a1);
            ushort h0 = f2bf(a0), l0 = f2bf(a0 - bf2f(h0));
            ushort h1 = f2bf(a1), l1 = f2bf(a1 - bf2f(h1));
            ohv[m] = (uint)h0 | ((uint)h1 << 16);
            olv[m] = (uint)l0 | ((uint)l1 << 16);
          }
          rh.x = ohv[0]; rh.y = ohv[1]; rh.z = ohv[2]; rh.w = ohv[3];
          rl.x = olv[0]; rl.y = olv[1]; rl.z = olv[2]; rl.w = olv[3];
        }
        *(uint4*)&xs[0][icg][xi][0] = rh;
        *(uint4*)&xs[1][icg][xi][0] = rl;
      }
      __syncthreads();

#pragma unroll
      for (int kx = 0; kx < 3; ++kx) {
        const int kk = ky * 3 + kx;
        const size_t wbase =
            ((size_t)((kk * 4 + ic32) * 2 + ohf)) * 4096 + (size_t)l * 8;
        const ushort* pwh = wph + wbase;
        const ushort* pwl = wpl + wbase;

        bf16x8 xbh[4], xbl[4];
#pragma unroll
        for (int pf = 0; pf < 4; ++pf) {
          int xi = xhf * 64 + pf * 16 + lr + kx;
          xbh[pf] = *(const bf16x8*)&xs[0][kg][xi][0];
          xbl[pf] = *(const bf16x8*)&xs[1][kg][xi][0];
        }
#pragma unroll
        for (int oh2 = 0; oh2 < 2; ++oh2) {
          bf16x8 awh[4], awl[4];
#pragma unroll
          for (int o4 = 0; o4 < 4; ++o4) {
            awh[o4] = *(const bf16x8*)(pwh + (oh2 * 4 + o4) * 512);
            awl[o4] = *(const bf16x8*)(pwl + (oh2 * 4 + o4) * 512);
          }
#pragma unroll
          for (int o4 = 0; o4 < 4; ++o4) {
            const int of = oh2 * 4 + o4;
#pragma unroll
            for (int pf = 0; pf < 4; ++pf) {
              acc[of][pf] = __builtin_amdgcn_mfma_f32_16x16x32_bf16(awh[o4], xbh[pf], acc[of][pf], 0, 0, 0);
              acc[of][pf] = __builtin_amdgcn_mfma_f32_16x16x32_bf16(awh[o4], xbl[pf], acc[of][pf], 0, 0, 0);
              acc[of][pf] = __builtin_amdgcn_mfma_f32_16x16x32_bf16(awl[o4], xbh[pf], acc[of][pf], 0, 0, 0);
            }
          }
        }
      }
    }
  }

  // epilogue: blocked bf16 hi/lo [oc/8][(b*128+y)*128+x][8]
#pragma unroll
  for (int of = 0; of < 8; ++of) {
#pragma unroll
    for (int pf = 0; pf < 4; ++pf) {
      int oc = ohf * 128 + of * 16 + kg * 4;
      int x  = xhf * 64 + pf * 16 + lr;
      size_t pxg = ((size_t)b * 128 + y0) * 128 + x;
      size_t base = ((size_t)(oc >> 3) * 131072 + pxg) * 8 + (oc & 7);
      f32x4 a = acc[of][pf];
      ushort h0 = f2bf(a[0]); ushort l0 = f2bf(a[0] - bf2f(h0));
      ushort h1 = f2bf(a[1]); ushort l1 = f2bf(a[1] - bf2f(h1));
      ushort h2 = f2bf(a[2]); ushort l2 = f2bf(a[2] - bf2f(h2));
      ushort h3 = f2bf(a[3]); ushort l3 = f2bf(a[3] - bf2f(h3));
      uint2 uh; uh.x = (uint)h0 | ((uint)h1 << 16); uh.y = (uint)h2 | ((uint)h3 << 16);
      uint2 ul; ul.x = (uint)l0 | ((uint)l1 << 16); ul.y = (uint)l2 | ((uint)l3 << 16);
      *(uint2*)(x3h + base) = uh;
      *(uint2*)(x3l + base) = ul;
    }
  }
}

// ------- conv3/4/5 via MFMA, K-split, W fragments from global -------
template<int IC, int OC, int OH, int OW, int WPX, int CS, bool FBN>
__global__ __launch_bounds__(256, 2) void convs_mfma_k(
    const ushort* __restrict__ xh, const ushort* __restrict__ xl,
    const ushort* __restrict__ wh, const ushort* __restrict__ wl,
    const float* __restrict__ stats, const float* __restrict__ gg,
    const float* __restrict__ bb, float inv_n,
    float* __restrict__ part)
{
  constexpr int IH  = 2 * OH, IW = 2 * OW;
  constexpr int NCH = IC / 8;
  constexpr int NCHB = NCH / CS;
  constexpr int PFX = OW / 16;
  constexpr int RW  = 4 / WPX;
  constexpr int NZ = 4 * CS;
  constexpr int NX = OH / 4;
  constexpr int NWO = OC / 64;
  constexpr int SBN = FBN ? IC : 1;

  const int bid = blockIdx.x;
  const int wid = (bid & 7) * (NZ * NX) + (bid >> 3);
  const int zi = wid % NZ;
  const int y0 = ((wid / NZ) % NX) * 4;
  const int b  = wid / (NZ * NX);
  const int ky = zi & 3;
  const int cs = zi >> 2;

  __shared__ ushort xs[2][4][2][OW + 2][8];
  __shared__ float scs[SBN], sfs[SBN];

  const int t = threadIdx.x;
  if (FBN) {
    for (int c = t; c < IC; c += 256) {
      float m = stats[c] * inv_n;
      float v = stats[IC + c] * inv_n - m * m;
      float rs = rsqrtf(v + 1e-5f);
      float sc = gg[c] * rs;
      scs[c] = sc; sfs[c] = bb[c] - m * sc;
    }
  }

  const int w = t >> 6, l = t & 63;
  const int wo = w / WPX, wp = w % WPX;
  const int lr = l & 15, kg = l >> 4;
  const int oc0w = wo * 64;
  const int rb = wp * RW;

  f32x4 acc[4][4];
#pragma unroll
  for (int i = 0; i < 4; ++i)
#pragma unroll
    for (int j = 0; j < 4; ++j) acc[i][j] = (f32x4){0.f, 0.f, 0.f, 0.f};

  for (int cc = 0; cc < NCHB; ++cc) {
    const int ch = cs * NCHB + cc;
    __syncthreads();
    for (int e = t; e < 4 * (IW + 2); e += 256) {
      int r  = e / (IW + 2);
      int xi = e % (IW + 2);
      int xp = xi - 1;
      int iy = 2 * (y0 + r) + ky - 1;
      uint4 rh = {0, 0, 0, 0}, rl = {0, 0, 0, 0};
      if ((unsigned)iy < (unsigned)IH && (unsigned)xp < (unsigned)IW) {
        size_t gi = ((((size_t)ch * 8 + b) * IH + iy) * IW + xp) * 8;
        uint4 vh = *(const uint4*)(xh + gi);
        uint4 vl = *(const uint4*)(xl + gi);
        if (FBN) {
          int c0 = ch * 8;
          uint hw[4] = {vh.x, vh.y, vh.z, vh.w};
          uint lw[4] = {vl.x, vl.y, vl.z, vl.w};
          uint ohv[4], olv[4];
#pragma unroll
          for (int m = 0; m < 4; ++m) {
            float f0 = __uint_as_float(hw[m] << 16) + __uint_as_float(lw[m] << 16);
            float f1 = __uint_as_float(hw[m] & 0xffff0000u) + __uint_as_float(lw[m] & 0xffff0000u);
            float a0 = fmaf(f0, scs[c0 + 2*m],   sfs[c0 + 2*m]);   a0 = fmaxf(a0, 0.1f * a0);
            float a1 = fmaf(f1, scs[c0 + 2*m+1], sfs[c0 + 2*m+1]); a1 = fmaxf(a1, 0.1f * a1);
            ushort h0 = f2bf(a0), l0 = f2bf(a0 - bf2f(h0));
            ushort h1 = f2bf(a1), l1 = f2bf(a1 - bf2f(h1));
            ohv[m] = (uint)h0 | ((uint)h1 << 16);
            olv[m] = (uint)l0 | ((uint)l1 << 16);
          }
          rh.x = ohv[0]; rh.y = ohv[1]; rh.z = ohv[2]; rh.w = ohv[3];
          rl.x = olv[0]; rl.y = olv[1]; rl.z = olv[2]; rl.w = olv[3];
        } else {
          rh = vh; rl = vl;
        }
      }
      int par = xp & 1;
      int idx = (xp + 1) >> 1;
      *(uint4*)&xs[0][r][par][idx][0] = rh;
      *(uint4*)&xs[1][r][par][idx][0] = rl;
    }
    __syncthreads();

    const size_t wbase =
        ((size_t)(ky * NCH + ch) * NWO + wo) * 2048 + (size_t)l * 8;
    bf16x8 ah[4], al[4], bh[4], bl[4];
#pragma unroll
    for (int of = 0; of < 4; ++of) {
      ah[of] = *(const bf16x8*)(wh + wbase + of * 512);
      al[of] = *(const bf16x8*)(wl + wbase + of * 512);
    }
    const int par = 1 - (kg & 1);
    const int xoff = kg >> 1;
#pragma unroll
    for (int pf = 0; pf < 4; ++pf) {
      int row = rb + pf / PFX;
      int x   = (pf % PFX) * 16 + lr;
      bh[pf] = *(const bf16x8*)&xs[0][row][par][x + xoff][0];
      bl[pf] = *(const bf16x8*)&xs[1][row][par][x + xoff][0];
    }
#pragma unroll
    for (int of = 0; of < 4; ++of) {
#pragma unroll
      for (int pf = 0; pf < 4; ++pf) {
        acc[of][pf] = __builtin_amdgcn_mfma_f32_16x16x32_bf16(ah[of], bh[pf], acc[of][pf], 0, 0, 0);
        acc[of][pf] = __builtin_amdgcn_mfma_f32_16x16x32_bf16(ah[of], bl[pf], acc[of][pf], 0, 0, 0);
        acc[of][pf] = __builtin_amdgcn_mfma_f32_16x16x32_bf16(al[of], bh[pf], acc[of][pf], 0, 0, 0);
      }
    }
  }

  float* yp = part + (size_t)zi * (8 * OH * OW * OC);
#pragma unroll
  for (int of = 0; of < 4; ++of) {
#pragma unroll
    for (int pf = 0; pf < 4; ++pf) {
      int row = rb + pf / PFX;
      int x   = (pf % PFX) * 16 + lr;
      int oc  = oc0w + of * 16 + kg * 4;
      float* p = yp + (((size_t)b * OH + y0 + row) * OW + x) * OC + oc;
      f32x4 a = acc[of][pf];
      float4 v = {a[0], a[1], a[2], a[3]};
      *(float4*)p = v;
    }
  }
}

// ------- reduce partials -> h (float4) -------
__global__ __launch_bounds__(256) void reduce_k(
    const float* __restrict__ part, float* __restrict__ h,
    int n4, int nparts)
{
  int i = blockIdx.x * 256 + threadIdx.x;
  if (i >= n4) return;
  float4 a = ((const float4*)part)[i];
  for (int z = 1; z < nparts; ++z) {
    float4 b = ((const float4*)part)[(size_t)z * n4 + i];
    a.x += b.x; a.y += b.y; a.z += b.z; a.w += b.w;
  }
  ((float4*)h)[i] = a;
}

// ---------------- capsule rearrange (h5 NHWC, BN inline) ----------------
__global__ void caps_k(const float* __restrict__ h5, const float* __restrict__ stats,
                       const float* __restrict__ g5, const float* __restrict__ b5,
                       float* __restrict__ caps)
{
  int e = blockIdx.x * 256 + threadIdx.x;
  if (e >= NB * NCAP * 8) return;
  int ii = e & 7;
  int n  = (e >> 3) & 511;
  int jb = e >> 12;
  int j = jb >> 3, b = jb & 7;
  int i = n >> 7, k = (n >> 5) & 3, ch = ((n & 31) << 3) | ii;
  int hh = (i << 2) | (j >> 2);
  int ww = ((j & 3) << 2) | k;
  float m  = stats[ch] * (1.f / 2048.f);
  float vv = stats[256 + ch] * (1.f / 2048.f) - m * m;
  float rs = rsqrtf(vv + 1e-5f);
  float sc = g5[ch] * rs;
  float sf = b5[ch] - m * sc;
  float v = h5[(((size_t)b * 16 + hh) * 16 + ww) * 256 + ch];
  float a = fmaf(v, sc, sf);
  a = fmaxf(a, 0.1f * a);
  caps[e] = a;
}

// ---------------- priors (bf16 output) ----------------
__global__ __launch_bounds__(256) void priors_k(
    const float* __restrict__ caps, const float* __restrict__ rw,
    ushort* __restrict__ priors)
{
  const int n = blockIdx.x;
  __shared__ float lrw[NCLS * 8 * NO];
  __shared__ float lc[NB * 8];
  const int t = threadIdx.x;
  for (int e = t; e < NCLS * 8 * NO; e += 256)
    lrw[e] = rw[(size_t)n * NCLS * 8 * NO + e];
  for (int e = t; e < NB * 8; e += 256) {
    int b = e >> 3, ii = e & 7;
    lc[e] = caps[((size_t)b * NCAP + n) * 8 + ii];
  }
  __syncthreads();

  int p[4], kk[4], oo[4];
#pragma unroll
  for (int q = 0; q < 4; ++q) {
    p[q]  = t + q * 256;
    kk[q] = (p[q] < KO) ? p[q] / NO : 0;
    oo[q] = (p[q] < KO) ? p[q] % NO : 0;
  }
  for (int b = 0; b < NB; ++b) {
    const float* cb = &lc[b * 8];
    float c0 = cb[0], c1 = cb[1], c2 = cb[2], c3 = cb[3];
    float c4 = cb[4], c5 = cb[5], c6 = cb[6], c7 = cb[7];
    ushort* pout = priors + ((size_t)b * NCAP + n) * KO;
#pragma unroll
    for (int q = 0; q < 4; ++q) {
      if (p[q] < KO) {
        const float* wv = &lrw[kk[q] * (8 * NO) + oo[q]];
        float a = c0 * wv[0];
        a = fmaf(c1, wv[21],  a);
        a = fmaf(c2, wv[42],  a);
        a = fmaf(c3, wv[63],  a);
        a = fmaf(c4, wv[84],  a);
        a = fmaf(c5, wv[105], a);
        a = fmaf(c6, wv[126], a);
        a = fmaf(c7, wv[147], a);
        pout[p[q]] = f2bf(a);
      }
    }
  }
}

// ---------------- routing ----------------
__global__ __launch_bounds__(256) void route_s_partial(
    const ushort* __restrict__ priors, float* __restrict__ s)
{
  const int b  = blockIdx.x >> 3;
  const int ns = blockIdx.x & 7;
  const int t  = threadIdx.x;
  const int p0 = t, p1 = t + 256, p2 = t + 512, p3 = t + 768;
  float a0 = 0.f, a1 = 0.f, a2 = 0.f, a3 = 0.f;
  const ushort* pb = priors + ((size_t)b * NCAP + ns * 64) * KO;
#pragma unroll 2
  for (int n = 0; n < 64; ++n) {
    const ushort* pn = pb + (size_t)n * KO;
    a0 += bf2f(pn[p0]); a1 += bf2f(pn[p1]); a2 += bf2f(pn[p2]);
    if (p3 < KO) a3 += bf2f(pn[p3]);
  }
  const float sc = 1.f / 43.f;
  atomicAdd(&s[b * KO + p0], a0 * sc);
  atomicAdd(&s[b * KO + p1], a1 * sc);
  atomicAdd(&s[b * KO + p2], a2 * sc);
  if (p3 < KO) atomicAdd(&s[b * KO + p3], a3 * sc);
}

// fused logits+softmax+s, wave-parallel over n
__global__ __launch_bounds__(256) void route_iter_k(
    const ushort* __restrict__ priors, const float* __restrict__ souts,
    float* __restrict__ logits, float* __restrict__ s,
    int readPrev, int writeL)
{
  const int b  = blockIdx.x >> 3;
  const int ns = blockIdx.x & 7;
  const int t  = threadIdx.x;
  const int w  = t >> 6;
  const int lane = t & 63;

  __shared__ float so_l[KO];
  __shared__ float sacc[4][KO];
  __shared__ float prow[4][KO];
  __shared__ float pk[4][NCLS];

  for (int e = t; e < KO; e += 256) so_l[e] = souts[b * KO + e];
  for (int e = lane; e < KO; e += 64) sacc[w][e] = 0.f;

  int kq[15];
#pragma unroll
  for (int q = 0; q < 15; ++q) {
    int e = lane + q * 64;
    kq[q] = (e < KO) ? e / NO : 0;
  }
  __syncthreads();

  for (int nn = 0; nn < 16; ++nn) {
    const int n = ns * 64 + w * 16 + nn;
    const ushort* pr = priors + ((size_t)(b * NCAP + n)) * KO;
    float v[15];
#pragma unroll
    for (int q = 0; q < 15; ++q) {
      int e = lane + q * 64;
      if (e < KO) { v[q] = bf2f(pr[e]); prow[w][e] = v[q]; }
      else v[q] = 0.f;
    }
    __syncthreads();

    float L = -1e30f;
    if (lane < NCLS) {
      float d = 0.f;
      const float* pp = &prow[w][lane * NO];
      const float* ss = &so_l[lane * NO];
#pragma unroll
      for (int o = 0; o < NO; ++o) d = fmaf(pp[o], ss[o], d);
      size_t lidx = ((size_t)(b * NCAP + n)) * NCLS + lane;
      L = (readPrev ? logits[lidx] : 0.f) + d;
      if (writeL) logits[lidx] = L;
    }
    float m = L;
#pragma unroll
    for (int off = 32; off > 0; off >>= 1) m = fmaxf(m, __shfl_xor(m, off));
    float ex = (lane < NCLS) ? __expf(L - m) : 0.f;
    float sm = ex;
#pragma unroll
    for (int off = 32; off > 0; off >>= 1) sm += __shfl_xor(sm, off);
    if (lane < NCLS) pk[w][lane] = ex / sm;
    __syncthreads();

#pragma unroll
    for (int q = 0; q < 15; ++q) {
      int e = lane + q * 64;
      if (e < KO) sacc[w][e] += pk[w][kq[q]] * v[q];
    }
  }
  __syncthreads();
  for (int e = t; e < KO; e += 256)
    atomicAdd(&s[b * KO + e], sacc[0][e] + sacc[1][e] + sacc[2][e] + sacc[3][e]);
}

__global__ void squash_k(const float* __restrict__ s, float* __restrict__ souts)
{
  int i = blockIdx.x * 256 + threadIdx.x;
  if (i >= NB * NCLS) return;
  int b = i / NCLS, k = i % NCLS;
  const float* sv = s + b * KO + k * NO;
  float sn = 0.f;
#pragma unroll
  for (int o = 0; o < NO; ++o) sn += sv[o] * sv[o];
  float f = sqrtf(sn) / (1.f + sn);
  float* ov = souts + b * KO + k * NO;
#pragma unroll
  for (int o = 0; o < NO; ++o) ov[o] = sv[o] * f;
}

__global__ void out_k(const float* __restrict__ souts, float* __restrict__ out)
{
  int i = blockIdx.x * 256 + threadIdx.x;
  if (i >= 8 * 16 * NCLS * NO) return;
  int o = i % NO;
  int r = i / NO;
  int k = r % NCLS; r /= NCLS;
  int g1 = r & 3; r >>= 2;
  int g0 = r & 3;
  int b  = r >> 2;
  int j  = g0 * 4 + g1;
  int jb = j * 8 + b;
  out[i] = souts[jb * KO + k * NO + o];
}

// ---------------- launcher ----------------
extern "C" void kernel_launch(void* const* d_in, const int* in_sizes, int n_in,
                              void* d_out, int out_size, void* d_ws, size_t ws_size,
                              hipStream_t stream)
{
  const float* x   = (const float*)d_in[0];
  const float* c1w = (const float*)d_in[1];
  const float* g1  = (const float*)d_in[3];  const float* b1  = (const float*)d_in[4];
  const float* c2w = (const float*)d_in[5];
  const float* g2  = (const float*)d_in[7];  const float* b2  = (const float*)d_in[8];
  const float* c3w = (const float*)d_in[9];
  const float* g3  = (const float*)d_in[11]; const float* b3  = (const float*)d_in[12];
  const float* c4w = (const float*)d_in[13];
  const float* g4  = (const float*)d_in[15]; const float* b4  = (const float*)d_in[16];
  const float* c5w = (const float*)d_in[17];
  const float* g5  = (const float*)d_in[19]; const float* b5  = (const float*)d_in[20];
  const float* rw  = (const float*)d_in[21];

  float* ws  = (float*)d_ws;
  float* out = (float*)d_out;

  ushort* x1h = (ushort*)(ws + F_X1H);
  ushort* x1l = (ushort*)(ws + F_X1L);
  ushort* wph = (ushort*)(ws + F_WPH);
  ushort* wpl = (ushort*)(ws + F_WPL);
  ushort* w3h = (ushort*)(ws + F_W3H);
  ushort* w3l = (ushort*)(ws + F_W3L);
  ushort* w4h = (ushort*)(ws + F_W4H);
  ushort* w4l = (ushort*)(ws + F_W4L);
  ushort* w5h = (ushort*)(ws + F_W5H);
  ushort* w5l = (ushort*)(ws + F_W5L);
  ushort* x3h = (ushort*)(ws + F_X3H);
  ushort* x3l = (ushort*)(ws + F_X3L);
  ushort* x4h = (ushort*)(ws + F_X4H);
  ushort* x4l = (ushort*)(ws + F_X4L);
  ushort* x5h = (ushort*)(ws + F_X5H);
  ushort* x5l = (ushort*)(ws + F_X5L);
  float* part   = ws + F_PART;
  float* h3     = ws + F_H3;
  float* h4     = ws + F_H4;
  float* h5     = ws + F_H5;
  float* caps   = ws + F_CAPS;
  ushort* priors = (ushort*)(ws + F_PRI);
  float* logits = ws + F_LOG;
  float* sbuf   = ws + F_S;
  float* souts  = ws + F_OUTS;
  float* stats  = ws + F_STAT;

  // ---- weight preps (merged, fragment-ordered) ----
  wsplit_all_k<<<(1212416 + 255) / 256, 256, 0, stream>>>(
      c2w, c3w, c4w, c5w, wph, wpl, w3h, w3l, w4h, w4l, w5h, w5l);

  // ---- conv1 -> blocked pre-BN bf16 hi/lo; stats ----
  conv1_k<<<dim3(8, 16, 32), 256, 0, stream>>>(x, c1w, x1h, x1l);
  hipMemsetAsync(stats, 0, 2 * 128 * sizeof(float), stream);
  bn_stats_blocked_k<<<16 * 16, 256, 0, stream>>>(x1h, x1l, stats, 16, 131072, 16);

  // ---- conv2 (MFMA, BN fused, W from global, XCD swizzle) -> pre-BN; stats ----
  conv2_mfma_k<<<1024, 256, 0, stream>>>(x1h, x1l, wph, wpl, stats, g1, b1, x3h, x3l);
  hipMemsetAsync(stats, 0, 2 * 256 * sizeof(float), stream);
  bn_stats_blocked_k<<<32 * 8, 256, 0, stream>>>(x3h, x3l, stats, 32, 131072, 8);

  // ---- conv3 (MFMA, ky-split x4, BN of x3 fused) ----
  convs_mfma_k<256, 64, 64, 64, 4, 1, true><<<512, 256, 0, stream>>>(
      x3h, x3l, w3h, w3l, stats, g2, b2, 1.f / 131072.f, part);
  reduce_k<<<(524288 + 255) / 256, 256, 0, stream>>>(part, h3, 524288, 4);
  hipMemsetAsync(stats, 0, 2 * 64 * sizeof(float), stream);
  bn_stats_nhwc_k<<<256, 256, 0, stream>>>(h3, stats, 63, 6, 32768);
  split_blocked_k<64><<<2048, 256, 0, stream>>>(h3, stats, g3, b3, 1.f / 32768.f, x4h, x4l, 32768);

  // ---- conv4 (MFMA, (ky x ch/2)-split x8) ----
  convs_mfma_k<64, 128, 32, 32, 2, 2, false><<<512, 256, 0, stream>>>(
      x4h, x4l, w4h, w4l, stats, g4, b4, 0.f, part);
  reduce_k<<<(262144 + 255) / 256, 256, 0, stream>>>(part, h4, 262144, 8);
  hipMemsetAsync(stats, 0, 2 * 128 * sizeof(float), stream);
  bn_stats_nhwc_k<<<128, 256, 0, stream>>>(h4, stats, 127, 7, 8192);
  split_blocked_k<128><<<512, 256, 0, stream>>>(h4, stats, g4, b4, 1.f / 8192.f, x5h, x5l, 8192);

  // ---- conv5 (MFMA, (ky x ch/2)-split x8) ----
  convs_mfma_k<128, 256, 16, 16, 1, 2, false><<<256, 256, 0, stream>>>(
      x5h, x5l, w5h, w5l, stats, g5, b5, 0.f, part);
  reduce_k<<<(131072 + 255) / 256, 256, 0, stream>>>(part, h5, 131072, 8);
  hipMemsetAsync(stats, 0, 2 * 256 * sizeof(float), stream);
  bn_stats_nhwc_k<<<64, 256, 0, stream>>>(h5, stats, 255, 8, 2048);

  // ---- capsules ----
  caps_k<<<2048, 256, 0, stream>>>(h5, stats, g5, b5, caps);
  priors_k<<<512, 256, 0, stream>>>(caps, rw, priors);

  // ---- routing: 3 iterations ----
  hipMemsetAsync(sbuf, 0, NB * KO * sizeof(float), stream);
  route_s_partial<<<NB * 8, 256, 0, stream>>>(priors, sbuf);
  squash_k<<<(NB * NCLS + 255) / 256, 256, 0, stream>>>(sbuf, souts);

  hipMemsetAsync(sbuf, 0, NB * KO * sizeof(float), stream);
  route_iter_k<<<NB * 8, 256, 0, stream>>>(priors, souts, logits, sbuf, 0, 1);
  squash_k<<<(NB * NCLS + 255) / 256, 256, 0, stream>>>(sbuf, souts);

  hipMemsetAsync(sbuf, 0, NB * KO * sizeof(float), stream);
  route_iter_k<<<NB * 8, 256, 0, stream>>>(priors, souts, logits, sbuf, 1, 0);
  squash_k<<<(NB * NCLS + 255) / 256, 256, 0, stream>>>(sbuf, souts);

  // ---- final scatter ----
  out_k<<<(8 * 16 * NCLS * NO + 255) / 256, 256, 0, stream>>>(souts, out);
}

// Round 8
// 702.552 us; speedup vs baseline: 1.0852x; 1.0852x over previous
//
#include <hip/hip_runtime.h>
#include <math.h>

typedef unsigned int   uint;
typedef unsigned short ushort;
using bf16x8 = __attribute__((ext_vector_type(8))) __bf16;
using f32x4  = __attribute__((ext_vector_type(4))) float;

constexpr int NB   = 128;
constexpr int NCAP = 512;
constexpr int NCLS = 43;
constexpr int NO   = 21;
constexpr int KO   = NCLS * NO; // 903

// ---- workspace layout (float offsets) ----
constexpr size_t F_X1H  = 0;          // conv1 out hi, blocked [16][131072][8] bf16
constexpr size_t F_X1L  = 8388608;
constexpr size_t F_PART = 0;          // conv3/4/5 K-split partials (x1 dead)
constexpr size_t F_STAT = 16777216;   // 1,024 floats (conv1 stats [0..255]; stats2 at +512)
constexpr size_t F_WPH  = 16778240;   // conv2 w (147,456)
constexpr size_t F_WPL  = 16925696;
constexpr size_t F_W3H  = 17073152;
constexpr size_t F_W3L  = 17204224;
constexpr size_t F_W4H  = 17335296;
constexpr size_t F_W4L  = 17400832;
constexpr size_t F_W5H  = 17466368;
constexpr size_t F_W5L  = 17728512;
constexpr size_t F_X3H  = 17990656;   // conv2 out hi, blocked [32][131072][8] bf16
constexpr size_t F_X3L  = 34767872;   // ends 51,545,088
constexpr size_t F_H3   = 51545088;   // h3 NHWC fp32 (2,097,152)
constexpr size_t F_X4H  = 53642240;
constexpr size_t F_X4L  = 54690816;
constexpr size_t F_H4   = 55739392;
constexpr size_t F_X5H  = 56787968;
constexpr size_t F_X5L  = 57312256;
constexpr size_t F_H5   = 57836544;   // (524,288)
// routing phase:
constexpr size_t F_PRI  = 0;          // bf16 priors: 59,179,008 ushorts
constexpr size_t F_CAPS = 59179008;   // 524,288
constexpr size_t F_LOG  = 59703296;   // 2,818,048
constexpr size_t F_S    = 65339392;   // 115,584
constexpr size_t F_OUTS = 65454976;   // 115,584 -> ends 65,570,560
constexpr size_t F_ZERO = 65570560;   // 16 floats zero stub for OOB global_load_lds

__device__ inline ushort f2bf(float x) {
  uint u = __float_as_uint(x);
  uint r = (u + 0x7fffu + ((u >> 16) & 1u)) >> 16;  // RNE
  return (ushort)r;
}
__device__ inline float bf2f(ushort h) { return __uint_as_float(((uint)h) << 16); }

#define GLL16(gsrc, ldst)                                               \
  __builtin_amdgcn_global_load_lds(                                     \
      (const __attribute__((address_space(1))) void*)(gsrc),            \
      (__attribute__((address_space(3))) void*)(ldst), 16, 0, 0)

// ---------------- conv1: fp32 direct, writes blocked pre-BN bf16 hi/lo ----
// + BN stats folded in (atomicAdd into stats[0..127]=sum, [128..255]=sumsq)
__global__ __launch_bounds__(256) void conv1_k(
    const float* __restrict__ in, const float* __restrict__ w,
    ushort* __restrict__ oh, ushort* __restrict__ ol,
    float* __restrict__ stats)
{
  constexpr int KS = 3, ICC = 3, IHT = 10, IWT = 18;
  const int ocb = blockIdx.z & 3;
  const int b   = blockIdx.z >> 2;
  const int tx0 = blockIdx.x * 16;
  const int ty0 = blockIdx.y * 8;
  const int oc0 = ocb * 32;

  __shared__ float lin[ICC][IHT][IWT];
  __shared__ float lw[ICC][KS * KS][32];
  __shared__ float b1sum[32], b1sq[32];

  const int t  = threadIdx.x;
  const int pq = t & 3;
  const int ty = (t >> 2) & 7;
  const int oq = t >> 5;

  float acc[4][4];
#pragma unroll
  for (int m = 0; m < 4; ++m)
#pragma unroll
    for (int j = 0; j < 4; ++j) acc[m][j] = 0.f;

  const int gx0 = tx0 - 1;
  const int gy0 = ty0 - 1;

  for (int e = t; e < ICC * IHT * IWT; e += 256) {
    int ic = e / (IHT * IWT);
    int rr = e % (IHT * IWT);
    int ey = rr / IWT, ex = rr % IWT;
    int gy = gy0 + ey, gx = gx0 + ex;
    float v = 0.f;
    if ((unsigned)gy < 128u && (unsigned)gx < 128u)
      v = in[((size_t)(b * 3 + ic) * 128 + gy) * 128 + gx];
    lin[ic][ey][ex] = v;
  }
  for (int e = t; e < ICC * 9 * 32; e += 256) {
    int ocl = e & 31;
    int rr  = e >> 5;
    int kk  = rr % 9;
    int ic  = rr / 9;
    lw[ic][kk][ocl] = w[((size_t)(oc0 + ocl) * 3 + ic) * 9 + kk];
  }
  __syncthreads();

  for (int ic = 0; ic < ICC; ++ic) {
#pragma unroll
    for (int ky = 0; ky < KS; ++ky) {
#pragma unroll
      for (int kx = 0; kx < KS; ++kx) {
        float xv[4];
#pragma unroll
        for (int j = 0; j < 4; ++j)
          xv[j] = lin[ic][ty + ky][pq * 4 + j + kx];
        const float4 w4 = *(const float4*)&lw[ic][ky * KS + kx][oq * 4];
#pragma unroll
        for (int j = 0; j < 4; ++j) {
          acc[0][j] = fmaf(w4.x, xv[j], acc[0][j]);
          acc[1][j] = fmaf(w4.y, xv[j], acc[1][j]);
          acc[2][j] = fmaf(w4.z, xv[j], acc[2][j]);
          acc[3][j] = fmaf(w4.w, xv[j], acc[3][j]);
        }
      }
    }
  }

  const int oy = ty0 + ty;
  const int oc0q = oc0 + oq * 4;
  const size_t icb = oc0q >> 3;
  const int off = oc0q & 7;
  float sm[4] = {0.f, 0.f, 0.f, 0.f}, qm[4] = {0.f, 0.f, 0.f, 0.f};
#pragma unroll
  for (int j = 0; j < 4; ++j) {
    int px = tx0 + pq * 4 + j;
    size_t pxg = ((size_t)b * 128 + oy) * 128 + px;
    size_t addr = (icb * 131072 + pxg) * 8 + off;
    ushort h0 = f2bf(acc[0][j]); ushort l0 = f2bf(acc[0][j] - bf2f(h0));
    ushort h1 = f2bf(acc[1][j]); ushort l1 = f2bf(acc[1][j] - bf2f(h1));
    ushort h2 = f2bf(acc[2][j]); ushort l2 = f2bf(acc[2][j] - bf2f(h2));
    ushort h3 = f2bf(acc[3][j]); ushort l3 = f2bf(acc[3][j] - bf2f(h3));
    uint2 uh; uh.x = (uint)h0 | ((uint)h1 << 16); uh.y = (uint)h2 | ((uint)h3 << 16);
    uint2 ul; ul.x = (uint)l0 | ((uint)l1 << 16); ul.y = (uint)l2 | ((uint)l3 << 16);
    *(uint2*)(oh + addr) = uh;
    *(uint2*)(ol + addr) = ul;
    float v0 = bf2f(h0) + bf2f(l0), v1 = bf2f(h1) + bf2f(l1);
    float v2 = bf2f(h2) + bf2f(l2), v3 = bf2f(h3) + bf2f(l3);
    sm[0] += v0; qm[0] += v0 * v0;
    sm[1] += v1; qm[1] += v1 * v1;
    sm[2] += v2; qm[2] += v2 * v2;
    sm[3] += v3; qm[3] += v3 * v3;
  }
  // reduce across the 32 lanes sharing oq
#pragma unroll
  for (int o = 16; o > 0; o >>= 1) {
#pragma unroll
    for (int m = 0; m < 4; ++m) {
      sm[m] += __shfl_xor(sm[m], o);
      qm[m] += __shfl_xor(qm[m], o);
    }
  }
  if ((t & 31) == 0) {
#pragma unroll
    for (int m = 0; m < 4; ++m) { b1sum[oq * 4 + m] = sm[m]; b1sq[oq * 4 + m] = qm[m]; }
  }
  __syncthreads();
  if (t < 32) {
    atomicAdd(&stats[oc0 + t], b1sum[t]);
    atomicAdd(&stats[128 + oc0 + t], b1sq[t]);
  }
}

// ---- in-place BN+LReLU on blocked bf16 hi/lo x1 (fin inline) ----
__global__ __launch_bounds__(256) void bn_apply_x1_k(
    ushort* __restrict__ xh, ushort* __restrict__ xl,
    const float* __restrict__ stats, const float* __restrict__ g,
    const float* __restrict__ bt)
{
  __shared__ float scs[128], sfs[128];
  const int t = threadIdx.x;
  if (t < 128) {
    float m = stats[t] * (1.f / 131072.f);
    float v = stats[128 + t] * (1.f / 131072.f) - m * m;
    float rs = rsqrtf(v + 1e-5f);
    float sc = g[t] * rs;
    scs[t] = sc; sfs[t] = bt[t] - m * sc;
  }
  __syncthreads();
  const size_t total = (size_t)16 * 131072;
  const size_t stride = (size_t)gridDim.x * 256;
  for (size_t i = (size_t)blockIdx.x * 256 + t; i < total; i += stride) {
    int j = (int)(i >> 17);
    int c0 = j * 8;
    uint4 vh = *(const uint4*)(xh + i * 8);
    uint4 vl = *(const uint4*)(xl + i * 8);
    uint hw[4] = {vh.x, vh.y, vh.z, vh.w};
    uint lw[4] = {vl.x, vl.y, vl.z, vl.w};
    uint ohv[4], olv[4];
#pragma unroll
    for (int m = 0; m < 4; ++m) {
      float f0 = __uint_as_float(hw[m] << 16) + __uint_as_float(lw[m] << 16);
      float f1 = __uint_as_float(hw[m] & 0xffff0000u) + __uint_as_float(lw[m] & 0xffff0000u);
      float a0 = fmaf(f0, scs[c0 + 2*m],   sfs[c0 + 2*m]);   a0 = fmaxf(a0, 0.1f * a0);
      float a1 = fmaf(f1, scs[c0 + 2*m+1], sfs[c0 + 2*m+1]); a1 = fmaxf(a1, 0.1f * a1);
      ushort h0 = f2bf(a0), l0 = f2bf(a0 - bf2f(h0));
      ushort h1 = f2bf(a1), l1 = f2bf(a1 - bf2f(h1));
      ohv[m] = (uint)h0 | ((uint)h1 << 16);
      olv[m] = (uint)l0 | ((uint)l1 << 16);
    }
    uint4 rh = {ohv[0], ohv[1], ohv[2], ohv[3]};
    uint4 rl = {olv[0], olv[1], olv[2], olv[3]};
    *(uint4*)(xh + i * 8) = rh;
    *(uint4*)(xl + i * 8) = rl;
  }
}

__global__ __launch_bounds__(256) void bn_stats_nhwc_k(
    const float* __restrict__ x, float* __restrict__ stats,
    int cmask, int lg2c, int totpx)
{
  int g = blockIdx.x * 256 + threadIdx.x;
  int c = g & cmask;
  int p0 = g >> lg2c;
  int stride = (gridDim.x * 256) >> lg2c;
  float s = 0.f, q = 0.f;
  for (int p = p0; p < totpx; p += stride) {
    float v = x[((size_t)p << lg2c) | c];
    s += v; q += v * v;
  }
  atomicAdd(&stats[c], s);
  atomicAdd(&stats[cmask + 1 + c], q);
}

// ---- BN+LReLU+split fp32 NHWC -> blocked bf16 hi/lo (inline fin) ----
template<int C>
__global__ __launch_bounds__(256) void split_blocked_k(
    const float* __restrict__ h, const float* __restrict__ stats,
    const float* __restrict__ g, const float* __restrict__ bt, float inv_n,
    ushort* __restrict__ oh, ushort* __restrict__ ol, int totpx)
{
  __shared__ ushort lh[16][C + 8], ll[16][C + 8];
  __shared__ float scs[C], sfs[C];
  const int px0 = blockIdx.x * 16;
  const int t = threadIdx.x;
  if (t < C) {
    float m = stats[t] * inv_n;
    float v = stats[C + t] * inv_n - m * m;
    float rs = rsqrtf(v + 1e-5f);
    float sc = g[t] * rs;
    scs[t] = sc; sfs[t] = bt[t] - m * sc;
  }
  __syncthreads();
  for (int e = t; e < 16 * C / 4; e += 256) {
    int px = e / (C / 4);
    int c0 = (e % (C / 4)) * 4;
    float4 v  = *(const float4*)(h + (size_t)(px0 + px) * C + c0);
    float a0 = fmaf(v.x, scs[c0],   sfs[c0]);   a0 = fmaxf(a0, 0.1f * a0);
    float a1 = fmaf(v.y, scs[c0+1], sfs[c0+1]); a1 = fmaxf(a1, 0.1f * a1);
    float a2 = fmaf(v.z, scs[c0+2], sfs[c0+2]); a2 = fmaxf(a2, 0.1f * a2);
    float a3 = fmaf(v.w, scs[c0+3], sfs[c0+3]); a3 = fmaxf(a3, 0.1f * a3);
    ushort h0 = f2bf(a0), h1 = f2bf(a1), h2v = f2bf(a2), h3v = f2bf(a3);
    lh[px][c0]   = h0;  ll[px][c0]   = f2bf(a0 - bf2f(h0));
    lh[px][c0+1] = h1;  ll[px][c0+1] = f2bf(a1 - bf2f(h1));
    lh[px][c0+2] = h2v; ll[px][c0+2] = f2bf(a2 - bf2f(h2v));
    lh[px][c0+3] = h3v; ll[px][c0+3] = f2bf(a3 - bf2f(h3v));
  }
  __syncthreads();
  for (int e = t; e < 16 * (C / 8); e += 256) {
    int j = e >> 4, px = e & 15;
    *(uint4*)(oh + ((size_t)j * totpx + px0 + px) * 8) = *(const uint4*)&lh[px][j * 8];
    *(uint4*)(ol + ((size_t)j * totpx + px0 + px) * 8) = *(const uint4*)&ll[px][j * 8];
  }
}

// ------- all weight splits merged; FRAGMENT-ORDERED layouts -------
__global__ void wsplit_all_k(
    const float* __restrict__ c2w, const float* __restrict__ c3w,
    const float* __restrict__ c4w, const float* __restrict__ c5w,
    ushort* __restrict__ wph, ushort* __restrict__ wpl,
    ushort* __restrict__ w3h, ushort* __restrict__ w3l,
    ushort* __restrict__ w4h, ushort* __restrict__ w4l,
    ushort* __restrict__ w5h, ushort* __restrict__ w5l)
{
  int i = blockIdx.x * 256 + threadIdx.x;
  if (i < 294912) {
    int kk = i % 9; int r = i / 9; int ic = r & 127; int oc = r >> 7;
    float v = c2w[i];
    ushort hi = f2bf(v), lo = f2bf(v - bf2f(hi));
    int ohf = oc >> 7, of = (oc >> 4) & 7, lr = oc & 15;
    int ic32 = ic >> 5, kg = (ic >> 3) & 3, ici = ic & 7;
    size_t d = ((((size_t)(kk * 4 + ic32) * 2 + ohf) * 8 + of) * 4 + kg) * 128
               + lr * 8 + ici;
    wph[d] = hi; wpl[d] = lo;
    return;
  }
  i -= 294912;
  const float* w; ushort *wh, *wl; int OC, IC, n;
  if (i < 262144)      { w = c3w; wh = w3h; wl = w3l; OC = 64;  IC = 256; n = i; }
  else if (i < 393216) { w = c4w; wh = w4h; wl = w4l; OC = 128; IC = 64;  n = i - 262144; }
  else if (i < 917504) { w = c5w; wh = w5h; wl = w5l; OC = 256; IC = 128; n = i - 393216; }
  else return;
  int kx = n & 3, ky = (n >> 2) & 3;
  int ic = (n >> 4) % IC, oc = (n >> 4) / IC;
  float v = w[n];
  ushort hi = f2bf(v), lo = f2bf(v - bf2f(hi));
  int NCH = IC >> 3, NWO = OC >> 6;
  int wo = oc >> 6, of = (oc >> 4) & 3, lr = oc & 15;
  int ch = ic >> 3, ici = ic & 7;
  size_t d = ((((size_t)(ky * NCH + ch) * NWO + wo) * 4 + of) * 4 + kx) * 128
             + lr * 8 + ici;
  wh[d] = hi; wl[d] = lo;
}

// ---- conv2 X staging: async global->LDS, byte-verbatim (x1 already BN'd) ----
__device__ __forceinline__ void stage_x(
    const ushort* __restrict__ x1h, const ushort* __restrict__ x1l,
    const ushort* __restrict__ zbuf,
    ushort* xh_dst, ushort* xl_dst, int t, int b, int gy, int ic32)
{
  const bool rowok = (unsigned)gy < 128u;
  const size_t rowb = ((size_t)b * 128 + (rowok ? gy : 0)) * 128;
#pragma unroll
  for (int k = 0; k < 2; ++k) {
    int e = t + k * 256;
    int icg = e / 130;
    int xi = e - icg * 130;
    int gx = xi - 1;
    const ushort* sh = zbuf;
    const ushort* sl = zbuf;
    if (rowok && (unsigned)gx < 128u) {
      size_t gi = ((size_t)(ic32 * 4 + icg) * 131072 + rowb + gx) * 8;
      sh = x1h + gi; sl = x1l + gi;
    }
    GLL16(sh, xh_dst + (size_t)e * 8);
    GLL16(sl, xl_dst + (size_t)e * 8);
  }
  if (t < 8) {
    int e = 512 + t;
    int xi = e - 390;          // icg = 3
    int gx = xi - 1;
    const ushort* sh = zbuf;
    const ushort* sl = zbuf;
    if (rowok && (unsigned)gx < 128u) {
      size_t gi = ((size_t)(ic32 * 4 + 3) * 131072 + rowb + gx) * 8;
      sh = x1h + gi; sl = x1l + gi;
    }
    GLL16(sh, xh_dst + (size_t)e * 8);
    GLL16(sl, xl_dst + (size_t)e * 8);
  }
}

// ------- conv2 via MFMA (bf16x3): async dbuf X staging, W from global -------
// 1 row x 128 px x 256 oc per block; XCD swizzle; stats fold-in epilogue.
__global__ __launch_bounds__(256, 2) void conv2_mfma_k(
    const ushort* __restrict__ x1h, const ushort* __restrict__ x1l,
    const ushort* __restrict__ wph, const ushort* __restrict__ wpl,
    const ushort* __restrict__ zbuf, float* __restrict__ stats2,
    ushort* __restrict__ x3h, ushort* __restrict__ x3l)
{
  const int bid = blockIdx.x;                 // 1024 blocks
  const int wid = (bid & 7) * 128 + (bid >> 3);
  const int y0  = wid & 127;
  const int b   = wid >> 7;

  __shared__ ushort xs[2][2][4][130][8];   // [buf][hl][icg][xi][8] : 33,280 B
  __shared__ float bsum[2][256], bsq[2][256];

  const int t = threadIdx.x;
  const int w  = t >> 6;
  const int l  = t & 63;
  const int xhf = w & 1;
  const int ohf = w >> 1;
  const int lr = l & 15;
  const int kg = l >> 4;

  f32x4 acc[8][4];
#pragma unroll
  for (int i = 0; i < 8; ++i)
#pragma unroll
    for (int j = 0; j < 4; ++j) acc[i][j] = (f32x4){0.f, 0.f, 0.f, 0.f};

  // prologue: stage phase 0 into buf 0
  stage_x(x1h, x1l, zbuf, (ushort*)&xs[0][0][0][0][0], (ushort*)&xs[0][1][0][0][0],
          t, b, y0 - 1, 0);
  __syncthreads();

  for (int ky = 0; ky < 3; ++ky) {
    for (int ic32 = 0; ic32 < 4; ++ic32) {
      const int buf = ic32 & 1;     // p = ky*4+ic32, ky*4 even
      // issue next phase's loads (async; drained by this phase's end barrier)
      const int np = ky * 4 + ic32 + 1;
      if (np < 12) {
        const int nbuf = buf ^ 1;
        stage_x(x1h, x1l, zbuf,
                (ushort*)&xs[nbuf][0][0][0][0], (ushort*)&xs[nbuf][1][0][0][0],
                t, b, y0 + (np >> 2) - 1, np & 3);
      }
#pragma unroll
      for (int kx = 0; kx < 3; ++kx) {
        const int kk = ky * 3 + kx;
        const size_t wbase =
            ((size_t)((kk * 4 + ic32) * 2 + ohf)) * 4096 + (size_t)l * 8;
        const ushort* pwh = wph + wbase;
        const ushort* pwl = wpl + wbase;

        bf16x8 xbh[4], xbl[4];
#pragma unroll
        for (int pf = 0; pf < 4; ++pf) {
          int xi = xhf * 64 + pf * 16 + lr + kx;
          xbh[pf] = *(const bf16x8*)&xs[buf][0][kg][xi][0];
          xbl[pf] = *(const bf16x8*)&xs[buf][1][kg][xi][0];
        }
#pragma unroll
        for (int oh2 = 0; oh2 < 2; ++oh2) {
          bf16x8 awh[4], awl[4];
#pragma unroll
          for (int o4 = 0; o4 < 4; ++o4) {
            awh[o4] = *(const bf16x8*)(pwh + (oh2 * 4 + o4) * 512);
            awl[o4] = *(const bf16x8*)(pwl + (oh2 * 4 + o4) * 512);
          }
#pragma unroll
          for (int o4 = 0; o4 < 4; ++o4) {
            const int of = oh2 * 4 + o4;
#pragma unroll
            for (int pf = 0; pf < 4; ++pf) {
              acc[of][pf] = __builtin_amdgcn_mfma_f32_16x16x32_bf16(awh[o4], xbh[pf], acc[of][pf], 0, 0, 0);
              acc[of][pf] = __builtin_amdgcn_mfma_f32_16x16x32_bf16(awh[o4], xbl[pf], acc[of][pf], 0, 0, 0);
              acc[of][pf] = __builtin_amdgcn_mfma_f32_16x16x32_bf16(awl[o4], xbh[pf], acc[of][pf], 0, 0, 0);
            }
          }
        }
      }
      __syncthreads();   // drains next-phase global_load_lds, syncs LDS reuse
    }
  }

  // epilogue: quantize+store + per-oc stats (sum over px, shfl-reduced)
#pragma unroll
  for (int of = 0; of < 8; ++of) {
    float s4[4] = {0.f, 0.f, 0.f, 0.f}, q4[4] = {0.f, 0.f, 0.f, 0.f};
#pragma unroll
    for (int pf = 0; pf < 4; ++pf) {
      int oc = ohf * 128 + of * 16 + kg * 4;
      int x  = xhf * 64 + pf * 16 + lr;
      size_t pxg = ((size_t)b * 128 + y0) * 128 + x;
      size_t base = ((size_t)(oc >> 3) * 131072 + pxg) * 8 + (oc & 7);
      f32x4 a = acc[of][pf];
      ushort h0 = f2bf(a[0]); ushort l0 = f2bf(a[0] - bf2f(h0));
      ushort h1 = f2bf(a[1]); ushort l1 = f2bf(a[1] - bf2f(h1));
      ushort h2 = f2bf(a[2]); ushort l2 = f2bf(a[2] - bf2f(h2));
      ushort h3 = f2bf(a[3]); ushort l3 = f2bf(a[3] - bf2f(h3));
      uint2 uh; uh.x = (uint)h0 | ((uint)h1 << 16); uh.y = (uint)h2 | ((uint)h3 << 16);
      uint2 ul; ul.x = (uint)l0 | ((uint)l1 << 16); ul.y = (uint)l2 | ((uint)l3 << 16);
      *(uint2*)(x3h + base) = uh;
      *(uint2*)(x3l + base) = ul;
      float v0 = bf2f(h0) + bf2f(l0), v1 = bf2f(h1) + bf2f(l1);
      float v2 = bf2f(h2) + bf2f(l2), v3 = bf2f(h3) + bf2f(l3);
      s4[0] += v0; q4[0] += v0 * v0;
      s4[1] += v1; q4[1] += v1 * v1;
      s4[2] += v2; q4[2] += v2 * v2;
      s4[3] += v3; q4[3] += v3 * v3;
    }
#pragma unroll
    for (int o = 8; o > 0; o >>= 1) {
#pragma unroll
      for (int j = 0; j < 4; ++j) {
        s4[j] += __shfl_xor(s4[j], o);
        q4[j] += __shfl_xor(q4[j], o);
      }
    }
    if (lr == 0) {
      int oc = ohf * 128 + of * 16 + kg * 4;
#pragma unroll
      for (int j = 0; j < 4; ++j) { bsum[xhf][oc + j] = s4[j]; bsq[xhf][oc + j] = q4[j]; }
    }
  }
  __syncthreads();
  if (t < 256) {
    atomicAdd(&stats2[t],       bsum[0][t] + bsum[1][t]);
    atomicAdd(&stats2[256 + t], bsq[0][t] + bsq[1][t]);
  }
}

// ------- conv3/4/5 via MFMA, K-split, W fragments from global -------
template<int IC, int OC, int OH, int OW, int WPX, int CS, bool FBN>
__global__ __launch_bounds__(256, 2) void convs_mfma_k(
    const ushort* __restrict__ xh, const ushort* __restrict__ xl,
    const ushort* __restrict__ wh, const ushort* __restrict__ wl,
    const float* __restrict__ stats, const float* __restrict__ gg,
    const float* __restrict__ bb, float inv_n,
    float* __restrict__ part)
{
  constexpr int IH  = 2 * OH, IW = 2 * OW;
  constexpr int NCH = IC / 8;
  constexpr int NCHB = NCH / CS;
  constexpr int PFX = OW / 16;
  constexpr int RW  = 4 / WPX;
  constexpr int NZ = 4 * CS;
  constexpr int NX = OH / 4;
  constexpr int NWO = OC / 64;
  constexpr int SBN = FBN ? IC : 1;

  const int bid = blockIdx.x;
  const int wid = (bid & 7) * (NZ * NX) + (bid >> 3);
  const int zi = wid % NZ;
  const int y0 = ((wid / NZ) % NX) * 4;
  const int b  = wid / (NZ * NX);
  const int ky = zi & 3;
  const int cs = zi >> 2;

  __shared__ ushort xs[2][4][2][OW + 2][8];
  __shared__ float scs[SBN], sfs[SBN];

  const int t = threadIdx.x;
  if (FBN) {
    for (int c = t; c < IC; c += 256) {
      float m = stats[c] * inv_n;
      float v = stats[IC + c] * inv_n - m * m;
      float rs = rsqrtf(v + 1e-5f);
      float sc = gg[c] * rs;
      scs[c] = sc; sfs[c] = bb[c] - m * sc;
    }
  }

  const int w = t >> 6, l = t & 63;
  const int wo = w / WPX, wp = w % WPX;
  const int lr = l & 15, kg = l >> 4;
  const int oc0w = wo * 64;
  const int rb = wp * RW;

  f32x4 acc[4][4];
#pragma unroll
  for (int i = 0; i < 4; ++i)
#pragma unroll
    for (int j = 0; j < 4; ++j) acc[i][j] = (f32x4){0.f, 0.f, 0.f, 0.f};

  for (int cc = 0; cc < NCHB; ++cc) {
    const int ch = cs * NCHB + cc;
    __syncthreads();
    for (int e = t; e < 4 * (IW + 2); e += 256) {
      int r  = e / (IW + 2);
      int xi = e % (IW + 2);
      int xp = xi - 1;
      int iy = 2 * (y0 + r) + ky - 1;
      uint4 rh = {0, 0, 0, 0}, rl = {0, 0, 0, 0};
      if ((unsigned)iy < (unsigned)IH && (unsigned)xp < (unsigned)IW) {
        size_t gi = ((((size_t)ch * 8 + b) * IH + iy) * IW + xp) * 8;
        uint4 vh = *(const uint4*)(xh + gi);
        uint4 vl = *(const uint4*)(xl + gi);
        if (FBN) {
          int c0 = ch * 8;
          uint hw[4] = {vh.x, vh.y, vh.z, vh.w};
          uint lw[4] = {vl.x, vl.y, vl.z, vl.w};
          uint ohv[4], olv[4];
#pragma unroll
          for (int m = 0; m < 4; ++m) {
            float f0 = __uint_as_float(hw[m] << 16) + __uint_as_float(lw[m] << 16);
            float f1 = __uint_as_float(hw[m] & 0xffff0000u) + __uint_as_float(lw[m] & 0xffff0000u);
            float a0 = fmaf(f0, scs[c0 + 2*m],   sfs[c0 + 2*m]);   a0 = fmaxf(a0, 0.1f * a0);
            float a1 = fmaf(f1, scs[c0 + 2*m+1], sfs[c0 + 2*m+1]); a1 = fmaxf(a1, 0.1f * a1);
            ushort h0 = f2bf(a0), l0 = f2bf(a0 - bf2f(h0));
            ushort h1 = f2bf(a1), l1 = f2bf(a1 - bf2f(h1));
            ohv[m] = (uint)h0 | ((uint)h1 << 16);
            olv[m] = (uint)l0 | ((uint)l1 << 16);
          }
          rh.x = ohv[0]; rh.y = ohv[1]; rh.z = ohv[2]; rh.w = ohv[3];
          rl.x = olv[0]; rl.y = olv[1]; rl.z = olv[2]; rl.w = olv[3];
        } else {
          rh = vh; rl = vl;
        }
      }
      int par = xp & 1;
      int idx = (xp + 1) >> 1;
      *(uint4*)&xs[0][r][par][idx][0] = rh;
      *(uint4*)&xs[1][r][par][idx][0] = rl;
    }
    __syncthreads();

    const size_t wbase =
        ((size_t)(ky * NCH + ch) * NWO + wo) * 2048 + (size_t)l * 8;
    bf16x8 ah[4], al[4], bh[4], bl[4];
#pragma unroll
    for (int of = 0; of < 4; ++of) {
      ah[of] = *(const bf16x8*)(wh + wbase + of * 512);
      al[of] = *(const bf16x8*)(wl + wbase + of * 512);
    }
    const int par = 1 - (kg & 1);
    const int xoff = kg >> 1;
#pragma unroll
    for (int pf = 0; pf < 4; ++pf) {
      int row = rb + pf / PFX;
      int x   = (pf % PFX) * 16 + lr;
      bh[pf] = *(const bf16x8*)&xs[0][row][par][x + xoff][0];
      bl[pf] = *(const bf16x8*)&xs[1][row][par][x + xoff][0];
    }
#pragma unroll
    for (int of = 0; of < 4; ++of) {
#pragma unroll
      for (int pf = 0; pf < 4; ++pf) {
        acc[of][pf] = __builtin_amdgcn_mfma_f32_16x16x32_bf16(ah[of], bh[pf], acc[of][pf], 0, 0, 0);
        acc[of][pf] = __builtin_amdgcn_mfma_f32_16x16x32_bf16(ah[of], bl[pf], acc[of][pf], 0, 0, 0);
        acc[of][pf] = __builtin_amdgcn_mfma_f32_16x16x32_bf16(al[of], bh[pf], acc[of][pf], 0, 0, 0);
      }
    }
  }

  float* yp = part + (size_t)zi * (8 * OH * OW * OC);
#pragma unroll
  for (int of = 0; of < 4; ++of) {
#pragma unroll
    for (int pf = 0; pf < 4; ++pf) {
      int row = rb + pf / PFX;
      int x   = (pf % PFX) * 16 + lr;
      int oc  = oc0w + of * 16 + kg * 4;
      float* p = yp + (((size_t)b * OH + y0 + row) * OW + x) * OC + oc;
      f32x4 a = acc[of][pf];
      float4 v = {a[0], a[1], a[2], a[3]};
      *(float4*)p = v;
    }
  }
}

// ------- reduce partials -> h (float4) -------
__global__ __launch_bounds__(256) void reduce_k(
    const float* __restrict__ part, float* __restrict__ h,
    int n4, int nparts)
{
  int i = blockIdx.x * 256 + threadIdx.x;
  if (i >= n4) return;
  float4 a = ((const float4*)part)[i];
  for (int z = 1; z < nparts; ++z) {
    float4 b = ((const float4*)part)[(size_t)z * n4 + i];
    a.x += b.x; a.y += b.y; a.z += b.z; a.w += b.w;
  }
  ((float4*)h)[i] = a;
}

// ---------------- capsule rearrange (h5 NHWC, BN inline) ----------------
__global__ void caps_k(const float* __restrict__ h5, const float* __restrict__ stats,
                       const float* __restrict__ g5, const float* __restrict__ b5,
                       float* __restrict__ caps)
{
  int e = blockIdx.x * 256 + threadIdx.x;
  if (e >= NB * NCAP * 8) return;
  int ii = e & 7;
  int n  = (e >> 3) & 511;
  int jb = e >> 12;
  int j = jb >> 3, b = jb & 7;
  int i = n >> 7, k = (n >> 5) & 3, ch = ((n & 31) << 3) | ii;
  int hh = (i << 2) | (j >> 2);
  int ww = ((j & 3) << 2) | k;
  float m  = stats[ch] * (1.f / 2048.f);
  float vv = stats[256 + ch] * (1.f / 2048.f) - m * m;
  float rs = rsqrtf(vv + 1e-5f);
  float sc = g5[ch] * rs;
  float sf = b5[ch] - m * sc;
  float v = h5[(((size_t)b * 16 + hh) * 16 + ww) * 256 + ch];
  float a = fmaf(v, sc, sf);
  a = fmaxf(a, 0.1f * a);
  caps[e] = a;
}

// ---------------- priors (bf16 output) ----------------
__global__ __launch_bounds__(256) void priors_k(
    const float* __restrict__ caps, const float* __restrict__ rw,
    ushort* __restrict__ priors)
{
  const int n = blockIdx.x;
  __shared__ float lrw[NCLS * 8 * NO];
  __shared__ float lc[NB * 8];
  const int t = threadIdx.x;
  for (int e = t; e < NCLS * 8 * NO; e += 256)
    lrw[e] = rw[(size_t)n * NCLS * 8 * NO + e];
  for (int e = t; e < NB * 8; e += 256) {
    int b = e >> 3, ii = e & 7;
    lc[e] = caps[((size_t)b * NCAP + n) * 8 + ii];
  }
  __syncthreads();

  int p[4], kk[4], oo[4];
#pragma unroll
  for (int q = 0; q < 4; ++q) {
    p[q]  = t + q * 256;
    kk[q] = (p[q] < KO) ? p[q] / NO : 0;
    oo[q] = (p[q] < KO) ? p[q] % NO : 0;
  }
  for (int b = 0; b < NB; ++b) {
    const float* cb = &lc[b * 8];
    float c0 = cb[0], c1 = cb[1], c2 = cb[2], c3 = cb[3];
    float c4 = cb[4], c5 = cb[5], c6 = cb[6], c7 = cb[7];
    ushort* pout = priors + ((size_t)b * NCAP + n) * KO;
#pragma unroll
    for (int q = 0; q < 4; ++q) {
      if (p[q] < KO) {
        const float* wv = &lrw[kk[q] * (8 * NO) + oo[q]];
        float a = c0 * wv[0];
        a = fmaf(c1, wv[21],  a);
        a = fmaf(c2, wv[42],  a);
        a = fmaf(c3, wv[63],  a);
        a = fmaf(c4, wv[84],  a);
        a = fmaf(c5, wv[105], a);
        a = fmaf(c6, wv[126], a);
        a = fmaf(c7, wv[147], a);
        pout[p[q]] = f2bf(a);
      }
    }
  }
}

// ---------------- routing ----------------
__global__ __launch_bounds__(256) void route_s_partial(
    const ushort* __restrict__ priors, float* __restrict__ s)
{
  const int b  = blockIdx.x >> 3;
  const int ns = blockIdx.x & 7;
  const int t  = threadIdx.x;
  const int p0 = t, p1 = t + 256, p2 = t + 512, p3 = t + 768;
  float a0 = 0.f, a1 = 0.f, a2 = 0.f, a3 = 0.f;
  const ushort* pb = priors + ((size_t)b * NCAP + ns * 64) * KO;
#pragma unroll 2
  for (int n = 0; n < 64; ++n) {
    const ushort* pn = pb + (size_t)n * KO;
    a0 += bf2f(pn[p0]); a1 += bf2f(pn[p1]); a2 += bf2f(pn[p2]);
    if (p3 < KO) a3 += bf2f(pn[p3]);
  }
  const float sc = 1.f / 43.f;
  atomicAdd(&s[b * KO + p0], a0 * sc);
  atomicAdd(&s[b * KO + p1], a1 * sc);
  atomicAdd(&s[b * KO + p2], a2 * sc);
  if (p3 < KO) atomicAdd(&s[b * KO + p3], a3 * sc);
}

// fused logits+softmax+s, wave-parallel over n
__global__ __launch_bounds__(256) void route_iter_k(
    const ushort* __restrict__ priors, const float* __restrict__ souts,
    float* __restrict__ logits, float* __restrict__ s,
    int readPrev, int writeL)
{
  const int b  = blockIdx.x >> 3;
  const int ns = blockIdx.x & 7;
  const int t  = threadIdx.x;
  const int w  = t >> 6;
  const int lane = t & 63;

  __shared__ float so_l[KO];
  __shared__ float sacc[4][KO];
  __shared__ float prow[4][KO];
  __shared__ float pk[4][NCLS];

  for (int e = t; e < KO; e += 256) so_l[e] = souts[b * KO + e];
  for (int e = lane; e < KO; e += 64) sacc[w][e] = 0.f;

  int kq[15];
#pragma unroll
  for (int q = 0; q < 15; ++q) {
    int e = lane + q * 64;
    kq[q] = (e < KO) ? e / NO : 0;
  }
  __syncthreads();

  for (int nn = 0; nn < 16; ++nn) {
    const int n = ns * 64 + w * 16 + nn;
    const ushort* pr = priors + ((size_t)(b * NCAP + n)) * KO;
    float v[15];
#pragma unroll
    for (int q = 0; q < 15; ++q) {
      int e = lane + q * 64;
      if (e < KO) { v[q] = bf2f(pr[e]); prow[w][e] = v[q]; }
      else v[q] = 0.f;
    }
    __syncthreads();

    float L = -1e30f;
    if (lane < NCLS) {
      float d = 0.f;
      const float* pp = &prow[w][lane * NO];
      const float* ss = &so_l[lane * NO];
#pragma unroll
      for (int o = 0; o < NO; ++o) d = fmaf(pp[o], ss[o], d);
      size_t lidx = ((size_t)(b * NCAP + n)) * NCLS + lane;
      L = (readPrev ? logits[lidx] : 0.f) + d;
      if (writeL) logits[lidx] = L;
    }
    float m = L;
#pragma unroll
    for (int off = 32; off > 0; off >>= 1) m = fmaxf(m, __shfl_xor(m, off));
    float ex = (lane < NCLS) ? __expf(L - m) : 0.f;
    float sm = ex;
#pragma unroll
    for (int off = 32; off > 0; off >>= 1) sm += __shfl_xor(sm, off);
    if (lane < NCLS) pk[w][lane] = ex / sm;
    __syncthreads();

#pragma unroll
    for (int q = 0; q < 15; ++q) {
      int e = lane + q * 64;
      if (e < KO) sacc[w][e] += pk[w][kq[q]] * v[q];
    }
  }
  __syncthreads();
  for (int e = t; e < KO; e += 256)
    atomicAdd(&s[b * KO + e], sacc[0][e] + sacc[1][e] + sacc[2][e] + sacc[3][e]);
}

__global__ void squash_k(const float* __restrict__ s, float* __restrict__ souts)
{
  int i = blockIdx.x * 256 + threadIdx.x;
  if (i >= NB * NCLS) return;
  int b = i / NCLS, k = i % NCLS;
  const float* sv = s + b * KO + k * NO;
  float sn = 0.f;
#pragma unroll
  for (int o = 0; o < NO; ++o) sn += sv[o] * sv[o];
  float f = sqrtf(sn) / (1.f + sn);
  float* ov = souts + b * KO + k * NO;
#pragma unroll
  for (int o = 0; o < NO; ++o) ov[o] = sv[o] * f;
}

__global__ void out_k(const float* __restrict__ souts, float* __restrict__ out)
{
  int i = blockIdx.x * 256 + threadIdx.x;
  if (i >= 8 * 16 * NCLS * NO) return;
  int o = i % NO;
  int r = i / NO;
  int k = r % NCLS; r /= NCLS;
  int g1 = r & 3; r >>= 2;
  int g0 = r & 3;
  int b  = r >> 2;
  int j  = g0 * 4 + g1;
  int jb = j * 8 + b;
  out[i] = souts[jb * KO + k * NO + o];
}

// ---------------- launcher ----------------
extern "C" void kernel_launch(void* const* d_in, const int* in_sizes, int n_in,
                              void* d_out, int out_size, void* d_ws, size_t ws_size,
                              hipStream_t stream)
{
  const float* x   = (const float*)d_in[0];
  const float* c1w = (const float*)d_in[1];
  const float* g1  = (const float*)d_in[3];  const float* b1  = (const float*)d_in[4];
  const float* c2w = (const float*)d_in[5];
  const float* g2  = (const float*)d_in[7];  const float* b2  = (const float*)d_in[8];
  const float* c3w = (const float*)d_in[9];
  const float* g3  = (const float*)d_in[11]; const float* b3  = (const float*)d_in[12];
  const float* c4w = (const float*)d_in[13];
  const float* g4  = (const float*)d_in[15]; const float* b4  = (const float*)d_in[16];
  const float* c5w = (const float*)d_in[17];
  const float* g5  = (const float*)d_in[19]; const float* b5  = (const float*)d_in[20];
  const float* rw  = (const float*)d_in[21];

  float* ws  = (float*)d_ws;
  float* out = (float*)d_out;

  ushort* x1h = (ushort*)(ws + F_X1H);
  ushort* x1l = (ushort*)(ws + F_X1L);
  ushort* wph = (ushort*)(ws + F_WPH);
  ushort* wpl = (ushort*)(ws + F_WPL);
  ushort* w3h = (ushort*)(ws + F_W3H);
  ushort* w3l = (ushort*)(ws + F_W3L);
  ushort* w4h = (ushort*)(ws + F_W4H);
  ushort* w4l = (ushort*)(ws + F_W4L);
  ushort* w5h = (ushort*)(ws + F_W5H);
  ushort* w5l = (ushort*)(ws + F_W5L);
  ushort* x3h = (ushort*)(ws + F_X3H);
  ushort* x3l = (ushort*)(ws + F_X3L);
  ushort* x4h = (ushort*)(ws + F_X4H);
  ushort* x4l = (ushort*)(ws + F_X4L);
  ushort* x5h = (ushort*)(ws + F_X5H);
  ushort* x5l = (ushort*)(ws + F_X5L);
  float* part   = ws + F_PART;
  float* h3     = ws + F_H3;
  float* h4     = ws + F_H4;
  float* h5     = ws + F_H5;
  float* caps   = ws + F_CAPS;
  ushort* priors = (ushort*)(ws + F_PRI);
  float* logits = ws + F_LOG;
  float* sbuf   = ws + F_S;
  float* souts  = ws + F_OUTS;
  float* stats  = ws + F_STAT;          // conv1 stats [0..255]; scratch [0..511]
  float* stats2 = ws + F_STAT + 512;    // conv2 stats [0..511]
  ushort* zbuf  = (ushort*)(ws + F_ZERO);

  // ---- init: zero stats (conv1+conv2 atomics) and the OOB zero stub ----
  hipMemsetAsync(stats, 0, 1024 * sizeof(float), stream);
  hipMemsetAsync(zbuf, 0, 64, stream);

  // ---- weight preps (merged, fragment-ordered) ----
  wsplit_all_k<<<(1212416 + 255) / 256, 256, 0, stream>>>(
      c2w, c3w, c4w, c5w, wph, wpl, w3h, w3l, w4h, w4l, w5h, w5l);

  // ---- conv1 -> blocked pre-BN bf16 hi/lo (stats folded in) ----
  conv1_k<<<dim3(8, 16, 32), 256, 0, stream>>>(x, c1w, x1h, x1l, stats);

  // ---- BN+LReLU applied in place to x1 ----
  bn_apply_x1_k<<<2048, 256, 0, stream>>>(x1h, x1l, stats, g1, b1);

  // ---- conv2 (MFMA, async dbuf staging, W from global, XCD swizzle) ----
  conv2_mfma_k<<<1024, 256, 0, stream>>>(x1h, x1l, wph, wpl, zbuf, stats2, x3h, x3l);

  // ---- conv3 (MFMA, ky-split x4, BN of x3 fused via stats2) ----
  convs_mfma_k<256, 64, 64, 64, 4, 1, true><<<512, 256, 0, stream>>>(
      x3h, x3l, w3h, w3l, stats2, g2, b2, 1.f / 131072.f, part);
  reduce_k<<<(524288 + 255) / 256, 256, 0, stream>>>(part, h3, 524288, 4);
  hipMemsetAsync(stats, 0, 2 * 64 * sizeof(float), stream);
  bn_stats_nhwc_k<<<256, 256, 0, stream>>>(h3, stats, 63, 6, 32768);
  split_blocked_k<64><<<2048, 256, 0, stream>>>(h3, stats, g3, b3, 1.f / 32768.f, x4h, x4l, 32768);

  // ---- conv4 (MFMA, (ky x ch/2)-split x8) ----
  convs_mfma_k<64, 128, 32, 32, 2, 2, false><<<512, 256, 0, stream>>>(
      x4h, x4l, w4h, w4l, stats, g4, b4, 0.f, part);
  reduce_k<<<(262144 + 255) / 256, 256, 0, stream>>>(part, h4, 262144, 8);
  hipMemsetAsync(stats, 0, 2 * 128 * sizeof(float), stream);
  bn_stats_nhwc_k<<<128, 256, 0, stream>>>(h4, stats, 127, 7, 8192);
  split_blocked_k<128><<<512, 256, 0, stream>>>(h4, stats, g4, b4, 1.f / 8192.f, x5h, x5l, 8192);

  // ---- conv5 (MFMA, (ky x ch/2)-split x8) ----
  convs_mfma_k<128, 256, 16, 16, 1, 2, false><<<256, 256, 0, stream>>>(
      x5h, x5l, w5h, w5l, stats, g5, b5, 0.f, part);
  reduce_k<<<(131072 + 255) / 256, 256, 0, stream>>>(part, h5, 131072, 8);
  hipMemsetAsync(stats, 0, 2 * 256 * sizeof(float), stream);
  bn_stats_nhwc_k<<<64, 256, 0, stream>>>(h5, stats, 255, 8, 2048);

  // ---- capsules ----
  caps_k<<<2048, 256, 0, stream>>>(h5, stats, g5, b5, caps);
  priors_k<<<512, 256, 0, stream>>>(caps, rw, priors);

  // ---- routing: 3 iterations ----
  hipMemsetAsync(sbuf, 0, NB * KO * sizeof(float), stream);
  route_s_partial<<<NB * 8, 256, 0, stream>>>(priors, sbuf);
  squash_k<<<(NB * NCLS + 255) / 256, 256, 0, stream>>>(sbuf, souts);

  hipMemsetAsync(sbuf, 0, NB * KO * sizeof(float), stream);
  route_iter_k<<<NB * 8, 256, 0, stream>>>(priors, souts, logits, sbuf, 0, 1);
  squash_k<<<(NB * NCLS + 255) / 256, 256, 0, stream>>>(sbuf, souts);

  hipMemsetAsync(sbuf, 0, NB * KO * sizeof(float), stream);
  route_iter_k<<<NB * 8, 256, 0, stream>>>(priors, souts, logits, sbuf, 1, 0);
  squash_k<<<(NB * NCLS + 255) / 256, 256, 0, stream>>>(sbuf, souts);

  // ---- final scatter ----
  out_k<<<(8 * 16 * NCLS * NO + 255) / 256, 256, 0, stream>>>(souts, out);
}

// Round 9
// 681.051 us; speedup vs baseline: 1.1195x; 1.0316x over previous
//
#include <hip/hip_runtime.h>
#include <math.h>

typedef unsigned int   uint;
typedef unsigned short ushort;
using bf16x8 = __attribute__((ext_vector_type(8))) __bf16;
using f32x4  = __attribute__((ext_vector_type(4))) float;

constexpr int NB   = 128;
constexpr int NCAP = 512;
constexpr int NCLS = 43;
constexpr int NO   = 21;
constexpr int KO   = NCLS * NO; // 903

// ---- workspace layout (float offsets) ----
constexpr size_t F_X1H  = 0;          // conv1 out hi, blocked [16][131072][8] bf16
constexpr size_t F_X1L  = 8388608;
constexpr size_t F_PART = 0;          // conv3/4/5 K-split partials (x1 dead)
constexpr size_t F_STAT = 16777216;   // 1,024 floats (conv1 stats [0..255]; stats2 at +512)
constexpr size_t F_WPH  = 16778240;   // conv2 w (147,456)
constexpr size_t F_WPL  = 16925696;
constexpr size_t F_W3H  = 17073152;
constexpr size_t F_W3L  = 17204224;
constexpr size_t F_W4H  = 17335296;
constexpr size_t F_W4L  = 17400832;
constexpr size_t F_W5H  = 17466368;
constexpr size_t F_W5L  = 17728512;
constexpr size_t F_X3H  = 17990656;   // conv2 out hi, blocked [32][131072][8] bf16
constexpr size_t F_X3L  = 34767872;   // ends 51,545,088
constexpr size_t F_H3   = 51545088;   // h3 NHWC fp32 (2,097,152)
constexpr size_t F_X4H  = 53642240;
constexpr size_t F_X4L  = 54690816;
constexpr size_t F_H4   = 55739392;
constexpr size_t F_X5H  = 56787968;
constexpr size_t F_X5L  = 57312256;
constexpr size_t F_H5   = 57836544;   // (524,288)
// routing phase:
constexpr size_t F_PRI  = 0;          // bf16 priors: 59,179,008 ushorts
constexpr size_t F_CAPS = 59179008;   // 524,288
constexpr size_t F_LOG  = 59703296;   // 2,818,048
constexpr size_t F_S    = 65339392;   // 115,584
constexpr size_t F_OUTS = 65454976;   // 115,584 -> ends 65,570,560
constexpr size_t F_ZERO = 65570560;   // 16 floats zero stub for OOB global_load_lds

__device__ inline ushort f2bf(float x) {
  uint u = __float_as_uint(x);
  uint r = (u + 0x7fffu + ((u >> 16) & 1u)) >> 16;  // RNE
  return (ushort)r;
}
__device__ inline float bf2f(ushort h) { return __uint_as_float(((uint)h) << 16); }

#define GLL16(gsrc, ldst)                                               \
  __builtin_amdgcn_global_load_lds(                                     \
      (const __attribute__((address_space(1))) void*)(gsrc),            \
      (__attribute__((address_space(3))) void*)(ldst), 16, 0, 0)

// ---------------- conv1: fp32 direct, writes blocked pre-BN bf16 hi/lo ----
__global__ __launch_bounds__(256) void conv1_k(
    const float* __restrict__ in, const float* __restrict__ w,
    ushort* __restrict__ oh, ushort* __restrict__ ol,
    float* __restrict__ stats)
{
  constexpr int KS = 3, ICC = 3, IHT = 10, IWT = 18;
  const int ocb = blockIdx.z & 3;
  const int b   = blockIdx.z >> 2;
  const int tx0 = blockIdx.x * 16;
  const int ty0 = blockIdx.y * 8;
  const int oc0 = ocb * 32;

  __shared__ float lin[ICC][IHT][IWT];
  __shared__ float lw[ICC][KS * KS][32];
  __shared__ float b1sum[32], b1sq[32];

  const int t  = threadIdx.x;
  const int pq = t & 3;
  const int ty = (t >> 2) & 7;
  const int oq = t >> 5;

  float acc[4][4];
#pragma unroll
  for (int m = 0; m < 4; ++m)
#pragma unroll
    for (int j = 0; j < 4; ++j) acc[m][j] = 0.f;

  const int gx0 = tx0 - 1;
  const int gy0 = ty0 - 1;

  for (int e = t; e < ICC * IHT * IWT; e += 256) {
    int ic = e / (IHT * IWT);
    int rr = e % (IHT * IWT);
    int ey = rr / IWT, ex = rr % IWT;
    int gy = gy0 + ey, gx = gx0 + ex;
    float v = 0.f;
    if ((unsigned)gy < 128u && (unsigned)gx < 128u)
      v = in[((size_t)(b * 3 + ic) * 128 + gy) * 128 + gx];
    lin[ic][ey][ex] = v;
  }
  for (int e = t; e < ICC * 9 * 32; e += 256) {
    int ocl = e & 31;
    int rr  = e >> 5;
    int kk  = rr % 9;
    int ic  = rr / 9;
    lw[ic][kk][ocl] = w[((size_t)(oc0 + ocl) * 3 + ic) * 9 + kk];
  }
  __syncthreads();

  for (int ic = 0; ic < ICC; ++ic) {
#pragma unroll
    for (int ky = 0; ky < KS; ++ky) {
#pragma unroll
      for (int kx = 0; kx < KS; ++kx) {
        float xv[4];
#pragma unroll
        for (int j = 0; j < 4; ++j)
          xv[j] = lin[ic][ty + ky][pq * 4 + j + kx];
        const float4 w4 = *(const float4*)&lw[ic][ky * KS + kx][oq * 4];
#pragma unroll
        for (int j = 0; j < 4; ++j) {
          acc[0][j] = fmaf(w4.x, xv[j], acc[0][j]);
          acc[1][j] = fmaf(w4.y, xv[j], acc[1][j]);
          acc[2][j] = fmaf(w4.z, xv[j], acc[2][j]);
          acc[3][j] = fmaf(w4.w, xv[j], acc[3][j]);
        }
      }
    }
  }

  const int oy = ty0 + ty;
  const int oc0q = oc0 + oq * 4;
  const size_t icb = oc0q >> 3;
  const int off = oc0q & 7;
  float sm[4] = {0.f, 0.f, 0.f, 0.f}, qm[4] = {0.f, 0.f, 0.f, 0.f};
#pragma unroll
  for (int j = 0; j < 4; ++j) {
    int px = tx0 + pq * 4 + j;
    size_t pxg = ((size_t)b * 128 + oy) * 128 + px;
    size_t addr = (icb * 131072 + pxg) * 8 + off;
    ushort h0 = f2bf(acc[0][j]); ushort l0 = f2bf(acc[0][j] - bf2f(h0));
    ushort h1 = f2bf(acc[1][j]); ushort l1 = f2bf(acc[1][j] - bf2f(h1));
    ushort h2 = f2bf(acc[2][j]); ushort l2 = f2bf(acc[2][j] - bf2f(h2));
    ushort h3 = f2bf(acc[3][j]); ushort l3 = f2bf(acc[3][j] - bf2f(h3));
    uint2 uh; uh.x = (uint)h0 | ((uint)h1 << 16); uh.y = (uint)h2 | ((uint)h3 << 16);
    uint2 ul; ul.x = (uint)l0 | ((uint)l1 << 16); ul.y = (uint)l2 | ((uint)l3 << 16);
    *(uint2*)(oh + addr) = uh;
    *(uint2*)(ol + addr) = ul;
    float v0 = bf2f(h0) + bf2f(l0), v1 = bf2f(h1) + bf2f(l1);
    float v2 = bf2f(h2) + bf2f(l2), v3 = bf2f(h3) + bf2f(l3);
    sm[0] += v0; qm[0] += v0 * v0;
    sm[1] += v1; qm[1] += v1 * v1;
    sm[2] += v2; qm[2] += v2 * v2;
    sm[3] += v3; qm[3] += v3 * v3;
  }
#pragma unroll
  for (int o = 16; o > 0; o >>= 1) {
#pragma unroll
    for (int m = 0; m < 4; ++m) {
      sm[m] += __shfl_xor(sm[m], o);
      qm[m] += __shfl_xor(qm[m], o);
    }
  }
  if ((t & 31) == 0) {
#pragma unroll
    for (int m = 0; m < 4; ++m) { b1sum[oq * 4 + m] = sm[m]; b1sq[oq * 4 + m] = qm[m]; }
  }
  __syncthreads();
  if (t < 32) {
    atomicAdd(&stats[oc0 + t], b1sum[t]);
    atomicAdd(&stats[128 + oc0 + t], b1sq[t]);
  }
}

// ---- in-place BN+LReLU on blocked bf16 hi/lo x1 (fin inline) ----
__global__ __launch_bounds__(256) void bn_apply_x1_k(
    ushort* __restrict__ xh, ushort* __restrict__ xl,
    const float* __restrict__ stats, const float* __restrict__ g,
    const float* __restrict__ bt)
{
  __shared__ float scs[128], sfs[128];
  const int t = threadIdx.x;
  if (t < 128) {
    float m = stats[t] * (1.f / 131072.f);
    float v = stats[128 + t] * (1.f / 131072.f) - m * m;
    float rs = rsqrtf(v + 1e-5f);
    float sc = g[t] * rs;
    scs[t] = sc; sfs[t] = bt[t] - m * sc;
  }
  __syncthreads();
  const size_t total = (size_t)16 * 131072;
  const size_t stride = (size_t)gridDim.x * 256;
  for (size_t i = (size_t)blockIdx.x * 256 + t; i < total; i += stride) {
    int j = (int)(i >> 17);
    int c0 = j * 8;
    uint4 vh = *(const uint4*)(xh + i * 8);
    uint4 vl = *(const uint4*)(xl + i * 8);
    uint hw[4] = {vh.x, vh.y, vh.z, vh.w};
    uint lw[4] = {vl.x, vl.y, vl.z, vl.w};
    uint ohv[4], olv[4];
#pragma unroll
    for (int m = 0; m < 4; ++m) {
      float f0 = __uint_as_float(hw[m] << 16) + __uint_as_float(lw[m] << 16);
      float f1 = __uint_as_float(hw[m] & 0xffff0000u) + __uint_as_float(lw[m] & 0xffff0000u);
      float a0 = fmaf(f0, scs[c0 + 2*m],   sfs[c0 + 2*m]);   a0 = fmaxf(a0, 0.1f * a0);
      float a1 = fmaf(f1, scs[c0 + 2*m+1], sfs[c0 + 2*m+1]); a1 = fmaxf(a1, 0.1f * a1);
      ushort h0 = f2bf(a0), l0 = f2bf(a0 - bf2f(h0));
      ushort h1 = f2bf(a1), l1 = f2bf(a1 - bf2f(h1));
      ohv[m] = (uint)h0 | ((uint)h1 << 16);
      olv[m] = (uint)l0 | ((uint)l1 << 16);
    }
    uint4 rh = {ohv[0], ohv[1], ohv[2], ohv[3]};
    uint4 rl = {olv[0], olv[1], olv[2], olv[3]};
    *(uint4*)(xh + i * 8) = rh;
    *(uint4*)(xl + i * 8) = rl;
  }
}

__global__ __launch_bounds__(256) void bn_stats_nhwc_k(
    const float* __restrict__ x, float* __restrict__ stats,
    int cmask, int lg2c, int totpx)
{
  int g = blockIdx.x * 256 + threadIdx.x;
  int c = g & cmask;
  int p0 = g >> lg2c;
  int stride = (gridDim.x * 256) >> lg2c;
  float s = 0.f, q = 0.f;
  for (int p = p0; p < totpx; p += stride) {
    float v = x[((size_t)p << lg2c) | c];
    s += v; q += v * v;
  }
  atomicAdd(&stats[c], s);
  atomicAdd(&stats[cmask + 1 + c], q);
}

// ---- BN+LReLU+split fp32 NHWC -> blocked bf16 hi/lo (inline fin) ----
template<int C>
__global__ __launch_bounds__(256) void split_blocked_k(
    const float* __restrict__ h, const float* __restrict__ stats,
    const float* __restrict__ g, const float* __restrict__ bt, float inv_n,
    ushort* __restrict__ oh, ushort* __restrict__ ol, int totpx)
{
  __shared__ ushort lh[16][C + 8], ll[16][C + 8];
  __shared__ float scs[C], sfs[C];
  const int px0 = blockIdx.x * 16;
  const int t = threadIdx.x;
  if (t < C) {
    float m = stats[t] * inv_n;
    float v = stats[C + t] * inv_n - m * m;
    float rs = rsqrtf(v + 1e-5f);
    float sc = g[t] * rs;
    scs[t] = sc; sfs[t] = bt[t] - m * sc;
  }
  __syncthreads();
  for (int e = t; e < 16 * C / 4; e += 256) {
    int px = e / (C / 4);
    int c0 = (e % (C / 4)) * 4;
    float4 v  = *(const float4*)(h + (size_t)(px0 + px) * C + c0);
    float a0 = fmaf(v.x, scs[c0],   sfs[c0]);   a0 = fmaxf(a0, 0.1f * a0);
    float a1 = fmaf(v.y, scs[c0+1], sfs[c0+1]); a1 = fmaxf(a1, 0.1f * a1);
    float a2 = fmaf(v.z, scs[c0+2], sfs[c0+2]); a2 = fmaxf(a2, 0.1f * a2);
    float a3 = fmaf(v.w, scs[c0+3], sfs[c0+3]); a3 = fmaxf(a3, 0.1f * a3);
    ushort h0 = f2bf(a0), h1 = f2bf(a1), h2v = f2bf(a2), h3v = f2bf(a3);
    lh[px][c0]   = h0;  ll[px][c0]   = f2bf(a0 - bf2f(h0));
    lh[px][c0+1] = h1;  ll[px][c0+1] = f2bf(a1 - bf2f(h1));
    lh[px][c0+2] = h2v; ll[px][c0+2] = f2bf(a2 - bf2f(h2v));
    lh[px][c0+3] = h3v; ll[px][c0+3] = f2bf(a3 - bf2f(h3v));
  }
  __syncthreads();
  for (int e = t; e < 16 * (C / 8); e += 256) {
    int j = e >> 4, px = e & 15;
    *(uint4*)(oh + ((size_t)j * totpx + px0 + px) * 8) = *(const uint4*)&lh[px][j * 8];
    *(uint4*)(ol + ((size_t)j * totpx + px0 + px) * 8) = *(const uint4*)&ll[px][j * 8];
  }
}

// ------- all weight splits merged; FRAGMENT-ORDERED layouts -------
__global__ void wsplit_all_k(
    const float* __restrict__ c2w, const float* __restrict__ c3w,
    const float* __restrict__ c4w, const float* __restrict__ c5w,
    ushort* __restrict__ wph, ushort* __restrict__ wpl,
    ushort* __restrict__ w3h, ushort* __restrict__ w3l,
    ushort* __restrict__ w4h, ushort* __restrict__ w4l,
    ushort* __restrict__ w5h, ushort* __restrict__ w5l)
{
  int i = blockIdx.x * 256 + threadIdx.x;
  if (i < 294912) {
    int kk = i % 9; int r = i / 9; int ic = r & 127; int oc = r >> 7;
    float v = c2w[i];
    ushort hi = f2bf(v), lo = f2bf(v - bf2f(hi));
    int ohf = oc >> 7, of = (oc >> 4) & 7, lr = oc & 15;
    int ic32 = ic >> 5, kg = (ic >> 3) & 3, ici = ic & 7;
    size_t d = ((((size_t)(kk * 4 + ic32) * 2 + ohf) * 8 + of) * 4 + kg) * 128
               + lr * 8 + ici;
    wph[d] = hi; wpl[d] = lo;
    return;
  }
  i -= 294912;
  const float* w; ushort *wh, *wl; int OC, IC, n;
  if (i < 262144)      { w = c3w; wh = w3h; wl = w3l; OC = 64;  IC = 256; n = i; }
  else if (i < 393216) { w = c4w; wh = w4h; wl = w4l; OC = 128; IC = 64;  n = i - 262144; }
  else if (i < 917504) { w = c5w; wh = w5h; wl = w5l; OC = 256; IC = 128; n = i - 393216; }
  else return;
  int kx = n & 3, ky = (n >> 2) & 3;
  int ic = (n >> 4) % IC, oc = (n >> 4) / IC;
  float v = w[n];
  ushort hi = f2bf(v), lo = f2bf(v - bf2f(hi));
  int NCH = IC >> 3, NWO = OC >> 6;
  int wo = oc >> 6, of = (oc >> 4) & 3, lr = oc & 15;
  int ch = ic >> 3, ici = ic & 7;
  size_t d = ((((size_t)(ky * NCH + ch) * NWO + wo) * 4 + of) * 4 + kx) * 128
             + lr * 8 + ici;
  wh[d] = hi; wl[d] = lo;
}

// ---- conv2 X staging: async global->LDS, uniform 6 GLL16 per thread ----
// slots 0..519: slot = icg*130 + xi; slots 0..511 via 2 full rounds,
// tail 512..519 distributed 2 per wave (lanes 0,1).
__device__ __forceinline__ void stage_x3(
    const ushort* __restrict__ x1h, const ushort* __restrict__ x1l,
    const ushort* __restrict__ zbuf,
    ushort* xh_dst, ushort* xl_dst, int t, int b, int gy)
// gy here is the global row; ic32 folded into caller's base pointers? no:
{
  // (kept signature simple; ic32 handled by caller passing adjusted x1h/x1l)
  const bool rowok = (unsigned)gy < 128u;
  const size_t rowb = ((size_t)b * 128 + (rowok ? gy : 0)) * 128;
#pragma unroll
  for (int k = 0; k < 2; ++k) {
    int e = t + k * 256;
    int icg = e / 130;
    int xi  = e - icg * 130;
    int gx  = xi - 1;
    const ushort* sh = zbuf;
    const ushort* sl = zbuf;
    if (rowok && (unsigned)gx < 128u) {
      size_t gi = ((size_t)icg * 131072 + rowb + gx) * 8;
      sh = x1h + gi; sl = x1l + gi;
    }
    GLL16(sh, xh_dst + (size_t)e * 8);
    GLL16(sl, xl_dst + (size_t)e * 8);
  }
  {
    int wv = t >> 6, lane = t & 63;
    int e  = 512 + wv * 2 + lane;      // meaningful for lane<2
    int xi = e - 390;                  // icg = 3
    int gx = xi - 1;
    if (lane < 2) {
      const ushort* sh = zbuf;
      const ushort* sl = zbuf;
      if (rowok && (unsigned)gx < 128u) {
        size_t gi = ((size_t)3 * 131072 + rowb + gx) * 8;
        sh = x1h + gi; sl = x1l + gi;
      }
      GLL16(sh, xh_dst + (size_t)e * 8);
      GLL16(sl, xl_dst + (size_t)e * 8);
    }
  }
}

// ------- conv2 via MFMA (bf16x3): 2-deep async pipeline, counted vmcnt -------
// 1 row x 128 px x 256 oc per block; W fragments from global; XCD swizzle.
__global__ __launch_bounds__(256, 2) void conv2_mfma_k(
    const ushort* __restrict__ x1h, const ushort* __restrict__ x1l,
    const ushort* __restrict__ wph, const ushort* __restrict__ wpl,
    const ushort* __restrict__ zbuf, float* __restrict__ stats2,
    ushort* __restrict__ x3h, ushort* __restrict__ x3l)
{
  const int bid = blockIdx.x;                 // 1024 blocks
  const int wid = (bid & 7) * 128 + (bid >> 3);
  const int y0  = wid & 127;
  const int b   = wid >> 7;

  __shared__ ushort xs[3][2][4][130][8];   // [buf][hl][icg][xi][8] : 49,920 B
  __shared__ float bsum[2][256], bsq[2][256];

  const int t = threadIdx.x;
  const int w  = t >> 6;
  const int l  = t & 63;
  const int xhf = w & 1;
  const int ohf = w >> 1;
  const int lr = l & 15;
  const int kg = l >> 4;

  f32x4 acc[8][4];
#pragma unroll
  for (int i = 0; i < 8; ++i)
#pragma unroll
    for (int j = 0; j < 4; ++j) acc[i][j] = (f32x4){0.f, 0.f, 0.f, 0.f};

  // prologue: stage phases 0 and 1 (p = ky*4+ic32; gy = y0 + (p>>2) - 1)
  stage_x3(x1h + (size_t)(0 * 4) * 131072 * 8, x1l + (size_t)(0 * 4) * 131072 * 8,
           zbuf, (ushort*)&xs[0][0][0][0][0], (ushort*)&xs[0][1][0][0][0],
           t, b, y0 - 1);
  stage_x3(x1h + (size_t)(1 * 4) * 131072 * 8, x1l + (size_t)(1 * 4) * 131072 * 8,
           zbuf, (ushort*)&xs[1][0][0][0][0], (ushort*)&xs[1][1][0][0][0],
           t, b, y0 - 1);

  for (int p = 0; p < 12; ++p) {
    // drain own stage(p) (6 ops); allow stage(p+1)'s 6 to stay in flight
    if (p < 11) { asm volatile("s_waitcnt vmcnt(6)" ::: "memory"); }
    else        { asm volatile("s_waitcnt vmcnt(0)" ::: "memory"); }
    __builtin_amdgcn_sched_barrier(0);
    __builtin_amdgcn_s_barrier();
    __builtin_amdgcn_sched_barrier(0);

    // stage(p+2) into buf (p+2)%3 (== (p-1)%3, last read at p-1: safe)
    if (p + 2 < 12) {
      const int np = p + 2;
      stage_x3(x1h + (size_t)((np & 3) * 4) * 131072 * 8,
               x1l + (size_t)((np & 3) * 4) * 131072 * 8,
               zbuf,
               (ushort*)&xs[np % 3][0][0][0][0], (ushort*)&xs[np % 3][1][0][0][0],
               t, b, y0 + (np >> 2) - 1);
    }

    const int buf  = p % 3;
    const int ky   = p >> 2;
    const int ic32 = p & 3;
#pragma unroll
    for (int kx = 0; kx < 3; ++kx) {
      const int kk = ky * 3 + kx;
      const size_t wbase =
          ((size_t)((kk * 4 + ic32) * 2 + ohf)) * 4096 + (size_t)l * 8;
      const ushort* pwh = wph + wbase;
      const ushort* pwl = wpl + wbase;

      bf16x8 xbh[4], xbl[4];
#pragma unroll
      for (int pf = 0; pf < 4; ++pf) {
        int xi = xhf * 64 + pf * 16 + lr + kx;
        xbh[pf] = *(const bf16x8*)&xs[buf][0][kg][xi][0];
        xbl[pf] = *(const bf16x8*)&xs[buf][1][kg][xi][0];
      }
#pragma unroll
      for (int oh2 = 0; oh2 < 2; ++oh2) {
        bf16x8 awh[4], awl[4];
#pragma unroll
        for (int o4 = 0; o4 < 4; ++o4) {
          awh[o4] = *(const bf16x8*)(pwh + (oh2 * 4 + o4) * 512);
          awl[o4] = *(const bf16x8*)(pwl + (oh2 * 4 + o4) * 512);
        }
#pragma unroll
        for (int o4 = 0; o4 < 4; ++o4) {
          const int of = oh2 * 4 + o4;
#pragma unroll
          for (int pf = 0; pf < 4; ++pf) {
            acc[of][pf] = __builtin_amdgcn_mfma_f32_16x16x32_bf16(awh[o4], xbh[pf], acc[of][pf], 0, 0, 0);
            acc[of][pf] = __builtin_amdgcn_mfma_f32_16x16x32_bf16(awh[o4], xbl[pf], acc[of][pf], 0, 0, 0);
            acc[of][pf] = __builtin_amdgcn_mfma_f32_16x16x32_bf16(awl[o4], xbh[pf], acc[of][pf], 0, 0, 0);
          }
        }
      }
    }
  }

  // epilogue: quantize+store + per-oc stats
#pragma unroll
  for (int of = 0; of < 8; ++of) {
    float s4[4] = {0.f, 0.f, 0.f, 0.f}, q4[4] = {0.f, 0.f, 0.f, 0.f};
#pragma unroll
    for (int pf = 0; pf < 4; ++pf) {
      int oc = ohf * 128 + of * 16 + kg * 4;
      int x  = xhf * 64 + pf * 16 + lr;
      size_t pxg = ((size_t)b * 128 + y0) * 128 + x;
      size_t base = ((size_t)(oc >> 3) * 131072 + pxg) * 8 + (oc & 7);
      f32x4 a = acc[of][pf];
      ushort h0 = f2bf(a[0]); ushort l0 = f2bf(a[0] - bf2f(h0));
      ushort h1 = f2bf(a[1]); ushort l1 = f2bf(a[1] - bf2f(h1));
      ushort h2 = f2bf(a[2]); ushort l2 = f2bf(a[2] - bf2f(h2));
      ushort h3 = f2bf(a[3]); ushort l3 = f2bf(a[3] - bf2f(h3));
      uint2 uh; uh.x = (uint)h0 | ((uint)h1 << 16); uh.y = (uint)h2 | ((uint)h3 << 16);
      uint2 ul; ul.x = (uint)l0 | ((uint)l1 << 16); ul.y = (uint)l2 | ((uint)l3 << 16);
      *(uint2*)(x3h + base) = uh;
      *(uint2*)(x3l + base) = ul;
      float v0 = bf2f(h0) + bf2f(l0), v1 = bf2f(h1) + bf2f(l1);
      float v2 = bf2f(h2) + bf2f(l2), v3 = bf2f(h3) + bf2f(l3);
      s4[0] += v0; q4[0] += v0 * v0;
      s4[1] += v1; q4[1] += v1 * v1;
      s4[2] += v2; q4[2] += v2 * v2;
      s4[3] += v3; q4[3] += v3 * v3;
    }
#pragma unroll
    for (int o = 8; o > 0; o >>= 1) {
#pragma unroll
      for (int j = 0; j < 4; ++j) {
        s4[j] += __shfl_xor(s4[j], o);
        q4[j] += __shfl_xor(q4[j], o);
      }
    }
    if (lr == 0) {
      int oc = ohf * 128 + of * 16 + kg * 4;
#pragma unroll
      for (int j = 0; j < 4; ++j) { bsum[xhf][oc + j] = s4[j]; bsq[xhf][oc + j] = q4[j]; }
    }
  }
  __syncthreads();
  if (t < 256) {
    atomicAdd(&stats2[t],       bsum[0][t] + bsum[1][t]);
    atomicAdd(&stats2[256 + t], bsq[0][t] + bsq[1][t]);
  }
}

// ------- conv3/4/5 via MFMA, K-split, W fragments from global -------
template<int IC, int OC, int OH, int OW, int WPX, int CS, bool FBN>
__global__ __launch_bounds__(256, 2) void convs_mfma_k(
    const ushort* __restrict__ xh, const ushort* __restrict__ xl,
    const ushort* __restrict__ wh, const ushort* __restrict__ wl,
    const float* __restrict__ stats, const float* __restrict__ gg,
    const float* __restrict__ bb, float inv_n,
    float* __restrict__ part)
{
  constexpr int IH  = 2 * OH, IW = 2 * OW;
  constexpr int NCH = IC / 8;
  constexpr int NCHB = NCH / CS;
  constexpr int PFX = OW / 16;
  constexpr int RW  = 4 / WPX;
  constexpr int NZ = 4 * CS;
  constexpr int NX = OH / 4;
  constexpr int NWO = OC / 64;
  constexpr int SBN = FBN ? IC : 1;

  const int bid = blockIdx.x;
  const int wid = (bid & 7) * (NZ * NX) + (bid >> 3);
  const int zi = wid % NZ;
  const int y0 = ((wid / NZ) % NX) * 4;
  const int b  = wid / (NZ * NX);
  const int ky = zi & 3;
  const int cs = zi >> 2;

  __shared__ ushort xs[2][4][2][OW + 2][8];
  __shared__ float scs[SBN], sfs[SBN];

  const int t = threadIdx.x;
  if (FBN) {
    for (int c = t; c < IC; c += 256) {
      float m = stats[c] * inv_n;
      float v = stats[IC + c] * inv_n - m * m;
      float rs = rsqrtf(v + 1e-5f);
      float sc = gg[c] * rs;
      scs[c] = sc; sfs[c] = bb[c] - m * sc;
    }
  }

  const int w = t >> 6, l = t & 63;
  const int wo = w / WPX, wp = w % WPX;
  const int lr = l & 15, kg = l >> 4;
  const int oc0w = wo * 64;
  const int rb = wp * RW;

  f32x4 acc[4][4];
#pragma unroll
  for (int i = 0; i < 4; ++i)
#pragma unroll
    for (int j = 0; j < 4; ++j) acc[i][j] = (f32x4){0.f, 0.f, 0.f, 0.f};

  for (int cc = 0; cc < NCHB; ++cc) {
    const int ch = cs * NCHB + cc;
    __syncthreads();
    for (int e = t; e < 4 * (IW + 2); e += 256) {
      int r  = e / (IW + 2);
      int xi = e % (IW + 2);
      int xp = xi - 1;
      int iy = 2 * (y0 + r) + ky - 1;
      uint4 rh = {0, 0, 0, 0}, rl = {0, 0, 0, 0};
      if ((unsigned)iy < (unsigned)IH && (unsigned)xp < (unsigned)IW) {
        size_t gi = ((((size_t)ch * 8 + b) * IH + iy) * IW + xp) * 8;
        uint4 vh = *(const uint4*)(xh + gi);
        uint4 vl = *(const uint4*)(xl + gi);
        if (FBN) {
          int c0 = ch * 8;
          uint hw[4] = {vh.x, vh.y, vh.z, vh.w};
          uint lw[4] = {vl.x, vl.y, vl.z, vl.w};
          uint ohv[4], olv[4];
#pragma unroll
          for (int m = 0; m < 4; ++m) {
            float f0 = __uint_as_float(hw[m] << 16) + __uint_as_float(lw[m] << 16);
            float f1 = __uint_as_float(hw[m] & 0xffff0000u) + __uint_as_float(lw[m] & 0xffff0000u);
            float a0 = fmaf(f0, scs[c0 + 2*m],   sfs[c0 + 2*m]);   a0 = fmaxf(a0, 0.1f * a0);
            float a1 = fmaf(f1, scs[c0 + 2*m+1], sfs[c0 + 2*m+1]); a1 = fmaxf(a1, 0.1f * a1);
            ushort h0 = f2bf(a0), l0 = f2bf(a0 - bf2f(h0));
            ushort h1 = f2bf(a1), l1 = f2bf(a1 - bf2f(h1));
            ohv[m] = (uint)h0 | ((uint)h1 << 16);
            olv[m] = (uint)l0 | ((uint)l1 << 16);
          }
          rh.x = ohv[0]; rh.y = ohv[1]; rh.z = ohv[2]; rh.w = ohv[3];
          rl.x = olv[0]; rl.y = olv[1]; rl.z = olv[2]; rl.w = olv[3];
        } else {
          rh = vh; rl = vl;
        }
      }
      int par = xp & 1;
      int idx = (xp + 1) >> 1;
      *(uint4*)&xs[0][r][par][idx][0] = rh;
      *(uint4*)&xs[1][r][par][idx][0] = rl;
    }
    __syncthreads();

    const size_t wbase =
        ((size_t)(ky * NCH + ch) * NWO + wo) * 2048 + (size_t)l * 8;
    bf16x8 ah[4], al[4], bh[4], bl[4];
#pragma unroll
    for (int of = 0; of < 4; ++of) {
      ah[of] = *(const bf16x8*)(wh + wbase + of * 512);
      al[of] = *(const bf16x8*)(wl + wbase + of * 512);
    }
    const int par = 1 - (kg & 1);
    const int xoff = kg >> 1;
#pragma unroll
    for (int pf = 0; pf < 4; ++pf) {
      int row = rb + pf / PFX;
      int x   = (pf % PFX) * 16 + lr;
      bh[pf] = *(const bf16x8*)&xs[0][row][par][x + xoff][0];
      bl[pf] = *(const bf16x8*)&xs[1][row][par][x + xoff][0];
    }
#pragma unroll
    for (int of = 0; of < 4; ++of) {
#pragma unroll
      for (int pf = 0; pf < 4; ++pf) {
        acc[of][pf] = __builtin_amdgcn_mfma_f32_16x16x32_bf16(ah[of], bh[pf], acc[of][pf], 0, 0, 0);
        acc[of][pf] = __builtin_amdgcn_mfma_f32_16x16x32_bf16(ah[of], bl[pf], acc[of][pf], 0, 0, 0);
        acc[of][pf] = __builtin_amdgcn_mfma_f32_16x16x32_bf16(al[of], bh[pf], acc[of][pf], 0, 0, 0);
      }
    }
  }

  float* yp = part + (size_t)zi * (8 * OH * OW * OC);
#pragma unroll
  for (int of = 0; of < 4; ++of) {
#pragma unroll
    for (int pf = 0; pf < 4; ++pf) {
      int row = rb + pf / PFX;
      int x   = (pf % PFX) * 16 + lr;
      int oc  = oc0w + of * 16 + kg * 4;
      float* p = yp + (((size_t)b * OH + y0 + row) * OW + x) * OC + oc;
      f32x4 a = acc[of][pf];
      float4 v = {a[0], a[1], a[2], a[3]};
      *(float4*)p = v;
    }
  }
}

// ------- reduce partials -> h (float4) -------
__global__ __launch_bounds__(256) void reduce_k(
    const float* __restrict__ part, float* __restrict__ h,
    int n4, int nparts)
{
  int i = blockIdx.x * 256 + threadIdx.x;
  if (i >= n4) return;
  float4 a = ((const float4*)part)[i];
  for (int z = 1; z < nparts; ++z) {
    float4 b = ((const float4*)part)[(size_t)z * n4 + i];
    a.x += b.x; a.y += b.y; a.z += b.z; a.w += b.w;
  }
  ((float4*)h)[i] = a;
}

// ---------------- capsule rearrange (h5 NHWC, BN inline) ----------------
__global__ void caps_k(const float* __restrict__ h5, const float* __restrict__ stats,
                       const float* __restrict__ g5, const float* __restrict__ b5,
                       float* __restrict__ caps)
{
  int e = blockIdx.x * 256 + threadIdx.x;
  if (e >= NB * NCAP * 8) return;
  int ii = e & 7;
  int n  = (e >> 3) & 511;
  int jb = e >> 12;
  int j = jb >> 3, b = jb & 7;
  int i = n >> 7, k = (n >> 5) & 3, ch = ((n & 31) << 3) | ii;
  int hh = (i << 2) | (j >> 2);
  int ww = ((j & 3) << 2) | k;
  float m  = stats[ch] * (1.f / 2048.f);
  float vv = stats[256 + ch] * (1.f / 2048.f) - m * m;
  float rs = rsqrtf(vv + 1e-5f);
  float sc = g5[ch] * rs;
  float sf = b5[ch] - m * sc;
  float v = h5[(((size_t)b * 16 + hh) * 16 + ww) * 256 + ch];
  float a = fmaf(v, sc, sf);
  a = fmaxf(a, 0.1f * a);
  caps[e] = a;
}

// ---------------- priors (bf16 output) ----------------
__global__ __launch_bounds__(256) void priors_k(
    const float* __restrict__ caps, const float* __restrict__ rw,
    ushort* __restrict__ priors)
{
  const int n = blockIdx.x;
  __shared__ float lrw[NCLS * 8 * NO];
  __shared__ float lc[NB * 8];
  const int t = threadIdx.x;
  for (int e = t; e < NCLS * 8 * NO; e += 256)
    lrw[e] = rw[(size_t)n * NCLS * 8 * NO + e];
  for (int e = t; e < NB * 8; e += 256) {
    int b = e >> 3, ii = e & 7;
    lc[e] = caps[((size_t)b * NCAP + n) * 8 + ii];
  }
  __syncthreads();

  int p[4], kk[4], oo[4];
#pragma unroll
  for (int q = 0; q < 4; ++q) {
    p[q]  = t + q * 256;
    kk[q] = (p[q] < KO) ? p[q] / NO : 0;
    oo[q] = (p[q] < KO) ? p[q] % NO : 0;
  }
  for (int b = 0; b < NB; ++b) {
    const float* cb = &lc[b * 8];
    float c0 = cb[0], c1 = cb[1], c2 = cb[2], c3 = cb[3];
    float c4 = cb[4], c5 = cb[5], c6 = cb[6], c7 = cb[7];
    ushort* pout = priors + ((size_t)b * NCAP + n) * KO;
#pragma unroll
    for (int q = 0; q < 4; ++q) {
      if (p[q] < KO) {
        const float* wv = &lrw[kk[q] * (8 * NO) + oo[q]];
        float a = c0 * wv[0];
        a = fmaf(c1, wv[21],  a);
        a = fmaf(c2, wv[42],  a);
        a = fmaf(c3, wv[63],  a);
        a = fmaf(c4, wv[84],  a);
        a = fmaf(c5, wv[105], a);
        a = fmaf(c6, wv[126], a);
        a = fmaf(c7, wv[147], a);
        pout[p[q]] = f2bf(a);
      }
    }
  }
}

// ---------------- routing ----------------
__global__ __launch_bounds__(256) void route_s_partial(
    const ushort* __restrict__ priors, float* __restrict__ s)
{
  const int b  = blockIdx.x >> 3;
  const int ns = blockIdx.x & 7;
  const int t  = threadIdx.x;
  const int p0 = t, p1 = t + 256, p2 = t + 512, p3 = t + 768;
  float a0 = 0.f, a1 = 0.f, a2 = 0.f, a3 = 0.f;
  const ushort* pb = priors + ((size_t)b * NCAP + ns * 64) * KO;
#pragma unroll 2
  for (int n = 0; n < 64; ++n) {
    const ushort* pn = pb + (size_t)n * KO;
    a0 += bf2f(pn[p0]); a1 += bf2f(pn[p1]); a2 += bf2f(pn[p2]);
    if (p3 < KO) a3 += bf2f(pn[p3]);
  }
  const float sc = 1.f / 43.f;
  atomicAdd(&s[b * KO + p0], a0 * sc);
  atomicAdd(&s[b * KO + p1], a1 * sc);
  atomicAdd(&s[b * KO + p2], a2 * sc);
  if (p3 < KO) atomicAdd(&s[b * KO + p3], a3 * sc);
}

// fused logits+softmax+s: barrier-free, lane k owns class k, wave-local LDS
__global__ __launch_bounds__(256) void route_iter_k(
    const ushort* __restrict__ priors, const float* __restrict__ souts,
    float* __restrict__ logits, float* __restrict__ s,
    int readPrev, int writeL)
{
  const int b  = blockIdx.x >> 3;
  const int ns = blockIdx.x & 7;
  const int t  = threadIdx.x;
  const int w  = t >> 6;
  const int lane = t & 63;
  const bool act = lane < NCLS;

  __shared__ float prow[4][928];   // per-wave row buffer; reused as reduce buf

  float so[NO], sacc[NO], v[NO];
  if (act) {
#pragma unroll
    for (int o = 0; o < NO; ++o) so[o] = souts[b * KO + lane * NO + o];
  }
#pragma unroll
  for (int o = 0; o < NO; ++o) { sacc[o] = 0.f; v[o] = 0.f; }

  for (int nn = 0; nn < 16; ++nn) {
    const int n = ns * 64 + w * 16 + nn;
    const ushort* pr = priors + ((size_t)(b * NCAP + n)) * KO;
#pragma unroll
    for (int q = 0; q < 15; ++q) {
      int e = lane + q * 64;
      if (e < KO) prow[w][e] = bf2f(pr[e]);
    }
    // wave-local LDS exchange: ds ops in-order per wave, no barrier needed
    float L = -1e30f;
    if (act) {
      float d = 0.f;
#pragma unroll
      for (int o = 0; o < NO; ++o) v[o] = prow[w][lane * NO + o];
#pragma unroll
      for (int o = 0; o < NO; ++o) d = fmaf(v[o], so[o], d);
      size_t lidx = ((size_t)(b * NCAP + n)) * NCLS + lane;
      L = (readPrev ? logits[lidx] : 0.f) + d;
      if (writeL) logits[lidx] = L;
    }
    float m = L;
#pragma unroll
    for (int off = 32; off > 0; off >>= 1) m = fmaxf(m, __shfl_xor(m, off));
    float ex = act ? __expf(L - m) : 0.f;
    float sm = ex;
#pragma unroll
    for (int off = 32; off > 0; off >>= 1) sm += __shfl_xor(sm, off);
    float pk = ex / sm;
    if (act) {
#pragma unroll
      for (int o = 0; o < NO; ++o) sacc[o] = fmaf(pk, v[o], sacc[o]);
    }
  }
  // cross-wave reduce via LDS (prow reused), then one atomic per element
  if (act) {
#pragma unroll
    for (int o = 0; o < NO; ++o) prow[w][lane * NO + o] = sacc[o];
  }
  __syncthreads();
  for (int e = t; e < KO; e += 256)
    atomicAdd(&s[b * KO + e], prow[0][e] + prow[1][e] + prow[2][e] + prow[3][e]);
}

__global__ void squash_k(const float* __restrict__ s, float* __restrict__ souts)
{
  int i = blockIdx.x * 256 + threadIdx.x;
  if (i >= NB * NCLS) return;
  int b = i / NCLS, k = i % NCLS;
  const float* sv = s + b * KO + k * NO;
  float sn = 0.f;
#pragma unroll
  for (int o = 0; o < NO; ++o) sn += sv[o] * sv[o];
  float f = sqrtf(sn) / (1.f + sn);
  float* ov = souts + b * KO + k * NO;
#pragma unroll
  for (int o = 0; o < NO; ++o) ov[o] = sv[o] * f;
}

__global__ void out_k(const float* __restrict__ souts, float* __restrict__ out)
{
  int i = blockIdx.x * 256 + threadIdx.x;
  if (i >= 8 * 16 * NCLS * NO) return;
  int o = i % NO;
  int r = i / NO;
  int k = r % NCLS; r /= NCLS;
  int g1 = r & 3; r >>= 2;
  int g0 = r & 3;
  int b  = r >> 2;
  int j  = g0 * 4 + g1;
  int jb = j * 8 + b;
  out[i] = souts[jb * KO + k * NO + o];
}

// ---------------- launcher ----------------
extern "C" void kernel_launch(void* const* d_in, const int* in_sizes, int n_in,
                              void* d_out, int out_size, void* d_ws, size_t ws_size,
                              hipStream_t stream)
{
  const float* x   = (const float*)d_in[0];
  const float* c1w = (const float*)d_in[1];
  const float* g1  = (const float*)d_in[3];  const float* b1  = (const float*)d_in[4];
  const float* c2w = (const float*)d_in[5];
  const float* g2  = (const float*)d_in[7];  const float* b2  = (const float*)d_in[8];
  const float* c3w = (const float*)d_in[9];
  const float* g3  = (const float*)d_in[11]; const float* b3  = (const float*)d_in[12];
  const float* c4w = (const float*)d_in[13];
  const float* g4  = (const float*)d_in[15]; const float* b4  = (const float*)d_in[16];
  const float* c5w = (const float*)d_in[17];
  const float* g5  = (const float*)d_in[19]; const float* b5  = (const float*)d_in[20];
  const float* rw  = (const float*)d_in[21];

  float* ws  = (float*)d_ws;
  float* out = (float*)d_out;

  ushort* x1h = (ushort*)(ws + F_X1H);
  ushort* x1l = (ushort*)(ws + F_X1L);
  ushort* wph = (ushort*)(ws + F_WPH);
  ushort* wpl = (ushort*)(ws + F_WPL);
  ushort* w3h = (ushort*)(ws + F_W3H);
  ushort* w3l = (ushort*)(ws + F_W3L);
  ushort* w4h = (ushort*)(ws + F_W4H);
  ushort* w4l = (ushort*)(ws + F_W4L);
  ushort* w5h = (ushort*)(ws + F_W5H);
  ushort* w5l = (ushort*)(ws + F_W5L);
  ushort* x3h = (ushort*)(ws + F_X3H);
  ushort* x3l = (ushort*)(ws + F_X3L);
  ushort* x4h = (ushort*)(ws + F_X4H);
  ushort* x4l = (ushort*)(ws + F_X4L);
  ushort* x5h = (ushort*)(ws + F_X5H);
  ushort* x5l = (ushort*)(ws + F_X5L);
  float* part   = ws + F_PART;
  float* h3     = ws + F_H3;
  float* h4     = ws + F_H4;
  float* h5     = ws + F_H5;
  float* caps   = ws + F_CAPS;
  ushort* priors = (ushort*)(ws + F_PRI);
  float* logits = ws + F_LOG;
  float* sbuf   = ws + F_S;
  float* souts  = ws + F_OUTS;
  float* stats  = ws + F_STAT;          // conv1 stats [0..255]; scratch [0..511]
  float* stats2 = ws + F_STAT + 512;    // conv2 stats [0..511]
  ushort* zbuf  = (ushort*)(ws + F_ZERO);

  // ---- init: zero stats and the OOB zero stub ----
  hipMemsetAsync(stats, 0, 1024 * sizeof(float), stream);
  hipMemsetAsync(zbuf, 0, 64, stream);

  // ---- weight preps (merged, fragment-ordered) ----
  wsplit_all_k<<<(1212416 + 255) / 256, 256, 0, stream>>>(
      c2w, c3w, c4w, c5w, wph, wpl, w3h, w3l, w4h, w4l, w5h, w5l);

  // ---- conv1 -> blocked pre-BN bf16 hi/lo (stats folded in) ----
  conv1_k<<<dim3(8, 16, 32), 256, 0, stream>>>(x, c1w, x1h, x1l, stats);

  // ---- BN+LReLU applied in place to x1 ----
  bn_apply_x1_k<<<2048, 256, 0, stream>>>(x1h, x1l, stats, g1, b1);

  // ---- conv2 (MFMA, 2-deep async pipeline, counted vmcnt, XCD swizzle) ----
  conv2_mfma_k<<<1024, 256, 0, stream>>>(x1h, x1l, wph, wpl, zbuf, stats2, x3h, x3l);

  // ---- conv3 (MFMA, ky-split x4, BN of x3 fused via stats2) ----
  convs_mfma_k<256, 64, 64, 64, 4, 1, true><<<512, 256, 0, stream>>>(
      x3h, x3l, w3h, w3l, stats2, g2, b2, 1.f / 131072.f, part);
  reduce_k<<<(524288 + 255) / 256, 256, 0, stream>>>(part, h3, 524288, 4);
  hipMemsetAsync(stats, 0, 2 * 64 * sizeof(float), stream);
  bn_stats_nhwc_k<<<256, 256, 0, stream>>>(h3, stats, 63, 6, 32768);
  split_blocked_k<64><<<2048, 256, 0, stream>>>(h3, stats, g3, b3, 1.f / 32768.f, x4h, x4l, 32768);

  // ---- conv4 (MFMA, (ky x ch/2)-split x8) ----
  convs_mfma_k<64, 128, 32, 32, 2, 2, false><<<512, 256, 0, stream>>>(
      x4h, x4l, w4h, w4l, stats, g4, b4, 0.f, part);
  reduce_k<<<(262144 + 255) / 256, 256, 0, stream>>>(part, h4, 262144, 8);
  hipMemsetAsync(stats, 0, 2 * 128 * sizeof(float), stream);
  bn_stats_nhwc_k<<<128, 256, 0, stream>>>(h4, stats, 127, 7, 8192);
  split_blocked_k<128><<<512, 256, 0, stream>>>(h4, stats, g4, b4, 1.f / 8192.f, x5h, x5l, 8192);

  // ---- conv5 (MFMA, (ky x ch/2)-split x8) ----
  convs_mfma_k<128, 256, 16, 16, 1, 2, false><<<256, 256, 0, stream>>>(
      x5h, x5l, w5h, w5l, stats, g5, b5, 0.f, part);
  reduce_k<<<(131072 + 255) / 256, 256, 0, stream>>>(part, h5, 131072, 8);
  hipMemsetAsync(stats, 0, 2 * 256 * sizeof(float), stream);
  bn_stats_nhwc_k<<<64, 256, 0, stream>>>(h5, stats, 255, 8, 2048);

  // ---- capsules ----
  caps_k<<<2048, 256, 0, stream>>>(h5, stats, g5, b5, caps);
  priors_k<<<512, 256, 0, stream>>>(caps, rw, priors);

  // ---- routing: 3 iterations ----
  hipMemsetAsync(sbuf, 0, NB * KO * sizeof(float), stream);
  route_s_partial<<<NB * 8, 256, 0, stream>>>(priors, sbuf);
  squash_k<<<(NB * NCLS + 255) / 256, 256, 0, stream>>>(sbuf, souts);

  hipMemsetAsync(sbuf, 0, NB * KO * sizeof(float), stream);
  route_iter_k<<<NB * 8, 256, 0, stream>>>(priors, souts, logits, sbuf, 0, 1);
  squash_k<<<(NB * NCLS + 255) / 256, 256, 0, stream>>>(sbuf, souts);

  hipMemsetAsync(sbuf, 0, NB * KO * sizeof(float), stream);
  route_iter_k<<<NB * 8, 256, 0, stream>>>(priors, souts, logits, sbuf, 1, 0);
  squash_k<<<(NB * NCLS + 255) / 256, 256, 0, stream>>>(sbuf, souts);

  // ---- final scatter ----
  out_k<<<(8 * 16 * NCLS * NO + 255) / 256, 256, 0, stream>>>(souts, out);
}

// Round 10
// 669.768 us; speedup vs baseline: 1.1383x; 1.0168x over previous
//
#include <hip/hip_runtime.h>
#include <math.h>

typedef unsigned int   uint;
typedef unsigned short ushort;
using bf16x8 = __attribute__((ext_vector_type(8))) __bf16;
using f32x4  = __attribute__((ext_vector_type(4))) float;

constexpr int NB   = 128;
constexpr int NCAP = 512;
constexpr int NCLS = 43;
constexpr int NO   = 21;
constexpr int KO   = NCLS * NO; // 903

// ---- workspace layout (float offsets) ----
constexpr size_t F_X1H  = 0;          // conv1 out hi, blocked [16][131072][8] bf16
constexpr size_t F_X1L  = 8388608;
constexpr size_t F_PART = 0;          // conv3/4/5 K-split partials (x1 dead)
constexpr size_t F_STAT = 16777216;   // 1,024 floats (conv1 stats [0..255]; stats2 at +512)
constexpr size_t F_WPH  = 16778240;   // conv2 w (147,456)
constexpr size_t F_WPL  = 16925696;
constexpr size_t F_W3H  = 17073152;
constexpr size_t F_W3L  = 17204224;
constexpr size_t F_W4H  = 17335296;
constexpr size_t F_W4L  = 17400832;
constexpr size_t F_W5H  = 17466368;
constexpr size_t F_W5L  = 17728512;
constexpr size_t F_X3H  = 17990656;   // conv2 out hi, blocked [32][131072][8] bf16
constexpr size_t F_X3L  = 34767872;   // ends 51,545,088
constexpr size_t F_H3   = 51545088;   // h3 NHWC fp32 (2,097,152)
constexpr size_t F_X4H  = 53642240;
constexpr size_t F_X4L  = 54690816;
constexpr size_t F_H4   = 55739392;
constexpr size_t F_X5H  = 56787968;
constexpr size_t F_X5L  = 57312256;
constexpr size_t F_H5   = 57836544;   // (524,288)
// routing phase:
constexpr size_t F_PRI  = 0;          // bf16 priors: 59,179,008 ushorts
constexpr size_t F_CAPS = 59179008;   // 524,288
constexpr size_t F_LOG  = 59703296;   // 2,818,048
constexpr size_t F_S    = 65339392;   // 115,584
constexpr size_t F_OUTS = 65454976;   // 115,584 -> ends 65,570,560
constexpr size_t F_ZERO = 65570560;   // 16 floats zero stub for OOB global_load_lds

__device__ inline ushort f2bf(float x) {
  uint u = __float_as_uint(x);
  uint r = (u + 0x7fffu + ((u >> 16) & 1u)) >> 16;  // RNE
  return (ushort)r;
}
__device__ inline float bf2f(ushort h) { return __uint_as_float(((uint)h) << 16); }

#define GLL16(gsrc, ldst)                                               \
  __builtin_amdgcn_global_load_lds(                                     \
      (const __attribute__((address_space(1))) void*)(gsrc),            \
      (__attribute__((address_space(3))) void*)(ldst), 16, 0, 0)

// ---------------- conv1: fp32 direct, writes blocked pre-BN bf16 hi/lo ----
__global__ __launch_bounds__(256) void conv1_k(
    const float* __restrict__ in, const float* __restrict__ w,
    ushort* __restrict__ oh, ushort* __restrict__ ol,
    float* __restrict__ stats)
{
  constexpr int KS = 3, ICC = 3, IHT = 10, IWT = 18;
  const int ocb = blockIdx.z & 3;
  const int b   = blockIdx.z >> 2;
  const int tx0 = blockIdx.x * 16;
  const int ty0 = blockIdx.y * 8;
  const int oc0 = ocb * 32;

  __shared__ float lin[ICC][IHT][IWT];
  __shared__ float lw[ICC][KS * KS][32];
  __shared__ float b1sum[32], b1sq[32];

  const int t  = threadIdx.x;
  const int pq = t & 3;
  const int ty = (t >> 2) & 7;
  const int oq = t >> 5;

  float acc[4][4];
#pragma unroll
  for (int m = 0; m < 4; ++m)
#pragma unroll
    for (int j = 0; j < 4; ++j) acc[m][j] = 0.f;

  const int gx0 = tx0 - 1;
  const int gy0 = ty0 - 1;

  for (int e = t; e < ICC * IHT * IWT; e += 256) {
    int ic = e / (IHT * IWT);
    int rr = e % (IHT * IWT);
    int ey = rr / IWT, ex = rr % IWT;
    int gy = gy0 + ey, gx = gx0 + ex;
    float v = 0.f;
    if ((unsigned)gy < 128u && (unsigned)gx < 128u)
      v = in[((size_t)(b * 3 + ic) * 128 + gy) * 128 + gx];
    lin[ic][ey][ex] = v;
  }
  for (int e = t; e < ICC * 9 * 32; e += 256) {
    int ocl = e & 31;
    int rr  = e >> 5;
    int kk  = rr % 9;
    int ic  = rr / 9;
    lw[ic][kk][ocl] = w[((size_t)(oc0 + ocl) * 3 + ic) * 9 + kk];
  }
  __syncthreads();

  for (int ic = 0; ic < ICC; ++ic) {
#pragma unroll
    for (int ky = 0; ky < KS; ++ky) {
#pragma unroll
      for (int kx = 0; kx < KS; ++kx) {
        float xv[4];
#pragma unroll
        for (int j = 0; j < 4; ++j)
          xv[j] = lin[ic][ty + ky][pq * 4 + j + kx];
        const float4 w4 = *(const float4*)&lw[ic][ky * KS + kx][oq * 4];
#pragma unroll
        for (int j = 0; j < 4; ++j) {
          acc[0][j] = fmaf(w4.x, xv[j], acc[0][j]);
          acc[1][j] = fmaf(w4.y, xv[j], acc[1][j]);
          acc[2][j] = fmaf(w4.z, xv[j], acc[2][j]);
          acc[3][j] = fmaf(w4.w, xv[j], acc[3][j]);
        }
      }
    }
  }

  const int oy = ty0 + ty;
  const int oc0q = oc0 + oq * 4;
  const size_t icb = oc0q >> 3;
  const int off = oc0q & 7;
  float sm[4] = {0.f, 0.f, 0.f, 0.f}, qm[4] = {0.f, 0.f, 0.f, 0.f};
#pragma unroll
  for (int j = 0; j < 4; ++j) {
    int px = tx0 + pq * 4 + j;
    size_t pxg = ((size_t)b * 128 + oy) * 128 + px;
    size_t addr = (icb * 131072 + pxg) * 8 + off;
    ushort h0 = f2bf(acc[0][j]); ushort l0 = f2bf(acc[0][j] - bf2f(h0));
    ushort h1 = f2bf(acc[1][j]); ushort l1 = f2bf(acc[1][j] - bf2f(h1));
    ushort h2 = f2bf(acc[2][j]); ushort l2 = f2bf(acc[2][j] - bf2f(h2));
    ushort h3 = f2bf(acc[3][j]); ushort l3 = f2bf(acc[3][j] - bf2f(h3));
    uint2 uh; uh.x = (uint)h0 | ((uint)h1 << 16); uh.y = (uint)h2 | ((uint)h3 << 16);
    uint2 ul; ul.x = (uint)l0 | ((uint)l1 << 16); ul.y = (uint)l2 | ((uint)l3 << 16);
    *(uint2*)(oh + addr) = uh;
    *(uint2*)(ol + addr) = ul;
    float v0 = bf2f(h0) + bf2f(l0), v1 = bf2f(h1) + bf2f(l1);
    float v2 = bf2f(h2) + bf2f(l2), v3 = bf2f(h3) + bf2f(l3);
    sm[0] += v0; qm[0] += v0 * v0;
    sm[1] += v1; qm[1] += v1 * v1;
    sm[2] += v2; qm[2] += v2 * v2;
    sm[3] += v3; qm[3] += v3 * v3;
  }
#pragma unroll
  for (int o = 16; o > 0; o >>= 1) {
#pragma unroll
    for (int m = 0; m < 4; ++m) {
      sm[m] += __shfl_xor(sm[m], o);
      qm[m] += __shfl_xor(qm[m], o);
    }
  }
  if ((t & 31) == 0) {
#pragma unroll
    for (int m = 0; m < 4; ++m) { b1sum[oq * 4 + m] = sm[m]; b1sq[oq * 4 + m] = qm[m]; }
  }
  __syncthreads();
  if (t < 32) {
    atomicAdd(&stats[oc0 + t], b1sum[t]);
    atomicAdd(&stats[128 + oc0 + t], b1sq[t]);
  }
}

// ---- in-place BN+LReLU on blocked bf16 hi/lo x1 (fin inline) ----
__global__ __launch_bounds__(256) void bn_apply_x1_k(
    ushort* __restrict__ xh, ushort* __restrict__ xl,
    const float* __restrict__ stats, const float* __restrict__ g,
    const float* __restrict__ bt)
{
  __shared__ float scs[128], sfs[128];
  const int t = threadIdx.x;
  if (t < 128) {
    float m = stats[t] * (1.f / 131072.f);
    float v = stats[128 + t] * (1.f / 131072.f) - m * m;
    float rs = rsqrtf(v + 1e-5f);
    float sc = g[t] * rs;
    scs[t] = sc; sfs[t] = bt[t] - m * sc;
  }
  __syncthreads();
  const size_t total = (size_t)16 * 131072;
  const size_t stride = (size_t)gridDim.x * 256;
  for (size_t i = (size_t)blockIdx.x * 256 + t; i < total; i += stride) {
    int j = (int)(i >> 17);
    int c0 = j * 8;
    uint4 vh = *(const uint4*)(xh + i * 8);
    uint4 vl = *(const uint4*)(xl + i * 8);
    uint hw[4] = {vh.x, vh.y, vh.z, vh.w};
    uint lw[4] = {vl.x, vl.y, vl.z, vl.w};
    uint ohv[4], olv[4];
#pragma unroll
    for (int m = 0; m < 4; ++m) {
      float f0 = __uint_as_float(hw[m] << 16) + __uint_as_float(lw[m] << 16);
      float f1 = __uint_as_float(hw[m] & 0xffff0000u) + __uint_as_float(lw[m] & 0xffff0000u);
      float a0 = fmaf(f0, scs[c0 + 2*m],   sfs[c0 + 2*m]);   a0 = fmaxf(a0, 0.1f * a0);
      float a1 = fmaf(f1, scs[c0 + 2*m+1], sfs[c0 + 2*m+1]); a1 = fmaxf(a1, 0.1f * a1);
      ushort h0 = f2bf(a0), l0 = f2bf(a0 - bf2f(h0));
      ushort h1 = f2bf(a1), l1 = f2bf(a1 - bf2f(h1));
      ohv[m] = (uint)h0 | ((uint)h1 << 16);
      olv[m] = (uint)l0 | ((uint)l1 << 16);
    }
    uint4 rh = {ohv[0], ohv[1], ohv[2], ohv[3]};
    uint4 rl = {olv[0], olv[1], olv[2], olv[3]};
    *(uint4*)(xh + i * 8) = rh;
    *(uint4*)(xl + i * 8) = rl;
  }
}

__global__ __launch_bounds__(256) void bn_stats_nhwc_k(
    const float* __restrict__ x, float* __restrict__ stats,
    int cmask, int lg2c, int totpx)
{
  int g = blockIdx.x * 256 + threadIdx.x;
  int c = g & cmask;
  int p0 = g >> lg2c;
  int stride = (gridDim.x * 256) >> lg2c;
  float s = 0.f, q = 0.f;
  for (int p = p0; p < totpx; p += stride) {
    float v = x[((size_t)p << lg2c) | c];
    s += v; q += v * v;
  }
  atomicAdd(&stats[c], s);
  atomicAdd(&stats[cmask + 1 + c], q);
}

// ---- BN+LReLU+split fp32 NHWC -> blocked bf16 hi/lo (inline fin) ----
template<int C>
__global__ __launch_bounds__(256) void split_blocked_k(
    const float* __restrict__ h, const float* __restrict__ stats,
    const float* __restrict__ g, const float* __restrict__ bt, float inv_n,
    ushort* __restrict__ oh, ushort* __restrict__ ol, int totpx)
{
  __shared__ ushort lh[16][C + 8], ll[16][C + 8];
  __shared__ float scs[C], sfs[C];
  const int px0 = blockIdx.x * 16;
  const int t = threadIdx.x;
  if (t < C) {
    float m = stats[t] * inv_n;
    float v = stats[C + t] * inv_n - m * m;
    float rs = rsqrtf(v + 1e-5f);
    float sc = g[t] * rs;
    scs[t] = sc; sfs[t] = bt[t] - m * sc;
  }
  __syncthreads();
  for (int e = t; e < 16 * C / 4; e += 256) {
    int px = e / (C / 4);
    int c0 = (e % (C / 4)) * 4;
    float4 v  = *(const float4*)(h + (size_t)(px0 + px) * C + c0);
    float a0 = fmaf(v.x, scs[c0],   sfs[c0]);   a0 = fmaxf(a0, 0.1f * a0);
    float a1 = fmaf(v.y, scs[c0+1], sfs[c0+1]); a1 = fmaxf(a1, 0.1f * a1);
    float a2 = fmaf(v.z, scs[c0+2], sfs[c0+2]); a2 = fmaxf(a2, 0.1f * a2);
    float a3 = fmaf(v.w, scs[c0+3], sfs[c0+3]); a3 = fmaxf(a3, 0.1f * a3);
    ushort h0 = f2bf(a0), h1 = f2bf(a1), h2v = f2bf(a2), h3v = f2bf(a3);
    lh[px][c0]   = h0;  ll[px][c0]   = f2bf(a0 - bf2f(h0));
    lh[px][c0+1] = h1;  ll[px][c0+1] = f2bf(a1 - bf2f(h1));
    lh[px][c0+2] = h2v; ll[px][c0+2] = f2bf(a2 - bf2f(h2v));
    lh[px][c0+3] = h3v; ll[px][c0+3] = f2bf(a3 - bf2f(h3v));
  }
  __syncthreads();
  for (int e = t; e < 16 * (C / 8); e += 256) {
    int j = e >> 4, px = e & 15;
    *(uint4*)(oh + ((size_t)j * totpx + px0 + px) * 8) = *(const uint4*)&lh[px][j * 8];
    *(uint4*)(ol + ((size_t)j * totpx + px0 + px) * 8) = *(const uint4*)&ll[px][j * 8];
  }
}

// ------- all weight splits merged; FRAGMENT-ORDERED layouts -------
__global__ void wsplit_all_k(
    const float* __restrict__ c2w, const float* __restrict__ c3w,
    const float* __restrict__ c4w, const float* __restrict__ c5w,
    ushort* __restrict__ wph, ushort* __restrict__ wpl,
    ushort* __restrict__ w3h, ushort* __restrict__ w3l,
    ushort* __restrict__ w4h, ushort* __restrict__ w4l,
    ushort* __restrict__ w5h, ushort* __restrict__ w5l)
{
  int i = blockIdx.x * 256 + threadIdx.x;
  if (i < 294912) {
    int kk = i % 9; int r = i / 9; int ic = r & 127; int oc = r >> 7;
    float v = c2w[i];
    ushort hi = f2bf(v), lo = f2bf(v - bf2f(hi));
    int ohf = oc >> 7, of = (oc >> 4) & 7, lr = oc & 15;
    int ic32 = ic >> 5, kg = (ic >> 3) & 3, ici = ic & 7;
    size_t d = ((((size_t)(kk * 4 + ic32) * 2 + ohf) * 8 + of) * 4 + kg) * 128
               + lr * 8 + ici;
    wph[d] = hi; wpl[d] = lo;
    return;
  }
  i -= 294912;
  const float* w; ushort *wh, *wl; int OC, IC, n;
  if (i < 262144)      { w = c3w; wh = w3h; wl = w3l; OC = 64;  IC = 256; n = i; }
  else if (i < 393216) { w = c4w; wh = w4h; wl = w4l; OC = 128; IC = 64;  n = i - 262144; }
  else if (i < 917504) { w = c5w; wh = w5h; wl = w5l; OC = 256; IC = 128; n = i - 393216; }
  else return;
  int kx = n & 3, ky = (n >> 2) & 3;
  int ic = (n >> 4) % IC, oc = (n >> 4) / IC;
  float v = w[n];
  ushort hi = f2bf(v), lo = f2bf(v - bf2f(hi));
  int NCH = IC >> 3, NWO = OC >> 6;
  int wo = oc >> 6, of = (oc >> 4) & 3, lr = oc & 15;
  int ch = ic >> 3, ici = ic & 7;
  size_t d = ((((size_t)(ky * NCH + ch) * NWO + wo) * 4 + of) * 4 + kx) * 128
             + lr * 8 + ici;
  wh[d] = hi; wl[d] = lo;
}

// ---- conv2 X staging: async global->LDS, byte-verbatim (x1 already BN'd) ----
__device__ __forceinline__ void stage_x(
    const ushort* __restrict__ x1h, const ushort* __restrict__ x1l,
    const ushort* __restrict__ zbuf,
    ushort* xh_dst, ushort* xl_dst, int t, int b, int gy, int ic32)
{
  const bool rowok = (unsigned)gy < 128u;
  const size_t rowb = ((size_t)b * 128 + (rowok ? gy : 0)) * 128;
#pragma unroll
  for (int k = 0; k < 2; ++k) {
    int e = t + k * 256;
    int icg = e / 130;
    int xi = e - icg * 130;
    int gx = xi - 1;
    const ushort* sh = zbuf;
    const ushort* sl = zbuf;
    if (rowok && (unsigned)gx < 128u) {
      size_t gi = ((size_t)(ic32 * 4 + icg) * 131072 + rowb + gx) * 8;
      sh = x1h + gi; sl = x1l + gi;
    }
    GLL16(sh, xh_dst + (size_t)e * 8);
    GLL16(sl, xl_dst + (size_t)e * 8);
  }
  if (t < 8) {
    int e = 512 + t;
    int xi = e - 390;          // icg = 3
    int gx = xi - 1;
    const ushort* sh = zbuf;
    const ushort* sl = zbuf;
    if (rowok && (unsigned)gx < 128u) {
      size_t gi = ((size_t)(ic32 * 4 + 3) * 131072 + rowb + gx) * 8;
      sh = x1h + gi; sl = x1l + gi;
    }
    GLL16(sh, xh_dst + (size_t)e * 8);
    GLL16(sl, xl_dst + (size_t)e * 8);
  }
}

// ------- conv2 via MFMA (bf16x3): async dbuf X staging, W from global -------
// 1 row x 128 px x 256 oc per block; XCD swizzle; stats fold-in epilogue.
// (round-8 proven structure: 2 buffers, issue-next-then-compute, __syncthreads)
__global__ __launch_bounds__(256, 2) void conv2_mfma_k(
    const ushort* __restrict__ x1h, const ushort* __restrict__ x1l,
    const ushort* __restrict__ wph, const ushort* __restrict__ wpl,
    const ushort* __restrict__ zbuf, float* __restrict__ stats2,
    ushort* __restrict__ x3h, ushort* __restrict__ x3l)
{
  const int bid = blockIdx.x;                 // 1024 blocks
  const int wid = (bid & 7) * 128 + (bid >> 3);
  const int y0  = wid & 127;
  const int b   = wid >> 7;

  __shared__ ushort xs[2][2][4][130][8];   // [buf][hl][icg][xi][8] : 33,280 B
  __shared__ float bsum[2][256], bsq[2][256];

  const int t = threadIdx.x;
  const int w  = t >> 6;
  const int l  = t & 63;
  const int xhf = w & 1;
  const int ohf = w >> 1;
  const int lr = l & 15;
  const int kg = l >> 4;

  f32x4 acc[8][4];
#pragma unroll
  for (int i = 0; i < 8; ++i)
#pragma unroll
    for (int j = 0; j < 4; ++j) acc[i][j] = (f32x4){0.f, 0.f, 0.f, 0.f};

  // prologue: stage phase 0 into buf 0
  stage_x(x1h, x1l, zbuf, (ushort*)&xs[0][0][0][0][0], (ushort*)&xs[0][1][0][0][0],
          t, b, y0 - 1, 0);
  __syncthreads();

  for (int ky = 0; ky < 3; ++ky) {
    for (int ic32 = 0; ic32 < 4; ++ic32) {
      const int buf = ic32 & 1;     // p = ky*4+ic32, ky*4 even
      // issue next phase's loads (async; drained by this phase's end barrier)
      const int np = ky * 4 + ic32 + 1;
      if (np < 12) {
        const int nbuf = buf ^ 1;
        stage_x(x1h, x1l, zbuf,
                (ushort*)&xs[nbuf][0][0][0][0], (ushort*)&xs[nbuf][1][0][0][0],
                t, b, y0 + (np >> 2) - 1, np & 3);
      }
#pragma unroll
      for (int kx = 0; kx < 3; ++kx) {
        const int kk = ky * 3 + kx;
        const size_t wbase =
            ((size_t)((kk * 4 + ic32) * 2 + ohf)) * 4096 + (size_t)l * 8;
        const ushort* pwh = wph + wbase;
        const ushort* pwl = wpl + wbase;

        bf16x8 xbh[4], xbl[4];
#pragma unroll
        for (int pf = 0; pf < 4; ++pf) {
          int xi = xhf * 64 + pf * 16 + lr + kx;
          xbh[pf] = *(const bf16x8*)&xs[buf][0][kg][xi][0];
          xbl[pf] = *(const bf16x8*)&xs[buf][1][kg][xi][0];
        }
#pragma unroll
        for (int oh2 = 0; oh2 < 2; ++oh2) {
          bf16x8 awh[4], awl[4];
#pragma unroll
          for (int o4 = 0; o4 < 4; ++o4) {
            awh[o4] = *(const bf16x8*)(pwh + (oh2 * 4 + o4) * 512);
            awl[o4] = *(const bf16x8*)(pwl + (oh2 * 4 + o4) * 512);
          }
#pragma unroll
          for (int o4 = 0; o4 < 4; ++o4) {
            const int of = oh2 * 4 + o4;
#pragma unroll
            for (int pf = 0; pf < 4; ++pf) {
              acc[of][pf] = __builtin_amdgcn_mfma_f32_16x16x32_bf16(awh[o4], xbh[pf], acc[of][pf], 0, 0, 0);
              acc[of][pf] = __builtin_amdgcn_mfma_f32_16x16x32_bf16(awh[o4], xbl[pf], acc[of][pf], 0, 0, 0);
              acc[of][pf] = __builtin_amdgcn_mfma_f32_16x16x32_bf16(awl[o4], xbh[pf], acc[of][pf], 0, 0, 0);
            }
          }
        }
      }
      __syncthreads();   // drains next-phase global_load_lds, syncs LDS reuse
    }
  }

  // epilogue: quantize+store + per-oc stats (sum over px, shfl-reduced)
#pragma unroll
  for (int of = 0; of < 8; ++of) {
    float s4[4] = {0.f, 0.f, 0.f, 0.f}, q4[4] = {0.f, 0.f, 0.f, 0.f};
#pragma unroll
    for (int pf = 0; pf < 4; ++pf) {
      int oc = ohf * 128 + of * 16 + kg * 4;
      int x  = xhf * 64 + pf * 16 + lr;
      size_t pxg = ((size_t)b * 128 + y0) * 128 + x;
      size_t base = ((size_t)(oc >> 3) * 131072 + pxg) * 8 + (oc & 7);
      f32x4 a = acc[of][pf];
      ushort h0 = f2bf(a[0]); ushort l0 = f2bf(a[0] - bf2f(h0));
      ushort h1 = f2bf(a[1]); ushort l1 = f2bf(a[1] - bf2f(h1));
      ushort h2 = f2bf(a[2]); ushort l2 = f2bf(a[2] - bf2f(h2));
      ushort h3 = f2bf(a[3]); ushort l3 = f2bf(a[3] - bf2f(h3));
      uint2 uh; uh.x = (uint)h0 | ((uint)h1 << 16); uh.y = (uint)h2 | ((uint)h3 << 16);
      uint2 ul; ul.x = (uint)l0 | ((uint)l1 << 16); ul.y = (uint)l2 | ((uint)l3 << 16);
      *(uint2*)(x3h + base) = uh;
      *(uint2*)(x3l + base) = ul;
      float v0 = bf2f(h0) + bf2f(l0), v1 = bf2f(h1) + bf2f(l1);
      float v2 = bf2f(h2) + bf2f(l2), v3 = bf2f(h3) + bf2f(l3);
      s4[0] += v0; q4[0] += v0 * v0;
      s4[1] += v1; q4[1] += v1 * v1;
      s4[2] += v2; q4[2] += v2 * v2;
      s4[3] += v3; q4[3] += v3 * v3;
    }
#pragma unroll
    for (int o = 8; o > 0; o >>= 1) {
#pragma unroll
      for (int j = 0; j < 4; ++j) {
        s4[j] += __shfl_xor(s4[j], o);
        q4[j] += __shfl_xor(q4[j], o);
      }
    }
    if (lr == 0) {
      int oc = ohf * 128 + of * 16 + kg * 4;
#pragma unroll
      for (int j = 0; j < 4; ++j) { bsum[xhf][oc + j] = s4[j]; bsq[xhf][oc + j] = q4[j]; }
    }
  }
  __syncthreads();
  if (t < 256) {
    atomicAdd(&stats2[t],       bsum[0][t] + bsum[1][t]);
    atomicAdd(&stats2[256 + t], bsq[0][t] + bsq[1][t]);
  }
}

// ------- conv3/4/5 via MFMA, K-split, W fragments from global -------
template<int IC, int OC, int OH, int OW, int WPX, int CS, bool FBN>
__global__ __launch_bounds__(256, 2) void convs_mfma_k(
    const ushort* __restrict__ xh, const ushort* __restrict__ xl,
    const ushort* __restrict__ wh, const ushort* __restrict__ wl,
    const float* __restrict__ stats, const float* __restrict__ gg,
    const float* __restrict__ bb, float inv_n,
    float* __restrict__ part)
{
  constexpr int IH  = 2 * OH, IW = 2 * OW;
  constexpr int NCH = IC / 8;
  constexpr int NCHB = NCH / CS;
  constexpr int PFX = OW / 16;
  constexpr int RW  = 4 / WPX;
  constexpr int NZ = 4 * CS;
  constexpr int NX = OH / 4;
  constexpr int NWO = OC / 64;
  constexpr int SBN = FBN ? IC : 1;

  const int bid = blockIdx.x;
  const int wid = (bid & 7) * (NZ * NX) + (bid >> 3);
  const int zi = wid % NZ;
  const int y0 = ((wid / NZ) % NX) * 4;
  const int b  = wid / (NZ * NX);
  const int ky = zi & 3;
  const int cs = zi >> 2;

  __shared__ ushort xs[2][4][2][OW + 2][8];
  __shared__ float scs[SBN], sfs[SBN];

  const int t = threadIdx.x;
  if (FBN) {
    for (int c = t; c < IC; c += 256) {
      float m = stats[c] * inv_n;
      float v = stats[IC + c] * inv_n - m * m;
      float rs = rsqrtf(v + 1e-5f);
      float sc = gg[c] * rs;
      scs[c] = sc; sfs[c] = bb[c] - m * sc;
    }
  }

  const int w = t >> 6, l = t & 63;
  const int wo = w / WPX, wp = w % WPX;
  const int lr = l & 15, kg = l >> 4;
  const int oc0w = wo * 64;
  const int rb = wp * RW;

  f32x4 acc[4][4];
#pragma unroll
  for (int i = 0; i < 4; ++i)
#pragma unroll
    for (int j = 0; j < 4; ++j) acc[i][j] = (f32x4){0.f, 0.f, 0.f, 0.f};

  for (int cc = 0; cc < NCHB; ++cc) {
    const int ch = cs * NCHB + cc;
    __syncthreads();
    for (int e = t; e < 4 * (IW + 2); e += 256) {
      int r  = e / (IW + 2);
      int xi = e % (IW + 2);
      int xp = xi - 1;
      int iy = 2 * (y0 + r) + ky - 1;
      uint4 rh = {0, 0, 0, 0}, rl = {0, 0, 0, 0};
      if ((unsigned)iy < (unsigned)IH && (unsigned)xp < (unsigned)IW) {
        size_t gi = ((((size_t)ch * 8 + b) * IH + iy) * IW + xp) * 8;
        uint4 vh = *(const uint4*)(xh + gi);
        uint4 vl = *(const uint4*)(xl + gi);
        if (FBN) {
          int c0 = ch * 8;
          uint hw[4] = {vh.x, vh.y, vh.z, vh.w};
          uint lw[4] = {vl.x, vl.y, vl.z, vl.w};
          uint ohv[4], olv[4];
#pragma unroll
          for (int m = 0; m < 4; ++m) {
            float f0 = __uint_as_float(hw[m] << 16) + __uint_as_float(lw[m] << 16);
            float f1 = __uint_as_float(hw[m] & 0xffff0000u) + __uint_as_float(lw[m] & 0xffff0000u);
            float a0 = fmaf(f0, scs[c0 + 2*m],   sfs[c0 + 2*m]);   a0 = fmaxf(a0, 0.1f * a0);
            float a1 = fmaf(f1, scs[c0 + 2*m+1], sfs[c0 + 2*m+1]); a1 = fmaxf(a1, 0.1f * a1);
            ushort h0 = f2bf(a0), l0 = f2bf(a0 - bf2f(h0));
            ushort h1 = f2bf(a1), l1 = f2bf(a1 - bf2f(h1));
            ohv[m] = (uint)h0 | ((uint)h1 << 16);
            olv[m] = (uint)l0 | ((uint)l1 << 16);
          }
          rh.x = ohv[0]; rh.y = ohv[1]; rh.z = ohv[2]; rh.w = ohv[3];
          rl.x = olv[0]; rl.y = olv[1]; rl.z = olv[2]; rl.w = olv[3];
        } else {
          rh = vh; rl = vl;
        }
      }
      int par = xp & 1;
      int idx = (xp + 1) >> 1;
      *(uint4*)&xs[0][r][par][idx][0] = rh;
      *(uint4*)&xs[1][r][par][idx][0] = rl;
    }
    __syncthreads();

    const size_t wbase =
        ((size_t)(ky * NCH + ch) * NWO + wo) * 2048 + (size_t)l * 8;
    bf16x8 ah[4], al[4], bh[4], bl[4];
#pragma unroll
    for (int of = 0; of < 4; ++of) {
      ah[of] = *(const bf16x8*)(wh + wbase + of * 512);
      al[of] = *(const bf16x8*)(wl + wbase + of * 512);
    }
    const int par = 1 - (kg & 1);
    const int xoff = kg >> 1;
#pragma unroll
    for (int pf = 0; pf < 4; ++pf) {
      int row = rb + pf / PFX;
      int x   = (pf % PFX) * 16 + lr;
      bh[pf] = *(const bf16x8*)&xs[0][row][par][x + xoff][0];
      bl[pf] = *(const bf16x8*)&xs[1][row][par][x + xoff][0];
    }
#pragma unroll
    for (int of = 0; of < 4; ++of) {
#pragma unroll
      for (int pf = 0; pf < 4; ++pf) {
        acc[of][pf] = __builtin_amdgcn_mfma_f32_16x16x32_bf16(ah[of], bh[pf], acc[of][pf], 0, 0, 0);
        acc[of][pf] = __builtin_amdgcn_mfma_f32_16x16x32_bf16(ah[of], bl[pf], acc[of][pf], 0, 0, 0);
        acc[of][pf] = __builtin_amdgcn_mfma_f32_16x16x32_bf16(al[of], bh[pf], acc[of][pf], 0, 0, 0);
      }
    }
  }

  float* yp = part + (size_t)zi * (8 * OH * OW * OC);
#pragma unroll
  for (int of = 0; of < 4; ++of) {
#pragma unroll
    for (int pf = 0; pf < 4; ++pf) {
      int row = rb + pf / PFX;
      int x   = (pf % PFX) * 16 + lr;
      int oc  = oc0w + of * 16 + kg * 4;
      float* p = yp + (((size_t)b * OH + y0 + row) * OW + x) * OC + oc;
      f32x4 a = acc[of][pf];
      float4 v = {a[0], a[1], a[2], a[3]};
      *(float4*)p = v;
    }
  }
}

// ------- reduce partials -> h (float4) -------
__global__ __launch_bounds__(256) void reduce_k(
    const float* __restrict__ part, float* __restrict__ h,
    int n4, int nparts)
{
  int i = blockIdx.x * 256 + threadIdx.x;
  if (i >= n4) return;
  float4 a = ((const float4*)part)[i];
  for (int z = 1; z < nparts; ++z) {
    float4 b = ((const float4*)part)[(size_t)z * n4 + i];
    a.x += b.x; a.y += b.y; a.z += b.z; a.w += b.w;
  }
  ((float4*)h)[i] = a;
}

// ---------------- capsule rearrange (h5 NHWC, BN inline) ----------------
__global__ void caps_k(const float* __restrict__ h5, const float* __restrict__ stats,
                       const float* __restrict__ g5, const float* __restrict__ b5,
                       float* __restrict__ caps)
{
  int e = blockIdx.x * 256 + threadIdx.x;
  if (e >= NB * NCAP * 8) return;
  int ii = e & 7;
  int n  = (e >> 3) & 511;
  int jb = e >> 12;
  int j = jb >> 3, b = jb & 7;
  int i = n >> 7, k = (n >> 5) & 3, ch = ((n & 31) << 3) | ii;
  int hh = (i << 2) | (j >> 2);
  int ww = ((j & 3) << 2) | k;
  float m  = stats[ch] * (1.f / 2048.f);
  float vv = stats[256 + ch] * (1.f / 2048.f) - m * m;
  float rs = rsqrtf(vv + 1e-5f);
  float sc = g5[ch] * rs;
  float sf = b5[ch] - m * sc;
  float v = h5[(((size_t)b * 16 + hh) * 16 + ww) * 256 + ch];
  float a = fmaf(v, sc, sf);
  a = fmaxf(a, 0.1f * a);
  caps[e] = a;
}

// ---------------- priors (bf16 output) ----------------
__global__ __launch_bounds__(256) void priors_k(
    const float* __restrict__ caps, const float* __restrict__ rw,
    ushort* __restrict__ priors)
{
  const int n = blockIdx.x;
  __shared__ float lrw[NCLS * 8 * NO];
  __shared__ float lc[NB * 8];
  const int t = threadIdx.x;
  for (int e = t; e < NCLS * 8 * NO; e += 256)
    lrw[e] = rw[(size_t)n * NCLS * 8 * NO + e];
  for (int e = t; e < NB * 8; e += 256) {
    int b = e >> 3, ii = e & 7;
    lc[e] = caps[((size_t)b * NCAP + n) * 8 + ii];
  }
  __syncthreads();

  int p[4], kk[4], oo[4];
#pragma unroll
  for (int q = 0; q < 4; ++q) {
    p[q]  = t + q * 256;
    kk[q] = (p[q] < KO) ? p[q] / NO : 0;
    oo[q] = (p[q] < KO) ? p[q] % NO : 0;
  }
  for (int b = 0; b < NB; ++b) {
    const float* cb = &lc[b * 8];
    float c0 = cb[0], c1 = cb[1], c2 = cb[2], c3 = cb[3];
    float c4 = cb[4], c5 = cb[5], c6 = cb[6], c7 = cb[7];
    ushort* pout = priors + ((size_t)b * NCAP + n) * KO;
#pragma unroll
    for (int q = 0; q < 4; ++q) {
      if (p[q] < KO) {
        const float* wv = &lrw[kk[q] * (8 * NO) + oo[q]];
        float a = c0 * wv[0];
        a = fmaf(c1, wv[21],  a);
        a = fmaf(c2, wv[42],  a);
        a = fmaf(c3, wv[63],  a);
        a = fmaf(c4, wv[84],  a);
        a = fmaf(c5, wv[105], a);
        a = fmaf(c6, wv[126], a);
        a = fmaf(c7, wv[147], a);
        pout[p[q]] = f2bf(a);
      }
    }
  }
}

// ---------------- routing ----------------
__global__ __launch_bounds__(256) void route_s_partial(
    const ushort* __restrict__ priors, float* __restrict__ s)
{
  const int b  = blockIdx.x >> 3;
  const int ns = blockIdx.x & 7;
  const int t  = threadIdx.x;
  const int p0 = t, p1 = t + 256, p2 = t + 512, p3 = t + 768;
  float a0 = 0.f, a1 = 0.f, a2 = 0.f, a3 = 0.f;
  const ushort* pb = priors + ((size_t)b * NCAP + ns * 64) * KO;
#pragma unroll 2
  for (int n = 0; n < 64; ++n) {
    const ushort* pn = pb + (size_t)n * KO;
    a0 += bf2f(pn[p0]); a1 += bf2f(pn[p1]); a2 += bf2f(pn[p2]);
    if (p3 < KO) a3 += bf2f(pn[p3]);
  }
  const float sc = 1.f / 43.f;
  atomicAdd(&s[b * KO + p0], a0 * sc);
  atomicAdd(&s[b * KO + p1], a1 * sc);
  atomicAdd(&s[b * KO + p2], a2 * sc);
  if (p3 < KO) atomicAdd(&s[b * KO + p3], a3 * sc);
}

// fused logits+softmax+s: barrier-free, lane k owns class k, wave-local LDS
__global__ __launch_bounds__(256) void route_iter_k(
    const ushort* __restrict__ priors, const float* __restrict__ souts,
    float* __restrict__ logits, float* __restrict__ s,
    int readPrev, int writeL)
{
  const int b  = blockIdx.x >> 3;
  const int ns = blockIdx.x & 7;
  const int t  = threadIdx.x;
  const int w  = t >> 6;
  const int lane = t & 63;
  const bool act = lane < NCLS;

  __shared__ float prow[4][928];   // per-wave row buffer; reused as reduce buf

  float so[NO], sacc[NO], v[NO];
  if (act) {
#pragma unroll
    for (int o = 0; o < NO; ++o) so[o] = souts[b * KO + lane * NO + o];
  }
#pragma unroll
  for (int o = 0; o < NO; ++o) { sacc[o] = 0.f; v[o] = 0.f; }

  for (int nn = 0; nn < 16; ++nn) {
    const int n = ns * 64 + w * 16 + nn;
    const ushort* pr = priors + ((size_t)(b * NCAP + n)) * KO;
#pragma unroll
    for (int q = 0; q < 15; ++q) {
      int e = lane + q * 64;
      if (e < KO) prow[w][e] = bf2f(pr[e]);
    }
    // wave-local LDS exchange: ds ops in-order per wave, no barrier needed
    float L = -1e30f;
    if (act) {
      float d = 0.f;
#pragma unroll
      for (int o = 0; o < NO; ++o) v[o] = prow[w][lane * NO + o];
#pragma unroll
      for (int o = 0; o < NO; ++o) d = fmaf(v[o], so[o], d);
      size_t lidx = ((size_t)(b * NCAP + n)) * NCLS + lane;
      L = (readPrev ? logits[lidx] : 0.f) + d;
      if (writeL) logits[lidx] = L;
    }
    float m = L;
#pragma unroll
    for (int off = 32; off > 0; off >>= 1) m = fmaxf(m, __shfl_xor(m, off));
    float ex = act ? __expf(L - m) : 0.f;
    float sm = ex;
#pragma unroll
    for (int off = 32; off > 0; off >>= 1) sm += __shfl_xor(sm, off);
    float pk = ex / sm;
    if (act) {
#pragma unroll
      for (int o = 0; o < NO; ++o) sacc[o] = fmaf(pk, v[o], sacc[o]);
    }
  }
  // cross-wave reduce via LDS (prow reused), then one atomic per element
  if (act) {
#pragma unroll
    for (int o = 0; o < NO; ++o) prow[w][lane * NO + o] = sacc[o];
  }
  __syncthreads();
  for (int e = t; e < KO; e += 256)
    atomicAdd(&s[b * KO + e], prow[0][e] + prow[1][e] + prow[2][e] + prow[3][e]);
}

__global__ void squash_k(const float* __restrict__ s, float* __restrict__ souts)
{
  int i = blockIdx.x * 256 + threadIdx.x;
  if (i >= NB * NCLS) return;
  int b = i / NCLS, k = i % NCLS;
  const float* sv = s + b * KO + k * NO;
  float sn = 0.f;
#pragma unroll
  for (int o = 0; o < NO; ++o) sn += sv[o] * sv[o];
  float f = sqrtf(sn) / (1.f + sn);
  float* ov = souts + b * KO + k * NO;
#pragma unroll
  for (int o = 0; o < NO; ++o) ov[o] = sv[o] * f;
}

__global__ void out_k(const float* __restrict__ souts, float* __restrict__ out)
{
  int i = blockIdx.x * 256 + threadIdx.x;
  if (i >= 8 * 16 * NCLS * NO) return;
  int o = i % NO;
  int r = i / NO;
  int k = r % NCLS; r /= NCLS;
  int g1 = r & 3; r >>= 2;
  int g0 = r & 3;
  int b  = r >> 2;
  int j  = g0 * 4 + g1;
  int jb = j * 8 + b;
  out[i] = souts[jb * KO + k * NO + o];
}

// ---------------- launcher ----------------
extern "C" void kernel_launch(void* const* d_in, const int* in_sizes, int n_in,
                              void* d_out, int out_size, void* d_ws, size_t ws_size,
                              hipStream_t stream)
{
  const float* x   = (const float*)d_in[0];
  const float* c1w = (const float*)d_in[1];
  const float* g1  = (const float*)d_in[3];  const float* b1  = (const float*)d_in[4];
  const float* c2w = (const float*)d_in[5];
  const float* g2  = (const float*)d_in[7];  const float* b2  = (const float*)d_in[8];
  const float* c3w = (const float*)d_in[9];
  const float* g3  = (const float*)d_in[11]; const float* b3  = (const float*)d_in[12];
  const float* c4w = (const float*)d_in[13];
  const float* g4  = (const float*)d_in[15]; const float* b4  = (const float*)d_in[16];
  const float* c5w = (const float*)d_in[17];
  const float* g5  = (const float*)d_in[19]; const float* b5  = (const float*)d_in[20];
  const float* rw  = (const float*)d_in[21];

  float* ws  = (float*)d_ws;
  float* out = (float*)d_out;

  ushort* x1h = (ushort*)(ws + F_X1H);
  ushort* x1l = (ushort*)(ws + F_X1L);
  ushort* wph = (ushort*)(ws + F_WPH);
  ushort* wpl = (ushort*)(ws + F_WPL);
  ushort* w3h = (ushort*)(ws + F_W3H);
  ushort* w3l = (ushort*)(ws + F_W3L);
  ushort* w4h = (ushort*)(ws + F_W4H);
  ushort* w4l = (ushort*)(ws + F_W4L);
  ushort* w5h = (ushort*)(ws + F_W5H);
  ushort* w5l = (ushort*)(ws + F_W5L);
  ushort* x3h = (ushort*)(ws + F_X3H);
  ushort* x3l = (ushort*)(ws + F_X3L);
  ushort* x4h = (ushort*)(ws + F_X4H);
  ushort* x4l = (ushort*)(ws + F_X4L);
  ushort* x5h = (ushort*)(ws + F_X5H);
  ushort* x5l = (ushort*)(ws + F_X5L);
  float* part   = ws + F_PART;
  float* h3     = ws + F_H3;
  float* h4     = ws + F_H4;
  float* h5     = ws + F_H5;
  float* caps   = ws + F_CAPS;
  ushort* priors = (ushort*)(ws + F_PRI);
  float* logits = ws + F_LOG;
  float* sbuf   = ws + F_S;
  float* souts  = ws + F_OUTS;
  float* stats  = ws + F_STAT;          // conv1 stats [0..255]; scratch [0..511]
  float* stats2 = ws + F_STAT + 512;    // conv2 stats [0..511]
  ushort* zbuf  = (ushort*)(ws + F_ZERO);

  // ---- init: zero stats and the OOB zero stub ----
  hipMemsetAsync(stats, 0, 1024 * sizeof(float), stream);
  hipMemsetAsync(zbuf, 0, 64, stream);

  // ---- weight preps (merged, fragment-ordered) ----
  wsplit_all_k<<<(1212416 + 255) / 256, 256, 0, stream>>>(
      c2w, c3w, c4w, c5w, wph, wpl, w3h, w3l, w4h, w4l, w5h, w5l);

  // ---- conv1 -> blocked pre-BN bf16 hi/lo (stats folded in) ----
  conv1_k<<<dim3(8, 16, 32), 256, 0, stream>>>(x, c1w, x1h, x1l, stats);

  // ---- BN+LReLU applied in place to x1 ----
  bn_apply_x1_k<<<2048, 256, 0, stream>>>(x1h, x1l, stats, g1, b1);

  // ---- conv2 (MFMA, async dbuf staging, W from global, XCD swizzle) ----
  conv2_mfma_k<<<1024, 256, 0, stream>>>(x1h, x1l, wph, wpl, zbuf, stats2, x3h, x3l);

  // ---- conv3 (MFMA, ky-split x4, BN of x3 fused via stats2) ----
  convs_mfma_k<256, 64, 64, 64, 4, 1, true><<<512, 256, 0, stream>>>(
      x3h, x3l, w3h, w3l, stats2, g2, b2, 1.f / 131072.f, part);
  reduce_k<<<(524288 + 255) / 256, 256, 0, stream>>>(part, h3, 524288, 4);
  hipMemsetAsync(stats, 0, 2 * 64 * sizeof(float), stream);
  bn_stats_nhwc_k<<<256, 256, 0, stream>>>(h3, stats, 63, 6, 32768);
  split_blocked_k<64><<<2048, 256, 0, stream>>>(h3, stats, g3, b3, 1.f / 32768.f, x4h, x4l, 32768);

  // ---- conv4 (MFMA, (ky x ch/2)-split x8) ----
  convs_mfma_k<64, 128, 32, 32, 2, 2, false><<<512, 256, 0, stream>>>(
      x4h, x4l, w4h, w4l, stats, g4, b4, 0.f, part);
  reduce_k<<<(262144 + 255) / 256, 256, 0, stream>>>(part, h4, 262144, 8);
  hipMemsetAsync(stats, 0, 2 * 128 * sizeof(float), stream);
  bn_stats_nhwc_k<<<128, 256, 0, stream>>>(h4, stats, 127, 7, 8192);
  split_blocked_k<128><<<512, 256, 0, stream>>>(h4, stats, g4, b4, 1.f / 8192.f, x5h, x5l, 8192);

  // ---- conv5 (MFMA, (ky x ch/2)-split x8) ----
  convs_mfma_k<128, 256, 16, 16, 1, 2, false><<<256, 256, 0, stream>>>(
      x5h, x5l, w5h, w5l, stats, g5, b5, 0.f, part);
  reduce_k<<<(131072 + 255) / 256, 256, 0, stream>>>(part, h5, 131072, 8);
  hipMemsetAsync(stats, 0, 2 * 256 * sizeof(float), stream);
  bn_stats_nhwc_k<<<64, 256, 0, stream>>>(h5, stats, 255, 8, 2048);

  // ---- capsules ----
  caps_k<<<2048, 256, 0, stream>>>(h5, stats, g5, b5, caps);
  priors_k<<<512, 256, 0, stream>>>(caps, rw, priors);

  // ---- routing: 3 iterations ----
  hipMemsetAsync(sbuf, 0, NB * KO * sizeof(float), stream);
  route_s_partial<<<NB * 8, 256, 0, stream>>>(priors, sbuf);
  squash_k<<<(NB * NCLS + 255) / 256, 256, 0, stream>>>(sbuf, souts);

  hipMemsetAsync(sbuf, 0, NB * KO * sizeof(float), stream);
  route_iter_k<<<NB * 8, 256, 0, stream>>>(priors, souts, logits, sbuf, 0, 1);
  squash_k<<<(NB * NCLS + 255) / 256, 256, 0, stream>>>(sbuf, souts);

  hipMemsetAsync(sbuf, 0, NB * KO * sizeof(float), stream);
  route_iter_k<<<NB * 8, 256, 0, stream>>>(priors, souts, logits, sbuf, 1, 0);
  squash_k<<<(NB * NCLS + 255) / 256, 256, 0, stream>>>(sbuf, souts);

  // ---- final scatter ----
  out_k<<<(8 * 16 * NCLS * NO + 255) / 256, 256, 0, stream>>>(souts, out);
}

// Round 11
// 591.938 us; speedup vs baseline: 1.2880x; 1.1315x over previous
//
#include <hip/hip_runtime.h>
#include <math.h>

typedef unsigned int   uint;
typedef unsigned short ushort;
using bf16x8 = __attribute__((ext_vector_type(8))) __bf16;
using f32x4  = __attribute__((ext_vector_type(4))) float;

constexpr int NB   = 128;
constexpr int NCAP = 512;
constexpr int NCLS = 43;
constexpr int NO   = 21;
constexpr int KO   = NCLS * NO; // 903

// ---- workspace layout (float offsets) ----
constexpr size_t F_X1H  = 0;          // conv1 out, blocked [16][131072][8] bf16 (single)
constexpr size_t F_PART = 0;          // conv3/4/5 K-split partials (x1 dead by then)
constexpr size_t F_STAT = 16777216;   // 1,024 floats
constexpr size_t F_WPH  = 16778240;   // conv2 w hi (147,456)
constexpr size_t F_WPL  = 16925696;
constexpr size_t F_W3H  = 17073152;
constexpr size_t F_W3L  = 17204224;
constexpr size_t F_W4H  = 17335296;
constexpr size_t F_W4L  = 17400832;
constexpr size_t F_W5H  = 17466368;
constexpr size_t F_W5L  = 17728512;
constexpr size_t F_X3H  = 17990656;   // conv2 out, blocked [32][131072][8] bf16 (single)
constexpr size_t F_H3   = 51545088;   // h3 NHWC fp32 (2,097,152)
constexpr size_t F_X4H  = 53642240;
constexpr size_t F_H4   = 55739392;
constexpr size_t F_X5H  = 56787968;
constexpr size_t F_H5   = 57836544;   // (524,288)
// routing phase:
constexpr size_t F_PRI  = 0;          // bf16 priors: 59,179,008 ushorts
constexpr size_t F_CAPS = 59179008;   // 524,288
constexpr size_t F_LOG  = 59703296;   // 2,818,048
constexpr size_t F_S    = 65339392;   // 115,584
constexpr size_t F_OUTS = 65454976;   // 115,584
constexpr size_t F_ZERO = 65570560;   // zero stub for OOB global_load_lds

__device__ inline ushort f2bf(float x) {
  uint u = __float_as_uint(x);
  uint r = (u + 0x7fffu + ((u >> 16) & 1u)) >> 16;  // RNE
  return (ushort)r;
}
__device__ inline float bf2f(ushort h) { return __uint_as_float(((uint)h) << 16); }

#define GLL16(gsrc, ldst)                                               \
  __builtin_amdgcn_global_load_lds(                                     \
      (const __attribute__((address_space(1))) void*)(gsrc),            \
      (__attribute__((address_space(3))) void*)(ldst), 16, 0, 0)

// ---------------- conv1: fp32 direct, writes blocked pre-BN bf16 ----
__global__ __launch_bounds__(256) void conv1_k(
    const float* __restrict__ in, const float* __restrict__ w,
    ushort* __restrict__ oh, float* __restrict__ stats)
{
  constexpr int KS = 3, ICC = 3, IHT = 10, IWT = 18;
  const int ocb = blockIdx.z & 3;
  const int b   = blockIdx.z >> 2;
  const int tx0 = blockIdx.x * 16;
  const int ty0 = blockIdx.y * 8;
  const int oc0 = ocb * 32;

  __shared__ float lin[ICC][IHT][IWT];
  __shared__ float lw[ICC][KS * KS][32];
  __shared__ float b1sum[32], b1sq[32];

  const int t  = threadIdx.x;
  const int pq = t & 3;
  const int ty = (t >> 2) & 7;
  const int oq = t >> 5;

  float acc[4][4];
#pragma unroll
  for (int m = 0; m < 4; ++m)
#pragma unroll
    for (int j = 0; j < 4; ++j) acc[m][j] = 0.f;

  const int gx0 = tx0 - 1;
  const int gy0 = ty0 - 1;

  for (int e = t; e < ICC * IHT * IWT; e += 256) {
    int ic = e / (IHT * IWT);
    int rr = e % (IHT * IWT);
    int ey = rr / IWT, ex = rr % IWT;
    int gy = gy0 + ey, gx = gx0 + ex;
    float v = 0.f;
    if ((unsigned)gy < 128u && (unsigned)gx < 128u)
      v = in[((size_t)(b * 3 + ic) * 128 + gy) * 128 + gx];
    lin[ic][ey][ex] = v;
  }
  for (int e = t; e < ICC * 9 * 32; e += 256) {
    int ocl = e & 31;
    int rr  = e >> 5;
    int kk  = rr % 9;
    int ic  = rr / 9;
    lw[ic][kk][ocl] = w[((size_t)(oc0 + ocl) * 3 + ic) * 9 + kk];
  }
  __syncthreads();

  for (int ic = 0; ic < ICC; ++ic) {
#pragma unroll
    for (int ky = 0; ky < KS; ++ky) {
#pragma unroll
      for (int kx = 0; kx < KS; ++kx) {
        float xv[4];
#pragma unroll
        for (int j = 0; j < 4; ++j)
          xv[j] = lin[ic][ty + ky][pq * 4 + j + kx];
        const float4 w4 = *(const float4*)&lw[ic][ky * KS + kx][oq * 4];
#pragma unroll
        for (int j = 0; j < 4; ++j) {
          acc[0][j] = fmaf(w4.x, xv[j], acc[0][j]);
          acc[1][j] = fmaf(w4.y, xv[j], acc[1][j]);
          acc[2][j] = fmaf(w4.z, xv[j], acc[2][j]);
          acc[3][j] = fmaf(w4.w, xv[j], acc[3][j]);
        }
      }
    }
  }

  const int oy = ty0 + ty;
  const int oc0q = oc0 + oq * 4;
  const size_t icb = oc0q >> 3;
  const int off = oc0q & 7;
  float sm[4] = {0.f, 0.f, 0.f, 0.f}, qm[4] = {0.f, 0.f, 0.f, 0.f};
#pragma unroll
  for (int j = 0; j < 4; ++j) {
    int px = tx0 + pq * 4 + j;
    size_t pxg = ((size_t)b * 128 + oy) * 128 + px;
    size_t addr = (icb * 131072 + pxg) * 8 + off;
    ushort h0 = f2bf(acc[0][j]);
    ushort h1 = f2bf(acc[1][j]);
    ushort h2 = f2bf(acc[2][j]);
    ushort h3 = f2bf(acc[3][j]);
    uint2 uh; uh.x = (uint)h0 | ((uint)h1 << 16); uh.y = (uint)h2 | ((uint)h3 << 16);
    *(uint2*)(oh + addr) = uh;
    float v0 = bf2f(h0), v1 = bf2f(h1), v2 = bf2f(h2), v3 = bf2f(h3);
    sm[0] += v0; qm[0] += v0 * v0;
    sm[1] += v1; qm[1] += v1 * v1;
    sm[2] += v2; qm[2] += v2 * v2;
    sm[3] += v3; qm[3] += v3 * v3;
  }
#pragma unroll
  for (int o = 16; o > 0; o >>= 1) {
#pragma unroll
    for (int m = 0; m < 4; ++m) {
      sm[m] += __shfl_xor(sm[m], o);
      qm[m] += __shfl_xor(qm[m], o);
    }
  }
  if ((t & 31) == 0) {
#pragma unroll
    for (int m = 0; m < 4; ++m) { b1sum[oq * 4 + m] = sm[m]; b1sq[oq * 4 + m] = qm[m]; }
  }
  __syncthreads();
  if (t < 32) {
    atomicAdd(&stats[oc0 + t], b1sum[t]);
    atomicAdd(&stats[128 + oc0 + t], b1sq[t]);
  }
}

// ---- in-place BN+LReLU on blocked bf16 x1 ----
__global__ __launch_bounds__(256) void bn_apply_x1_k(
    ushort* __restrict__ xh, const float* __restrict__ stats,
    const float* __restrict__ g, const float* __restrict__ bt)
{
  __shared__ float scs[128], sfs[128];
  const int t = threadIdx.x;
  if (t < 128) {
    float m = stats[t] * (1.f / 131072.f);
    float v = stats[128 + t] * (1.f / 131072.f) - m * m;
    float rs = rsqrtf(v + 1e-5f);
    float sc = g[t] * rs;
    scs[t] = sc; sfs[t] = bt[t] - m * sc;
  }
  __syncthreads();
  const size_t total = (size_t)16 * 131072;
  const size_t stride = (size_t)gridDim.x * 256;
  for (size_t i = (size_t)blockIdx.x * 256 + t; i < total; i += stride) {
    int j = (int)(i >> 17);
    int c0 = j * 8;
    uint4 vh = *(const uint4*)(xh + i * 8);
    uint hw[4] = {vh.x, vh.y, vh.z, vh.w};
    uint ohv[4];
#pragma unroll
    for (int m = 0; m < 4; ++m) {
      float f0 = __uint_as_float(hw[m] << 16);
      float f1 = __uint_as_float(hw[m] & 0xffff0000u);
      float a0 = fmaf(f0, scs[c0 + 2*m],   sfs[c0 + 2*m]);   a0 = fmaxf(a0, 0.1f * a0);
      float a1 = fmaf(f1, scs[c0 + 2*m+1], sfs[c0 + 2*m+1]); a1 = fmaxf(a1, 0.1f * a1);
      ohv[m] = (uint)f2bf(a0) | ((uint)f2bf(a1) << 16);
    }
    uint4 rh = {ohv[0], ohv[1], ohv[2], ohv[3]};
    *(uint4*)(xh + i * 8) = rh;
  }
}

__global__ __launch_bounds__(256) void bn_stats_nhwc_k(
    const float* __restrict__ x, float* __restrict__ stats,
    int cmask, int lg2c, int totpx)
{
  int g = blockIdx.x * 256 + threadIdx.x;
  int c = g & cmask;
  int p0 = g >> lg2c;
  int stride = (gridDim.x * 256) >> lg2c;
  float s = 0.f, q = 0.f;
  for (int p = p0; p < totpx; p += stride) {
    float v = x[((size_t)p << lg2c) | c];
    s += v; q += v * v;
  }
  atomicAdd(&stats[c], s);
  atomicAdd(&stats[cmask + 1 + c], q);
}

// ---- BN+LReLU+split fp32 NHWC -> blocked bf16 (inline fin) ----
template<int C>
__global__ __launch_bounds__(256) void split_blocked_k(
    const float* __restrict__ h, const float* __restrict__ stats,
    const float* __restrict__ g, const float* __restrict__ bt, float inv_n,
    ushort* __restrict__ oh, int totpx)
{
  __shared__ ushort lh[16][C + 8];
  __shared__ float scs[C], sfs[C];
  const int px0 = blockIdx.x * 16;
  const int t = threadIdx.x;
  if (t < C) {
    float m = stats[t] * inv_n;
    float v = stats[C + t] * inv_n - m * m;
    float rs = rsqrtf(v + 1e-5f);
    float sc = g[t] * rs;
    scs[t] = sc; sfs[t] = bt[t] - m * sc;
  }
  __syncthreads();
  for (int e = t; e < 16 * C / 4; e += 256) {
    int px = e / (C / 4);
    int c0 = (e % (C / 4)) * 4;
    float4 v  = *(const float4*)(h + (size_t)(px0 + px) * C + c0);
    float a0 = fmaf(v.x, scs[c0],   sfs[c0]);   a0 = fmaxf(a0, 0.1f * a0);
    float a1 = fmaf(v.y, scs[c0+1], sfs[c0+1]); a1 = fmaxf(a1, 0.1f * a1);
    float a2 = fmaf(v.z, scs[c0+2], sfs[c0+2]); a2 = fmaxf(a2, 0.1f * a2);
    float a3 = fmaf(v.w, scs[c0+3], sfs[c0+3]); a3 = fmaxf(a3, 0.1f * a3);
    lh[px][c0]   = f2bf(a0);
    lh[px][c0+1] = f2bf(a1);
    lh[px][c0+2] = f2bf(a2);
    lh[px][c0+3] = f2bf(a3);
  }
  __syncthreads();
  for (int e = t; e < 16 * (C / 8); e += 256) {
    int j = e >> 4, px = e & 15;
    *(uint4*)(oh + ((size_t)j * totpx + px0 + px) * 8) = *(const uint4*)&lh[px][j * 8];
  }
}

// ------- all weight splits merged; FRAGMENT-ORDERED layouts (W keeps hi/lo) -------
__global__ void wsplit_all_k(
    const float* __restrict__ c2w, const float* __restrict__ c3w,
    const float* __restrict__ c4w, const float* __restrict__ c5w,
    ushort* __restrict__ wph, ushort* __restrict__ wpl,
    ushort* __restrict__ w3h, ushort* __restrict__ w3l,
    ushort* __restrict__ w4h, ushort* __restrict__ w4l,
    ushort* __restrict__ w5h, ushort* __restrict__ w5l)
{
  int i = blockIdx.x * 256 + threadIdx.x;
  if (i < 294912) {
    int kk = i % 9; int r = i / 9; int ic = r & 127; int oc = r >> 7;
    float v = c2w[i];
    ushort hi = f2bf(v), lo = f2bf(v - bf2f(hi));
    int ohf = oc >> 7, of = (oc >> 4) & 7, lr = oc & 15;
    int ic32 = ic >> 5, kg = (ic >> 3) & 3, ici = ic & 7;
    size_t d = ((((size_t)(kk * 4 + ic32) * 2 + ohf) * 8 + of) * 4 + kg) * 128
               + lr * 8 + ici;
    wph[d] = hi; wpl[d] = lo;
    return;
  }
  i -= 294912;
  const float* w; ushort *wh, *wl; int OC, IC, n;
  if (i < 262144)      { w = c3w; wh = w3h; wl = w3l; OC = 64;  IC = 256; n = i; }
  else if (i < 393216) { w = c4w; wh = w4h; wl = w4l; OC = 128; IC = 64;  n = i - 262144; }
  else if (i < 917504) { w = c5w; wh = w5h; wl = w5l; OC = 256; IC = 128; n = i - 393216; }
  else return;
  int kx = n & 3, ky = (n >> 2) & 3;
  int ic = (n >> 4) % IC, oc = (n >> 4) / IC;
  float v = w[n];
  ushort hi = f2bf(v), lo = f2bf(v - bf2f(hi));
  int NCH = IC >> 3, NWO = OC >> 6;
  int wo = oc >> 6, of = (oc >> 4) & 3, lr = oc & 15;
  int ch = ic >> 3, ici = ic & 7;
  size_t d = ((((size_t)(ky * NCH + ch) * NWO + wo) * 4 + of) * 4 + kx) * 128
             + lr * 8 + ici;
  wh[d] = hi; wl[d] = lo;
}

// ---- conv2 X staging: async global->LDS, single bf16 tensor ----
__device__ __forceinline__ void stage_x(
    const ushort* __restrict__ x1h, const ushort* __restrict__ zbuf,
    ushort* dst, int t, int b, int gy, int ic32)
{
  const bool rowok = (unsigned)gy < 128u;
  const size_t rowb = ((size_t)b * 128 + (rowok ? gy : 0)) * 128;
#pragma unroll
  for (int k = 0; k < 2; ++k) {
    int e = t + k * 256;
    int icg = e / 130;
    int xi = e - icg * 130;
    int gx = xi - 1;
    const ushort* sh = zbuf;
    if (rowok && (unsigned)gx < 128u) {
      size_t gi = ((size_t)(ic32 * 4 + icg) * 131072 + rowb + gx) * 8;
      sh = x1h + gi;
    }
    GLL16(sh, dst + (size_t)e * 8);
  }
  if (t < 8) {
    int e = 512 + t;
    int xi = e - 390;          // icg = 3
    int gx = xi - 1;
    const ushort* sh = zbuf;
    if (rowok && (unsigned)gx < 128u) {
      size_t gi = ((size_t)(ic32 * 4 + 3) * 131072 + rowb + gx) * 8;
      sh = x1h + gi;
    }
    GLL16(sh, dst + (size_t)e * 8);
  }
}

// ------- conv2 via MFMA (W bf16x2, X bf16): async dbuf staging -------
__global__ __launch_bounds__(256, 2) void conv2_mfma_k(
    const ushort* __restrict__ x1h,
    const ushort* __restrict__ wph, const ushort* __restrict__ wpl,
    const ushort* __restrict__ zbuf, float* __restrict__ stats2,
    ushort* __restrict__ x3h)
{
  const int bid = blockIdx.x;                 // 1024 blocks
  const int wid = (bid & 7) * 128 + (bid >> 3);
  const int y0  = wid & 127;
  const int b   = wid >> 7;

  __shared__ ushort xs[2][4][130][8];   // [buf][icg][xi][8ic] : 16,640 B
  __shared__ float bsum[2][256], bsq[2][256];

  const int t = threadIdx.x;
  const int w  = t >> 6;
  const int l  = t & 63;
  const int xhf = w & 1;
  const int ohf = w >> 1;
  const int lr = l & 15;
  const int kg = l >> 4;

  f32x4 acc[8][4];
#pragma unroll
  for (int i = 0; i < 8; ++i)
#pragma unroll
    for (int j = 0; j < 4; ++j) acc[i][j] = (f32x4){0.f, 0.f, 0.f, 0.f};

  // prologue: stage phase 0 into buf 0
  stage_x(x1h, zbuf, (ushort*)&xs[0][0][0][0], t, b, y0 - 1, 0);
  __syncthreads();

  for (int ky = 0; ky < 3; ++ky) {
    for (int ic32 = 0; ic32 < 4; ++ic32) {
      const int buf = ic32 & 1;
      const int np = ky * 4 + ic32 + 1;
      if (np < 12) {
        stage_x(x1h, zbuf, (ushort*)&xs[buf ^ 1][0][0][0],
                t, b, y0 + (np >> 2) - 1, np & 3);
      }
#pragma unroll
      for (int kx = 0; kx < 3; ++kx) {
        const int kk = ky * 3 + kx;
        const size_t wbase =
            ((size_t)((kk * 4 + ic32) * 2 + ohf)) * 4096 + (size_t)l * 8;
        const ushort* pwh = wph + wbase;
        const ushort* pwl = wpl + wbase;

        bf16x8 xbh[4];
#pragma unroll
        for (int pf = 0; pf < 4; ++pf) {
          int xi = xhf * 64 + pf * 16 + lr + kx;
          xbh[pf] = *(const bf16x8*)&xs[buf][kg][xi][0];
        }
#pragma unroll
        for (int oh2 = 0; oh2 < 2; ++oh2) {
          bf16x8 awh[4], awl[4];
#pragma unroll
          for (int o4 = 0; o4 < 4; ++o4) {
            awh[o4] = *(const bf16x8*)(pwh + (oh2 * 4 + o4) * 512);
            awl[o4] = *(const bf16x8*)(pwl + (oh2 * 4 + o4) * 512);
          }
#pragma unroll
          for (int o4 = 0; o4 < 4; ++o4) {
            const int of = oh2 * 4 + o4;
#pragma unroll
            for (int pf = 0; pf < 4; ++pf) {
              acc[of][pf] = __builtin_amdgcn_mfma_f32_16x16x32_bf16(awh[o4], xbh[pf], acc[of][pf], 0, 0, 0);
              acc[of][pf] = __builtin_amdgcn_mfma_f32_16x16x32_bf16(awl[o4], xbh[pf], acc[of][pf], 0, 0, 0);
            }
          }
        }
      }
      __syncthreads();   // drains next-phase global_load_lds, syncs LDS reuse
    }
  }

  // epilogue: quantize+store + per-oc stats
#pragma unroll
  for (int of = 0; of < 8; ++of) {
    float s4[4] = {0.f, 0.f, 0.f, 0.f}, q4[4] = {0.f, 0.f, 0.f, 0.f};
#pragma unroll
    for (int pf = 0; pf < 4; ++pf) {
      int oc = ohf * 128 + of * 16 + kg * 4;
      int x  = xhf * 64 + pf * 16 + lr;
      size_t pxg = ((size_t)b * 128 + y0) * 128 + x;
      size_t base = ((size_t)(oc >> 3) * 131072 + pxg) * 8 + (oc & 7);
      f32x4 a = acc[of][pf];
      ushort h0 = f2bf(a[0]);
      ushort h1 = f2bf(a[1]);
      ushort h2 = f2bf(a[2]);
      ushort h3 = f2bf(a[3]);
      uint2 uh; uh.x = (uint)h0 | ((uint)h1 << 16); uh.y = (uint)h2 | ((uint)h3 << 16);
      *(uint2*)(x3h + base) = uh;
      float v0 = bf2f(h0), v1 = bf2f(h1), v2 = bf2f(h2), v3 = bf2f(h3);
      s4[0] += v0; q4[0] += v0 * v0;
      s4[1] += v1; q4[1] += v1 * v1;
      s4[2] += v2; q4[2] += v2 * v2;
      s4[3] += v3; q4[3] += v3 * v3;
    }
#pragma unroll
    for (int o = 8; o > 0; o >>= 1) {
#pragma unroll
      for (int j = 0; j < 4; ++j) {
        s4[j] += __shfl_xor(s4[j], o);
        q4[j] += __shfl_xor(q4[j], o);
      }
    }
    if (lr == 0) {
      int oc = ohf * 128 + of * 16 + kg * 4;
#pragma unroll
      for (int j = 0; j < 4; ++j) { bsum[xhf][oc + j] = s4[j]; bsq[xhf][oc + j] = q4[j]; }
    }
  }
  __syncthreads();
  if (t < 256) {
    atomicAdd(&stats2[t],       bsum[0][t] + bsum[1][t]);
    atomicAdd(&stats2[256 + t], bsq[0][t] + bsq[1][t]);
  }
}

// ------- conv3/4/5 via MFMA (W bf16x2, X bf16), K-split -------
template<int IC, int OC, int OH, int OW, int WPX, int CS, bool FBN>
__global__ __launch_bounds__(256, 2) void convs_mfma_k(
    const ushort* __restrict__ xh,
    const ushort* __restrict__ wh, const ushort* __restrict__ wl,
    const float* __restrict__ stats, const float* __restrict__ gg,
    const float* __restrict__ bb, float inv_n,
    float* __restrict__ part)
{
  constexpr int IH  = 2 * OH, IW = 2 * OW;
  constexpr int NCH = IC / 8;
  constexpr int NCHB = NCH / CS;
  constexpr int PFX = OW / 16;
  constexpr int RW  = 4 / WPX;
  constexpr int NZ = 4 * CS;
  constexpr int NX = OH / 4;
  constexpr int NWO = OC / 64;
  constexpr int SBN = FBN ? IC : 1;

  const int bid = blockIdx.x;
  const int wid = (bid & 7) * (NZ * NX) + (bid >> 3);
  const int zi = wid % NZ;
  const int y0 = ((wid / NZ) % NX) * 4;
  const int b  = wid / (NZ * NX);
  const int ky = zi & 3;
  const int cs = zi >> 2;

  __shared__ ushort xs[4][2][OW + 2][8];
  __shared__ float scs[SBN], sfs[SBN];

  const int t = threadIdx.x;
  if (FBN) {
    for (int c = t; c < IC; c += 256) {
      float m = stats[c] * inv_n;
      float v = stats[IC + c] * inv_n - m * m;
      float rs = rsqrtf(v + 1e-5f);
      float sc = gg[c] * rs;
      scs[c] = sc; sfs[c] = bb[c] - m * sc;
    }
  }

  const int w = t >> 6, l = t & 63;
  const int wo = w / WPX, wp = w % WPX;
  const int lr = l & 15, kg = l >> 4;
  const int oc0w = wo * 64;
  const int rb = wp * RW;

  f32x4 acc[4][4];
#pragma unroll
  for (int i = 0; i < 4; ++i)
#pragma unroll
    for (int j = 0; j < 4; ++j) acc[i][j] = (f32x4){0.f, 0.f, 0.f, 0.f};

  for (int cc = 0; cc < NCHB; ++cc) {
    const int ch = cs * NCHB + cc;
    __syncthreads();
    for (int e = t; e < 4 * (IW + 2); e += 256) {
      int r  = e / (IW + 2);
      int xi = e % (IW + 2);
      int xp = xi - 1;
      int iy = 2 * (y0 + r) + ky - 1;
      uint4 rh = {0, 0, 0, 0};
      if ((unsigned)iy < (unsigned)IH && (unsigned)xp < (unsigned)IW) {
        size_t gi = ((((size_t)ch * 8 + b) * IH + iy) * IW + xp) * 8;
        uint4 vh = *(const uint4*)(xh + gi);
        if (FBN) {
          int c0 = ch * 8;
          uint hw[4] = {vh.x, vh.y, vh.z, vh.w};
          uint ohv[4];
#pragma unroll
          for (int m = 0; m < 4; ++m) {
            float f0 = __uint_as_float(hw[m] << 16);
            float f1 = __uint_as_float(hw[m] & 0xffff0000u);
            float a0 = fmaf(f0, scs[c0 + 2*m],   sfs[c0 + 2*m]);   a0 = fmaxf(a0, 0.1f * a0);
            float a1 = fmaf(f1, scs[c0 + 2*m+1], sfs[c0 + 2*m+1]); a1 = fmaxf(a1, 0.1f * a1);
            ohv[m] = (uint)f2bf(a0) | ((uint)f2bf(a1) << 16);
          }
          rh.x = ohv[0]; rh.y = ohv[1]; rh.z = ohv[2]; rh.w = ohv[3];
        } else {
          rh = vh;
        }
      }
      int par = xp & 1;
      int idx = (xp + 1) >> 1;
      *(uint4*)&xs[r][par][idx][0] = rh;
    }
    __syncthreads();

    const size_t wbase =
        ((size_t)(ky * NCH + ch) * NWO + wo) * 2048 + (size_t)l * 8;
    bf16x8 ah[4], al[4], bh[4];
#pragma unroll
    for (int of = 0; of < 4; ++of) {
      ah[of] = *(const bf16x8*)(wh + wbase + of * 512);
      al[of] = *(const bf16x8*)(wl + wbase + of * 512);
    }
    const int par = 1 - (kg & 1);
    const int xoff = kg >> 1;
#pragma unroll
    for (int pf = 0; pf < 4; ++pf) {
      int row = rb + pf / PFX;
      int x   = (pf % PFX) * 16 + lr;
      bh[pf] = *(const bf16x8*)&xs[row][par][x + xoff][0];
    }
#pragma unroll
    for (int of = 0; of < 4; ++of) {
#pragma unroll
      for (int pf = 0; pf < 4; ++pf) {
        acc[of][pf] = __builtin_amdgcn_mfma_f32_16x16x32_bf16(ah[of], bh[pf], acc[of][pf], 0, 0, 0);
        acc[of][pf] = __builtin_amdgcn_mfma_f32_16x16x32_bf16(al[of], bh[pf], acc[of][pf], 0, 0, 0);
      }
    }
  }

  float* yp = part + (size_t)zi * (8 * OH * OW * OC);
#pragma unroll
  for (int of = 0; of < 4; ++of) {
#pragma unroll
    for (int pf = 0; pf < 4; ++pf) {
      int row = rb + pf / PFX;
      int x   = (pf % PFX) * 16 + lr;
      int oc  = oc0w + of * 16 + kg * 4;
      float* p = yp + (((size_t)b * OH + y0 + row) * OW + x) * OC + oc;
      f32x4 a = acc[of][pf];
      float4 v = {a[0], a[1], a[2], a[3]};
      *(float4*)p = v;
    }
  }
}

// ------- reduce partials -> h (float4) -------
__global__ __launch_bounds__(256) void reduce_k(
    const float* __restrict__ part, float* __restrict__ h,
    int n4, int nparts)
{
  int i = blockIdx.x * 256 + threadIdx.x;
  if (i >= n4) return;
  float4 a = ((const float4*)part)[i];
  for (int z = 1; z < nparts; ++z) {
    float4 b = ((const float4*)part)[(size_t)z * n4 + i];
    a.x += b.x; a.y += b.y; a.z += b.z; a.w += b.w;
  }
  ((float4*)h)[i] = a;
}

// ---------------- capsule rearrange (h5 NHWC, BN inline) ----------------
__global__ void caps_k(const float* __restrict__ h5, const float* __restrict__ stats,
                       const float* __restrict__ g5, const float* __restrict__ b5,
                       float* __restrict__ caps)
{
  int e = blockIdx.x * 256 + threadIdx.x;
  if (e >= NB * NCAP * 8) return;
  int ii = e & 7;
  int n  = (e >> 3) & 511;
  int jb = e >> 12;
  int j = jb >> 3, b = jb & 7;
  int i = n >> 7, k = (n >> 5) & 3, ch = ((n & 31) << 3) | ii;
  int hh = (i << 2) | (j >> 2);
  int ww = ((j & 3) << 2) | k;
  float m  = stats[ch] * (1.f / 2048.f);
  float vv = stats[256 + ch] * (1.f / 2048.f) - m * m;
  float rs = rsqrtf(vv + 1e-5f);
  float sc = g5[ch] * rs;
  float sf = b5[ch] - m * sc;
  float v = h5[(((size_t)b * 16 + hh) * 16 + ww) * 256 + ch];
  float a = fmaf(v, sc, sf);
  a = fmaxf(a, 0.1f * a);
  caps[e] = a;
}

// ---------------- priors (bf16 output) ----------------
__global__ __launch_bounds__(256) void priors_k(
    const float* __restrict__ caps, const float* __restrict__ rw,
    ushort* __restrict__ priors)
{
  const int n = blockIdx.x;
  __shared__ float lrw[NCLS * 8 * NO];
  __shared__ float lc[NB * 8];
  const int t = threadIdx.x;
  for (int e = t; e < NCLS * 8 * NO; e += 256)
    lrw[e] = rw[(size_t)n * NCLS * 8 * NO + e];
  for (int e = t; e < NB * 8; e += 256) {
    int b = e >> 3, ii = e & 7;
    lc[e] = caps[((size_t)b * NCAP + n) * 8 + ii];
  }
  __syncthreads();

  int p[4], kk[4], oo[4];
#pragma unroll
  for (int q = 0; q < 4; ++q) {
    p[q]  = t + q * 256;
    kk[q] = (p[q] < KO) ? p[q] / NO : 0;
    oo[q] = (p[q] < KO) ? p[q] % NO : 0;
  }
  for (int b = 0; b < NB; ++b) {
    const float* cb = &lc[b * 8];
    float c0 = cb[0], c1 = cb[1], c2 = cb[2], c3 = cb[3];
    float c4 = cb[4], c5 = cb[5], c6 = cb[6], c7 = cb[7];
    ushort* pout = priors + ((size_t)b * NCAP + n) * KO;
#pragma unroll
    for (int q = 0; q < 4; ++q) {
      if (p[q] < KO) {
        const float* wv = &lrw[kk[q] * (8 * NO) + oo[q]];
        float a = c0 * wv[0];
        a = fmaf(c1, wv[21],  a);
        a = fmaf(c2, wv[42],  a);
        a = fmaf(c3, wv[63],  a);
        a = fmaf(c4, wv[84],  a);
        a = fmaf(c5, wv[105], a);
        a = fmaf(c6, wv[126], a);
        a = fmaf(c7, wv[147], a);
        pout[p[q]] = f2bf(a);
      }
    }
  }
}

// ---------------- routing ----------------
__global__ __launch_bounds__(256) void route_s_partial(
    const ushort* __restrict__ priors, float* __restrict__ s)
{
  const int b  = blockIdx.x >> 3;
  const int ns = blockIdx.x & 7;
  const int t  = threadIdx.x;
  const int p0 = t, p1 = t + 256, p2 = t + 512, p3 = t + 768;
  float a0 = 0.f, a1 = 0.f, a2 = 0.f, a3 = 0.f;
  const ushort* pb = priors + ((size_t)b * NCAP + ns * 64) * KO;
#pragma unroll 2
  for (int n = 0; n < 64; ++n) {
    const ushort* pn = pb + (size_t)n * KO;
    a0 += bf2f(pn[p0]); a1 += bf2f(pn[p1]); a2 += bf2f(pn[p2]);
    if (p3 < KO) a3 += bf2f(pn[p3]);
  }
  const float sc = 1.f / 43.f;
  atomicAdd(&s[b * KO + p0], a0 * sc);
  atomicAdd(&s[b * KO + p1], a1 * sc);
  atomicAdd(&s[b * KO + p2], a2 * sc);
  if (p3 < KO) atomicAdd(&s[b * KO + p3], a3 * sc);
}

// fused logits+softmax+s: barrier-free, lane k owns class k, wave-local LDS
__global__ __launch_bounds__(256) void route_iter_k(
    const ushort* __restrict__ priors, const float* __restrict__ souts,
    float* __restrict__ logits, float* __restrict__ s,
    int readPrev, int writeL)
{
  const int b  = blockIdx.x >> 3;
  const int ns = blockIdx.x & 7;
  const int t  = threadIdx.x;
  const int w  = t >> 6;
  const int lane = t & 63;
  const bool act = lane < NCLS;

  __shared__ float prow[4][928];

  float so[NO], sacc[NO], v[NO];
  if (act) {
#pragma unroll
    for (int o = 0; o < NO; ++o) so[o] = souts[b * KO + lane * NO + o];
  }
#pragma unroll
  for (int o = 0; o < NO; ++o) { sacc[o] = 0.f; v[o] = 0.f; }

  for (int nn = 0; nn < 16; ++nn) {
    const int n = ns * 64 + w * 16 + nn;
    const ushort* pr = priors + ((size_t)(b * NCAP + n)) * KO;
#pragma unroll
    for (int q = 0; q < 15; ++q) {
      int e = lane + q * 64;
      if (e < KO) prow[w][e] = bf2f(pr[e]);
    }
    float L = -1e30f;
    if (act) {
      float d = 0.f;
#pragma unroll
      for (int o = 0; o < NO; ++o) v[o] = prow[w][lane * NO + o];
#pragma unroll
      for (int o = 0; o < NO; ++o) d = fmaf(v[o], so[o], d);
      size_t lidx = ((size_t)(b * NCAP + n)) * NCLS + lane;
      L = (readPrev ? logits[lidx] : 0.f) + d;
      if (writeL) logits[lidx] = L;
    }
    float m = L;
#pragma unroll
    for (int off = 32; off > 0; off >>= 1) m = fmaxf(m, __shfl_xor(m, off));
    float ex = act ? __expf(L - m) : 0.f;
    float sm = ex;
#pragma unroll
    for (int off = 32; off > 0; off >>= 1) sm += __shfl_xor(sm, off);
    float pk = ex / sm;
    if (act) {
#pragma unroll
      for (int o = 0; o < NO; ++o) sacc[o] = fmaf(pk, v[o], sacc[o]);
    }
  }
  if (act) {
#pragma unroll
    for (int o = 0; o < NO; ++o) prow[w][lane * NO + o] = sacc[o];
  }
  __syncthreads();
  for (int e = t; e < KO; e += 256)
    atomicAdd(&s[b * KO + e], prow[0][e] + prow[1][e] + prow[2][e] + prow[3][e]);
}

__global__ void squash_k(const float* __restrict__ s, float* __restrict__ souts)
{
  int i = blockIdx.x * 256 + threadIdx.x;
  if (i >= NB * NCLS) return;
  int b = i / NCLS, k = i % NCLS;
  const float* sv = s + b * KO + k * NO;
  float sn = 0.f;
#pragma unroll
  for (int o = 0; o < NO; ++o) sn += sv[o] * sv[o];
  float f = sqrtf(sn) / (1.f + sn);
  float* ov = souts + b * KO + k * NO;
#pragma unroll
  for (int o = 0; o < NO; ++o) ov[o] = sv[o] * f;
}

__global__ void out_k(const float* __restrict__ souts, float* __restrict__ out)
{
  int i = blockIdx.x * 256 + threadIdx.x;
  if (i >= 8 * 16 * NCLS * NO) return;
  int o = i % NO;
  int r = i / NO;
  int k = r % NCLS; r /= NCLS;
  int g1 = r & 3; r >>= 2;
  int g0 = r & 3;
  int b  = r >> 2;
  int j  = g0 * 4 + g1;
  int jb = j * 8 + b;
  out[i] = souts[jb * KO + k * NO + o];
}

// ---------------- launcher ----------------
extern "C" void kernel_launch(void* const* d_in, const int* in_sizes, int n_in,
                              void* d_out, int out_size, void* d_ws, size_t ws_size,
                              hipStream_t stream)
{
  const float* x   = (const float*)d_in[0];
  const float* c1w = (const float*)d_in[1];
  const float* g1  = (const float*)d_in[3];  const float* b1  = (const float*)d_in[4];
  const float* c2w = (const float*)d_in[5];
  const float* g2  = (const float*)d_in[7];  const float* b2  = (const float*)d_in[8];
  const float* c3w = (const float*)d_in[9];
  const float* g3  = (const float*)d_in[11]; const float* b3  = (const float*)d_in[12];
  const float* c4w = (const float*)d_in[13];
  const float* g4  = (const float*)d_in[15]; const float* b4  = (const float*)d_in[16];
  const float* c5w = (const float*)d_in[17];
  const float* g5  = (const float*)d_in[19]; const float* b5  = (const float*)d_in[20];
  const float* rw  = (const float*)d_in[21];

  float* ws  = (float*)d_ws;
  float* out = (float*)d_out;

  ushort* x1h = (ushort*)(ws + F_X1H);
  ushort* wph = (ushort*)(ws + F_WPH);
  ushort* wpl = (ushort*)(ws + F_WPL);
  ushort* w3h = (ushort*)(ws + F_W3H);
  ushort* w3l = (ushort*)(ws + F_W3L);
  ushort* w4h = (ushort*)(ws + F_W4H);
  ushort* w4l = (ushort*)(ws + F_W4L);
  ushort* w5h = (ushort*)(ws + F_W5H);
  ushort* w5l = (ushort*)(ws + F_W5L);
  ushort* x3h = (ushort*)(ws + F_X3H);
  ushort* x4h = (ushort*)(ws + F_X4H);
  ushort* x5h = (ushort*)(ws + F_X5H);
  float* part   = ws + F_PART;
  float* h3     = ws + F_H3;
  float* h4     = ws + F_H4;
  float* h5     = ws + F_H5;
  float* caps   = ws + F_CAPS;
  ushort* priors = (ushort*)(ws + F_PRI);
  float* logits = ws + F_LOG;
  float* sbuf   = ws + F_S;
  float* souts  = ws + F_OUTS;
  float* stats  = ws + F_STAT;          // conv1 stats [0..255]; scratch [0..511]
  float* stats2 = ws + F_STAT + 512;    // conv2 stats [0..511]
  ushort* zbuf  = (ushort*)(ws + F_ZERO);

  // ---- init: zero stats and the OOB zero stub ----
  hipMemsetAsync(stats, 0, 1024 * sizeof(float), stream);
  hipMemsetAsync(zbuf, 0, 64, stream);

  // ---- weight preps (merged, fragment-ordered) ----
  wsplit_all_k<<<(1212416 + 255) / 256, 256, 0, stream>>>(
      c2w, c3w, c4w, c5w, wph, wpl, w3h, w3l, w4h, w4l, w5h, w5l);

  // ---- conv1 -> blocked pre-BN bf16 (stats folded in) ----
  conv1_k<<<dim3(8, 16, 32), 256, 0, stream>>>(x, c1w, x1h, stats);

  // ---- BN+LReLU applied in place to x1 ----
  bn_apply_x1_k<<<2048, 256, 0, stream>>>(x1h, stats, g1, b1);

  // ---- conv2 (MFMA W-bf16x2, async dbuf staging, XCD swizzle) ----
  conv2_mfma_k<<<1024, 256, 0, stream>>>(x1h, wph, wpl, zbuf, stats2, x3h);

  // ---- conv3 (MFMA, ky-split x4, BN of x3 fused via stats2) ----
  convs_mfma_k<256, 64, 64, 64, 4, 1, true><<<512, 256, 0, stream>>>(
      x3h, w3h, w3l, stats2, g2, b2, 1.f / 131072.f, part);
  reduce_k<<<(524288 + 255) / 256, 256, 0, stream>>>(part, h3, 524288, 4);
  hipMemsetAsync(stats, 0, 2 * 64 * sizeof(float), stream);
  bn_stats_nhwc_k<<<256, 256, 0, stream>>>(h3, stats, 63, 6, 32768);
  split_blocked_k<64><<<2048, 256, 0, stream>>>(h3, stats, g3, b3, 1.f / 32768.f, x4h, 32768);

  // ---- conv4 (MFMA, (ky x ch/2)-split x8) ----
  convs_mfma_k<64, 128, 32, 32, 2, 2, false><<<512, 256, 0, stream>>>(
      x4h, w4h, w4l, stats, g4, b4, 0.f, part);
  reduce_k<<<(262144 + 255) / 256, 256, 0, stream>>>(part, h4, 262144, 8);
  hipMemsetAsync(stats, 0, 2 * 128 * sizeof(float), stream);
  bn_stats_nhwc_k<<<128, 256, 0, stream>>>(h4, stats, 127, 7, 8192);
  split_blocked_k<128><<<512, 256, 0, stream>>>(h4, stats, g4, b4, 1.f / 8192.f, x5h, 8192);

  // ---- conv5 (MFMA, (ky x ch/2)-split x8) ----
  convs_mfma_k<128, 256, 16, 16, 1, 2, false><<<256, 256, 0, stream>>>(
      x5h, w5h, w5l, stats, g5, b5, 0.f, part);
  reduce_k<<<(131072 + 255) / 256, 256, 0, stream>>>(part, h5, 131072, 8);
  hipMemsetAsync(stats, 0, 2 * 256 * sizeof(float), stream);
  bn_stats_nhwc_k<<<64, 256, 0, stream>>>(h5, stats, 255, 8, 2048);

  // ---- capsules ----
  caps_k<<<2048, 256, 0, stream>>>(h5, stats, g5, b5, caps);
  priors_k<<<512, 256, 0, stream>>>(caps, rw, priors);

  // ---- routing: 3 iterations ----
  hipMemsetAsync(sbuf, 0, NB * KO * sizeof(float), stream);
  route_s_partial<<<NB * 8, 256, 0, stream>>>(priors, sbuf);
  squash_k<<<(NB * NCLS + 255) / 256, 256, 0, stream>>>(sbuf, souts);

  hipMemsetAsync(sbuf, 0, NB * KO * sizeof(float), stream);
  route_iter_k<<<NB * 8, 256, 0, stream>>>(priors, souts, logits, sbuf, 0, 1);
  squash_k<<<(NB * NCLS + 255) / 256, 256, 0, stream>>>(sbuf, souts);

  hipMemsetAsync(sbuf, 0, NB * KO * sizeof(float), stream);
  route_iter_k<<<NB * 8, 256, 0, stream>>>(priors, souts, logits, sbuf, 1, 0);
  squash_k<<<(NB * NCLS + 255) / 256, 256, 0, stream>>>(sbuf, souts);

  // ---- final scatter ----
  out_k<<<(8 * 16 * NCLS * NO + 255) / 256, 256, 0, stream>>>(souts, out);
}